// Round 10
// baseline (422.855 us; speedup 1.0000x reference)
//
#include <hip/hip_runtime.h>
#include <hip/hip_bf16.h>

typedef __attribute__((ext_vector_type(8))) short bf16x8;
typedef __attribute__((ext_vector_type(4))) float f32x4;

#define DEVFN static __device__ __forceinline__

constexpr int kSQ = 2048, kSKV = 2048, kD = 1024, kH = 16;
constexpr int kM = 4 * kSQ;   // 8192 rows (B*SQ)

DEVFN unsigned short f2bf(float f) {
  union { float f; unsigned u; } v; v.f = f;
  unsigned r = v.u + 0x7FFFu + ((v.u >> 16) & 1u);
  return (unsigned short)(r >> 16);
}
DEVFN float bf2f(unsigned short h) {
  union { unsigned u; float f; } v; v.u = ((unsigned)h) << 16; return v.f;
}
DEVFN unsigned cvtpk(float lo, float hi) {
  unsigned r;
  asm("v_cvt_pk_bf16_f32 %0, %1, %2" : "=v"(r) : "v"(lo), "v"(hi));
  return r;
}
DEVFN float vexp2(float x) {
  float r;
  asm("v_exp_f32 %0, %1" : "=v"(r) : "v"(x));
  return r;
}

DEVFN void gload16(const void* g, void* l) {
  __builtin_amdgcn_global_load_lds(
      (const __attribute__((address_space(1))) unsigned int*)g,
      (__attribute__((address_space(3))) unsigned int*)l, 16, 0, 0);
}

// ---------------------------------------------------------------------------
// Swizzled-tiled operand layouts (producer-side swizzle -> GEMM staging is
// perfectly LINEAR global_load_lds; ds_read_b128 frag reads are conflict-free):
//   A (8192x1024):  [p<32][kt<16][r<256][u<8][8]   u = (c>>3) ^ (r&7)
//   B (N-major):    [np<N/128][kt<16][r<128][u<8][8]  same rule
// ---------------------------------------------------------------------------

// Kernel 1 (merged): blocks [0, 2*kM): activation fp32->bf16 (swizzled-tiled)
// + LoRA-down dots. blocks [2*kM, 2*kM+1024): weight convert+transpose.
__global__ __launch_bounds__(256) void k_prep_wt(
    const float* __restrict__ hs, const float* __restrict__ enc,
    const float* __restrict__ qdn, const float* __restrict__ kdn,
    const float* __restrict__ vdn,
    const float* __restrict__ Wq, const float* __restrict__ Wk,
    const float* __restrict__ Wv, const float* __restrict__ Wo,
    unsigned short* __restrict__ hsb, unsigned short* __restrict__ encb,
    float* __restrict__ tq, float* __restrict__ tkv,
    unsigned short* __restrict__ Wqt, unsigned short* __restrict__ Wkvt,
    unsigned short* __restrict__ Wot) {
  __shared__ float red[4][8];
  __shared__ unsigned short tile[64][65];
  const int bid = blockIdx.x;
  const int tid = threadIdx.x;

  if (bid < 2 * kM) {
    const bool isH = bid < kM;
    const int rr = isH ? bid : bid - kM;
    const float* srcRow = (isH ? hs : enc) + (size_t)rr * kD;
    unsigned short* dstB = isH ? hsb : encb;

    float4 x = reinterpret_cast<const float4*>(srcRow)[tid];
    short4 o;
    o.x = (short)f2bf(x.x); o.y = (short)f2bf(x.y);
    o.z = (short)f2bf(x.z); o.w = (short)f2bf(x.w);
    {
      const int p = rr >> 8, r = rr & 255;
      const int kt = tid >> 4, us = (tid >> 1) & 7, e = (tid & 1) * 4;
      const int u = us ^ (r & 7);
      *reinterpret_cast<short4*>(
          &dstB[(((size_t)(p * 16 + kt)) * 256 + r) * 64 + u * 8 + e]) = o;
    }

    float xs[4] = {x.x, x.y, x.z, x.w};
    float a[4] = {0.f, 0.f, 0.f, 0.f};
    float bacc[4] = {0.f, 0.f, 0.f, 0.f};
    const float* dnA = isH ? qdn : kdn;
    const int base = tid * 4;
#pragma unroll
    for (int e = 0; e < 4; ++e) {
      const float* dr = dnA + (size_t)(base + e) * 4;
      a[0] += xs[e] * dr[0]; a[1] += xs[e] * dr[1];
      a[2] += xs[e] * dr[2]; a[3] += xs[e] * dr[3];
    }
    if (!isH) {
#pragma unroll
      for (int e = 0; e < 4; ++e) {
        const float* dr = vdn + (size_t)(base + e) * 4;
        bacc[0] += xs[e] * dr[0]; bacc[1] += xs[e] * dr[1];
        bacc[2] += xs[e] * dr[2]; bacc[3] += xs[e] * dr[3];
      }
    }
    const int l = tid & 63, w = tid >> 6;
    float vals[8] = {a[0], a[1], a[2], a[3], bacc[0], bacc[1], bacc[2], bacc[3]};
#pragma unroll
    for (int k2 = 0; k2 < 8; ++k2) {
      float v = vals[k2];
#pragma unroll
      for (int m = 1; m < 64; m <<= 1) v += __shfl_xor(v, m);
      if (l == 0) red[w][k2] = v;
    }
    __syncthreads();
    if (tid < 8) {
      float s = red[0][tid] + red[1][tid] + red[2][tid] + red[3][tid];
      if (isH) {
        if (tid < 4) tq[(size_t)rr * 4 + tid] = s;
      } else {
        tkv[(size_t)rr * 8 + tid] = s;   // 0..3 = k-down, 4..7 = v-down
      }
    }
  } else {
    const int t2 = bid - 2 * kM;
    const int wid = t2 >> 8, tt = t2 & 255;
    const float* W = (wid == 0) ? Wq : (wid == 1) ? Wk : (wid == 2) ? Wv : Wo;
    unsigned short* Wt = (wid == 0) ? Wqt : (wid <= 2) ? Wkvt : Wot;
    const int npOff = (wid == 2) ? 8 : 0;   // V weights occupy panels 8..15
    const int tk0 = (tt & 15) * 64;
    const int tn0 = (tt >> 4) * 64;
    for (int i = tid; i < 4096; i += 256) {
      int r = i >> 6, c = i & 63;
      tile[r][c] = f2bf(W[(size_t)(tk0 + r) * 1024 + tn0 + c]);
    }
    __syncthreads();
    const int kt = tk0 >> 6;
    for (int i = tid; i < 4096; i += 256) {
      int r2 = i >> 6, c2 = i & 63;       // r2 = n-offset, c2 = k-offset
      const int n = tn0 + r2;
      const int np = (n >> 7) + npOff, rB = n & 127;
      const int u = (c2 >> 3) ^ (rB & 7), e = c2 & 7;
      Wt[(((size_t)np * 16 + kt) * 128 + rB) * 64 + u * 8 + e] = tile[c2][r2];
    }
  }
}

// ---------------------------------------------------------------------------
// T3-minimum 2-phase GEMM (m248 recipe): stage tile kt+1 FIRST, then ds_read +
// MFMA the current tile, then a single vmcnt(0)+barrier per K-tile.

// Kernel 2: QKV projection. BM=BN=256, BK=64, 8 waves, 128KB LDS.
// grid 384 = 32 mp x 12 npb (npb<4: Q panels; npb in [4,12): K|V panels).
__global__ __launch_bounds__(512, 2) void k_gemm_qkv(
    const unsigned short* __restrict__ hsb, const unsigned short* __restrict__ encb,
    const unsigned short* __restrict__ Wqt, const unsigned short* __restrict__ Wkvt,
    const float* __restrict__ tq, const float* __restrict__ tkv,
    const float* __restrict__ q_up, const float* __restrict__ k_up,
    const float* __restrict__ v_up,
    unsigned short* __restrict__ Qhp, unsigned short* __restrict__ Khp,
    unsigned short* __restrict__ Vhp) {
  __shared__ unsigned short lA2[2][16384];
  __shared__ unsigned short lB2[2][16384];
  const int tid = threadIdx.x;
  const int l = tid & 63, w = tid >> 6;
  const int bid = blockIdx.x;
  const int rid = (bid & 7) * 48 + (bid >> 3);      // bijective, 384%8==0
  const int mp = rid / 12, npb = rid % 12;

  const unsigned short *Ag0, *Bg;
  const float *tmat, *up;
  unsigned short* dst;
  int np0, nOut0, tstr;
  if (npb < 4) {
    Ag0 = hsb + (size_t)mp * 16 * 16384;
    Bg = Wqt; np0 = npb * 2; nOut0 = np0 * 128;
    tmat = tq; tstr = 4; up = q_up; dst = Qhp;
  } else {
    Ag0 = encb + (size_t)mp * 16 * 16384;
    Bg = Wkvt; np0 = (npb - 4) * 2; tstr = 8;     // np0 in {0,2,...,14}
    if (np0 < 8) { tmat = tkv;     up = k_up; dst = Khp; nOut0 = np0 * 128; }
    else         { tmat = tkv + 4; up = v_up; dst = Vhp; nOut0 = np0 * 128 - 1024; }
  }
  const int lr = l & 15, lk = l >> 4;
  const int u0 = ((lk ^ (lr & 7)) << 3);        // kk=0 frag unit (shorts)
  const int u1 = (((4 + lk) ^ (lr & 7)) << 3);  // kk=1
  const int wr = (w >> 2) * 128, wcl = (w & 3) * 64;

  f32x4 acc[8][4];
  const f32x4 zero = {0.f, 0.f, 0.f, 0.f};
#pragma unroll
  for (int m = 0; m < 8; ++m)
#pragma unroll
    for (int n = 0; n < 4; ++n) acc[m][n] = zero;

#define STG(dbuf, kt) do {                                                    \
    _Pragma("unroll") for (int j = 0; j < 4; ++j) {                           \
      const int c = j * 8 + w;                                                \
      gload16(Ag0 + (size_t)(kt) * 16384 + c * 512 + l * 8,                   \
              &lA2[dbuf][c * 512]);                                           \
      gload16(Bg + ((size_t)((np0 + (c >> 4)) * 16 + (kt)) * 8192)            \
                  + (c & 15) * 512 + l * 8,                                   \
              &lB2[dbuf][c * 512]);                                           \
    } } while (0)

  STG(0, 0);
  asm volatile("s_waitcnt vmcnt(0)" ::: "memory");
  __builtin_amdgcn_s_barrier();
  for (int kt = 0; kt < 16; ++kt) {
    const int cur = kt & 1;
    if (kt < 15) STG(cur ^ 1, kt + 1);
    const unsigned short* hA = lA2[cur];
    const unsigned short* hB = lB2[cur];
#pragma unroll
    for (int kk = 0; kk < 2; ++kk) {
      const int uu = kk ? u1 : u0;
      bf16x8 af[8], bfr[4];
#pragma unroll
      for (int m = 0; m < 8; ++m)
        af[m] = *(const bf16x8*)&hA[(wr + m * 16 + lr) * 64 + uu];
#pragma unroll
      for (int n = 0; n < 4; ++n) {
        const int nc = wcl + n * 16 + lr;
        bfr[n] = *(const bf16x8*)&hB[(nc >> 7) * 8192 + (nc & 127) * 64 + uu];
      }
      __builtin_amdgcn_s_setprio(1);
#pragma unroll
      for (int m = 0; m < 8; ++m)
#pragma unroll
        for (int n = 0; n < 4; ++n)
          acc[m][n] = __builtin_amdgcn_mfma_f32_16x16x32_bf16(
              af[m], bfr[n], acc[m][n], 0, 0, 0);
      __builtin_amdgcn_s_setprio(0);
    }
    if (kt < 15) {
      asm volatile("s_waitcnt vmcnt(0)" ::: "memory");
      __builtin_amdgcn_s_barrier();
    }
  }
#undef STG

  const int m0 = mp * 256;
#pragma unroll
  for (int n = 0; n < 4; ++n) {
    const int gcol = nOut0 + wcl + n * 16 + lr;
    const float uu0 = up[gcol], uu1 = up[1024 + gcol];
    const float uu2 = up[2048 + gcol], uu3 = up[3072 + gcol];
    const int h = gcol >> 6, d = gcol & 63;
#pragma unroll
    for (int m = 0; m < 8; ++m) {
#pragma unroll
      for (int r = 0; r < 4; ++r) {
        const int grow = m0 + wr + m * 16 + lk * 4 + r;
        const float4 tt = *reinterpret_cast<const float4*>(tmat + (size_t)grow * tstr);
        const float val = acc[m][n][r] + tt.x * uu0 + tt.y * uu1 + tt.z * uu2 + tt.w * uu3;
        const int b = grow >> 11, s = grow & 2047;
        dst[(((size_t)(b * kH + h)) * 2048 + s) * 64 + d] = f2bf(val);
      }
    }
  }
}

// Kernel 3: out = Ob @ Wot^T + bias + t_o @ o_up (f32). BM=128 BN=256,
// grid 256 = 64 mp x 4 npb = exactly 1 round. 96KB LDS.
__global__ __launch_bounds__(512, 2) void k_gemm_out(
    const unsigned short* __restrict__ Ob, const unsigned short* __restrict__ Wot,
    const float* __restrict__ tmat, const float* __restrict__ up,
    const float* __restrict__ bias, float* __restrict__ outp) {
  __shared__ unsigned short lA2[2][8192];
  __shared__ unsigned short lB2[2][16384];
  const int tid = threadIdx.x;
  const int l = tid & 63, w = tid >> 6;
  const int rid = ((int)blockIdx.x & 7) * 32 + ((int)blockIdx.x >> 3);
  const int mp = rid >> 2, npb = rid & 3;
  const unsigned short* Ag0 =
      Ob + (size_t)(mp >> 1) * 16 * 16384 + (mp & 1) * 8192;
  const int np0 = npb * 2;
  const int lr = l & 15, lk = l >> 4;
  const int u0 = ((lk ^ (lr & 7)) << 3);
  const int u1 = (((4 + lk) ^ (lr & 7)) << 3);
  const int wr = (w >> 2) * 64, wcl = (w & 3) * 64;

  f32x4 acc[4][4];
  const f32x4 zero = {0.f, 0.f, 0.f, 0.f};
#pragma unroll
  for (int m = 0; m < 4; ++m)
#pragma unroll
    for (int n = 0; n < 4; ++n) acc[m][n] = zero;

#define STG(dbuf, kt) do {                                                    \
    _Pragma("unroll") for (int j = 0; j < 2; ++j) {                           \
      const int c = j * 8 + w;                                                \
      gload16(Ag0 + (size_t)(kt) * 16384 + c * 512 + l * 8,                   \
              &lA2[dbuf][c * 512]);                                           \
    }                                                                         \
    _Pragma("unroll") for (int j = 0; j < 4; ++j) {                           \
      const int c = j * 8 + w;                                                \
      gload16(Wot + ((size_t)((np0 + (c >> 4)) * 16 + (kt)) * 8192)           \
                  + (c & 15) * 512 + l * 8,                                   \
              &lB2[dbuf][c * 512]);                                           \
    } } while (0)

  STG(0, 0);
  asm volatile("s_waitcnt vmcnt(0)" ::: "memory");
  __builtin_amdgcn_s_barrier();
  for (int kt = 0; kt < 16; ++kt) {
    const int cur = kt & 1;
    if (kt < 15) STG(cur ^ 1, kt + 1);
    const unsigned short* hA = lA2[cur];
    const unsigned short* hB = lB2[cur];
#pragma unroll
    for (int kk = 0; kk < 2; ++kk) {
      const int uu = kk ? u1 : u0;
      bf16x8 af[4], bfr[4];
#pragma unroll
      for (int m = 0; m < 4; ++m)
        af[m] = *(const bf16x8*)&hA[(wr + m * 16 + lr) * 64 + uu];
#pragma unroll
      for (int n = 0; n < 4; ++n) {
        const int nc = wcl + n * 16 + lr;
        bfr[n] = *(const bf16x8*)&hB[(nc >> 7) * 8192 + (nc & 127) * 64 + uu];
      }
      __builtin_amdgcn_s_setprio(1);
#pragma unroll
      for (int m = 0; m < 4; ++m)
#pragma unroll
        for (int n = 0; n < 4; ++n)
          acc[m][n] = __builtin_amdgcn_mfma_f32_16x16x32_bf16(
              af[m], bfr[n], acc[m][n], 0, 0, 0);
      __builtin_amdgcn_s_setprio(0);
    }
    if (kt < 15) {
      asm volatile("s_waitcnt vmcnt(0)" ::: "memory");
      __builtin_amdgcn_s_barrier();
    }
  }
#undef STG

  const int m0 = mp * 128;
#pragma unroll
  for (int n = 0; n < 4; ++n) {
    const int gcol = npb * 256 + wcl + n * 16 + lr;
    const float uu0 = up[gcol], uu1 = up[1024 + gcol];
    const float uu2 = up[2048 + gcol], uu3 = up[3072 + gcol];
    const float bz = bias[gcol];
#pragma unroll
    for (int m = 0; m < 4; ++m) {
#pragma unroll
      for (int r = 0; r < 4; ++r) {
        const int grow = m0 + wr + m * 16 + lk * 4 + r;
        const float4 tt = *reinterpret_cast<const float4*>(tmat + (size_t)grow * 4);
        outp[(size_t)grow * 1024 + gcol] =
            acc[m][n][r] + tt.x * uu0 + tt.y * uu1 + tt.z * uu2 + tt.w * uu3 + bz;
      }
    }
  }
}

// ---------------------------------------------------------------------------
// Kernel 4: V head-layout transpose: (bh, s, d) -> (bh, d, s)
__global__ __launch_bounds__(256) void k_vt(const unsigned short* __restrict__ Vh,
                                            unsigned short* __restrict__ Vt) {
  __shared__ unsigned short tile[64][65];
  const int bh = blockIdx.y;
  const int s0 = blockIdx.x * 64;
  const unsigned short* src = Vh + ((size_t)bh * kSKV + s0) * 64;
  for (int i = threadIdx.x; i < 4096; i += 256) {
    int r = i >> 6, c = i & 63;
    tile[r][c] = src[(size_t)r * 64 + c];
  }
  __syncthreads();
  unsigned short* dst = Vt + (size_t)bh * 64 * kSKV + s0;
  for (int i = threadIdx.x; i < 4096; i += 256) {
    int r = i >> 6, c = i & 63;
    dst[(size_t)r * kSKV + c] = tile[c][r];
  }
}

// ---------------------------------------------------------------------------
// Kernel 5: flash attention (round-3 structure, best measured). Output written
// in swizzled-tiled A layout for the out-GEMM.
__global__ __launch_bounds__(256) void k_attn(
    const unsigned short* __restrict__ Qh, const unsigned short* __restrict__ Kh,
    const unsigned short* __restrict__ Vt, unsigned short* __restrict__ Obf) {
  __shared__ unsigned short lK[2][4096];
  __shared__ unsigned short lV[2][4096];
  __shared__ __align__(16) unsigned short lP[4][1024];

  const int bid = blockIdx.x + 16 * blockIdx.y;              // 1024 blocks
  const int rid = (bid & 7) * 128 + (bid >> 3);
  const int q0 = (rid & 15) * 128;
  const int bh = rid >> 4;

  const int tid = threadIdx.x;
  const int l = tid & 63, w = tid >> 6;
  const int lr = l & 15, lk = l >> 4;
  const int m7 = lr & 7;
  const int lkh = lk >> 1, lkb = lk & 1;

  const unsigned short* Qb = Qh + (size_t)bh * kSQ * 64;
  const unsigned short* Kb = Kh + (size_t)bh * kSKV * 64;
  const unsigned short* Vb = Vt + (size_t)bh * 64 * kSKV;

  const float QS = 0.125f * 1.4426950408889634f;
  bf16x8 qf[2][2];
#pragma unroll
  for (int m = 0; m < 2; ++m)
#pragma unroll
    for (int kk = 0; kk < 2; ++kk) {
      bf16x8 v = *(const bf16x8*)
          &Qb[(size_t)(q0 + w * 32 + m * 16 + lr) * 64 + kk * 32 + lk * 8];
#pragma unroll
      for (int j = 0; j < 8; ++j) {
        unsigned short u = (unsigned short)v[j];
        v[j] = (short)f2bf(bf2f(u) * QS);
      }
      qf[m][kk] = v;
    }

  f32x4 oacc[2][4];
  const f32x4 zero = {0.f, 0.f, 0.f, 0.f};
#pragma unroll
  for (int m = 0; m < 2; ++m)
#pragma unroll
    for (int n = 0; n < 4; ++n) oacc[m][n] = zero;
  float lrow[2] = {0.f, 0.f};

  const int sr8 = l >> 3;
  const int su = (l & 7) ^ sr8;
  unsigned short* lPw = lP[w];

#define ASTAGE(dbuf, tile) do { \
    _Pragma("unroll") for (int cc = 0; cc < 2; ++cc) { \
      const int c = 2 * w + cc; const int row = c * 8 + sr8; \
      gload16(Kb + (size_t)((tile) * 64 + row) * 64 + su * 8, &lK[dbuf][c * 512]); \
      gload16(Vb + (size_t)row * kSKV + (tile) * 64 + su * 8, &lV[dbuf][c * 512]); \
    } } while (0)

  ASTAGE(0, 0);
  __syncthreads();

#pragma unroll 2
  for (int kt = 0; kt < 32; ++kt) {
    const int cur = kt & 1;
    if (kt < 31) ASTAGE(cur ^ 1, kt + 1);
    const unsigned short* bufK = lK[cur];
    const unsigned short* bufV = lV[cur];

    bf16x8 kf[4][2];
#pragma unroll
    for (int n = 0; n < 4; ++n)
#pragma unroll
      for (int kk = 0; kk < 2; ++kk) {
        const int ub = (kk * 4 + lk) ^ m7;
        kf[n][kk] = *(const bf16x8*)&bufK[(n * 16 + lr) * 64 + ub * 8];
      }

    f32x4 s0[4];
#pragma unroll
    for (int n = 0; n < 4; ++n) s0[n] = zero;
    __builtin_amdgcn_s_setprio(1);
#pragma unroll
    for (int kk = 0; kk < 2; ++kk)
#pragma unroll
      for (int n = 0; n < 4; ++n)
        s0[n] = __builtin_amdgcn_mfma_f32_16x16x32_bf16(kf[n][kk], qf[0][kk],
                                                        s0[n], 0, 0, 0);
    __builtin_amdgcn_s_setprio(0);
    float ls0 = 0.f;
#pragma unroll
    for (int n = 0; n < 4; ++n) {
      const float p0 = vexp2(s0[n][0]);
      const float p1 = vexp2(s0[n][1]);
      const float p2 = vexp2(s0[n][2]);
      const float p3 = vexp2(s0[n][3]);
      ls0 += (p0 + p1) + (p2 + p3);
      uint2 pv; pv.x = cvtpk(p0, p1); pv.y = cvtpk(p2, p3);
      *(uint2*)&lPw[lr * 64 + (((2 * n + lkh) ^ m7) << 3) + lkb * 4] = pv;
    }
    lrow[0] += ls0;

    f32x4 s1[4];
#pragma unroll
    for (int n = 0; n < 4; ++n) s1[n] = zero;
    __builtin_amdgcn_s_setprio(1);
#pragma unroll
    for (int kk = 0; kk < 2; ++kk)
#pragma unroll
      for (int n = 0; n < 4; ++n)
        s1[n] = __builtin_amdgcn_mfma_f32_16x16x32_bf16(kf[n][kk], qf[1][kk],
                                                        s1[n], 0, 0, 0);
    __builtin_amdgcn_s_setprio(0);
    float ls1 = 0.f;
    uint2 pw1[4];
#pragma unroll
    for (int n = 0; n < 4; ++n) {
      const float p0 = vexp2(s1[n][0]);
      const float p1 = vexp2(s1[n][1]);
      const float p2 = vexp2(s1[n][2]);
      const float p3 = vexp2(s1[n][3]);
      ls1 += (p0 + p1) + (p2 + p3);
      pw1[n].x = cvtpk(p0, p1); pw1[n].y = cvtpk(p2, p3);
    }
    lrow[1] += ls1;

    bf16x8 pf0[2], pf1[2];
#pragma unroll
    for (int kk = 0; kk < 2; ++kk)
      pf0[kk] = *(const bf16x8*)&lPw[lr * 64 + (((kk * 4 + lk) ^ m7) << 3)];
#pragma unroll
    for (int n = 0; n < 4; ++n)
      *(uint2*)&lPw[lr * 64 + (((2 * n + lkh) ^ m7) << 3) + lkb * 4] = pw1[n];
#pragma unroll
    for (int kk = 0; kk < 2; ++kk)
      pf1[kk] = *(const bf16x8*)&lPw[lr * 64 + (((kk * 4 + lk) ^ m7) << 3)];

    __builtin_amdgcn_s_setprio(1);
#pragma unroll
    for (int n = 0; n < 4; ++n)
#pragma unroll
      for (int kk = 0; kk < 2; ++kk) {
        const int ub = (kk * 4 + lk) ^ m7;
        bf16x8 vf = *(const bf16x8*)&bufV[(n * 16 + lr) * 64 + ub * 8];
        oacc[0][n] = __builtin_amdgcn_mfma_f32_16x16x32_bf16(pf0[kk], vf,
                                                             oacc[0][n], 0, 0, 0);
        oacc[1][n] = __builtin_amdgcn_mfma_f32_16x16x32_bf16(pf1[kk], vf,
                                                             oacc[1][n], 0, 0, 0);
      }
    __builtin_amdgcn_s_setprio(0);

    __syncthreads();
  }
#undef ASTAGE

  float rinv[2][4];
#pragma unroll
  for (int m = 0; m < 2; ++m) {
    float s = lrow[m];
    s += __shfl_xor(s, 16);
    s += __shfl_xor(s, 32);
#pragma unroll
    for (int r = 0; r < 4; ++r) rinv[m][r] = 1.0f / __shfl(s, lk * 4 + r);
  }

  const int b = bh >> 4, h = bh & 15;
#pragma unroll
  for (int m = 0; m < 2; ++m)
#pragma unroll
    for (int n = 0; n < 4; ++n)
#pragma unroll
      for (int r = 0; r < 4; ++r) {
        const int qrow = q0 + w * 32 + m * 16 + lk * 4 + r;
        const int grow = b * kSQ + qrow;
        const int p = grow >> 8, rA = grow & 255;
        const int u = (n * 2 + (lr >> 3)) ^ (rA & 7);
        Obf[(((size_t)p * 16 + h) * 256 + rA) * 64 + u * 8 + (lr & 7)] =
            f2bf(oacc[m][n][r] * rinv[m][r]);
      }
}

// ---------------------------------------------------------------------------
// Kernel 6: t_o = O(bf16, swizzled-tiled) @ out_lora_down
__global__ __launch_bounds__(256) void k_tdown(const unsigned short* __restrict__ Ob,
                                               const float* __restrict__ dn,
                                               float* __restrict__ t_o) {
  const int row = blockIdx.x;
  const int tid = threadIdx.x;
  const int p = row >> 8, r = row & 255;
  const int kt = tid >> 4, us = (tid >> 1) & 7, e = (tid & 1) * 4;
  const int u = us ^ (r & 7);
  short4 v4 = *reinterpret_cast<const short4*>(
      &Ob[(((size_t)p * 16 + kt) * 256 + r) * 64 + u * 8 + e]);
  short vs[4] = {v4.x, v4.y, v4.z, v4.w};
  float a[4] = {0.f, 0.f, 0.f, 0.f};
#pragma unroll
  for (int e2 = 0; e2 < 4; ++e2) {
    const float x = bf2f((unsigned short)vs[e2]);
    const float* dr = dn + (size_t)(tid * 4 + e2) * 4;
    a[0] += x * dr[0]; a[1] += x * dr[1]; a[2] += x * dr[2]; a[3] += x * dr[3];
  }
  __shared__ float red[4][4];
  const int l = tid & 63, w = tid >> 6;
#pragma unroll
  for (int k2 = 0; k2 < 4; ++k2) {
    float v = a[k2];
#pragma unroll
    for (int m = 1; m < 64; m <<= 1) v += __shfl_xor(v, m);
    if (l == 0) red[w][k2] = v;
  }
  __syncthreads();
  if (tid < 4)
    t_o[(size_t)row * 4 + tid] = red[0][tid] + red[1][tid] + red[2][tid] + red[3][tid];
}

// ---------------------------------------------------------------------------
extern "C" void kernel_launch(void* const* d_in, const int* in_sizes, int n_in,
                              void* d_out, int out_size, void* d_ws, size_t ws_size,
                              hipStream_t stream) {
  (void)in_sizes; (void)n_in; (void)out_size; (void)ws_size;
  const float* hs   = (const float*)d_in[0];
  const float* enc  = (const float*)d_in[1];
  const float* Wq   = (const float*)d_in[2];
  const float* Wk   = (const float*)d_in[3];
  const float* Wv   = (const float*)d_in[4];
  const float* Wo   = (const float*)d_in[5];
  const float* bo   = (const float*)d_in[6];
  const float* q_dn = (const float*)d_in[7];
  const float* q_up = (const float*)d_in[8];
  const float* k_dn = (const float*)d_in[9];
  const float* k_up = (const float*)d_in[10];
  const float* v_dn = (const float*)d_in[11];
  const float* v_up = (const float*)d_in[12];
  const float* o_dn = (const float*)d_in[13];
  const float* o_up = (const float*)d_in[14];

  char* ws = (char*)d_ws;
  size_t off = 0;
  auto alloc = [&](size_t bytes) -> void* {
    void* p = ws + off;
    off += (bytes + 255) & ~(size_t)255;
    return p;
  };
  const size_t ACT = (size_t)kM * kD * 2;
  unsigned short* hsb  = (unsigned short*)alloc(ACT);
  unsigned short* encb = (unsigned short*)alloc(ACT);
  unsigned short* Wqt  = (unsigned short*)alloc((size_t)1024 * 1024 * 2);
  unsigned short* Wkvt = (unsigned short*)alloc((size_t)2048 * 1024 * 2);
  unsigned short* Wot  = (unsigned short*)alloc((size_t)1024 * 1024 * 2);
  unsigned short* Qhp  = (unsigned short*)alloc(ACT);
  unsigned short* Khp  = (unsigned short*)alloc(ACT);
  unsigned short* Vhp  = (unsigned short*)alloc(ACT);
  float* tq  = (float*)alloc((size_t)kM * 4 * 4);
  float* tkv = (float*)alloc((size_t)kM * 8 * 4);
  float* to  = (float*)alloc((size_t)kM * 4 * 4);
  unsigned short* Vtt = hsb;   // alias: V^T reuses hidden bf16 buffer
  unsigned short* Ob  = encb;  // alias: attention O reuses encoder bf16 buffer

  k_prep_wt<<<dim3(2 * kM + 1024), dim3(256), 0, stream>>>(
      hs, enc, q_dn, k_dn, v_dn, Wq, Wk, Wv, Wo,
      hsb, encb, tq, tkv, Wqt, Wkvt, Wot);

  k_gemm_qkv<<<dim3(384), dim3(512), 0, stream>>>(
      hsb, encb, Wqt, Wkvt, tq, tkv, q_up, k_up, v_up, Qhp, Khp, Vhp);

  k_vt<<<dim3(32, 64), dim3(256), 0, stream>>>(Vhp, Vtt);
  k_attn<<<dim3(16, 64), dim3(256), 0, stream>>>(Qhp, Khp, Vtt, Ob);
  k_tdown<<<dim3(kM), dim3(256), 0, stream>>>(Ob, o_dn, to);

  k_gemm_out<<<dim3(256), dim3(512), 0, stream>>>(Ob, Wot, to, o_up, bo,
                                                  (float*)d_out);
}

// Round 11
// 324.497 us; speedup vs baseline: 1.3031x; 1.3031x over previous
//
#include <hip/hip_runtime.h>
#include <hip/hip_bf16.h>

typedef __attribute__((ext_vector_type(8))) short bf16x8;
typedef __attribute__((ext_vector_type(4))) float f32x4;

#define DEVFN static __device__ __forceinline__

constexpr int kSQ = 2048, kSKV = 2048, kD = 1024, kH = 16;
constexpr int kM = 4 * kSQ;   // 8192 query rows (B*SQ)

DEVFN unsigned short f2bf(float f) {
  union { float f; unsigned u; } v; v.f = f;
  unsigned r = v.u + 0x7FFFu + ((v.u >> 16) & 1u);
  return (unsigned short)(r >> 16);
}
DEVFN float bf2f(unsigned short h) {
  union { unsigned u; float f; } v; v.u = ((unsigned)h) << 16; return v.f;
}
DEVFN unsigned cvtpk(float lo, float hi) {
  unsigned r;
  asm("v_cvt_pk_bf16_f32 %0, %1, %2" : "=v"(r) : "v"(lo), "v"(hi));
  return r;
}
DEVFN float vexp2(float x) {
  float r;
  asm("v_exp_f32 %0, %1" : "=v"(r) : "v"(x));
  return r;
}

DEVFN void gload16(const void* g, void* l) {
  __builtin_amdgcn_global_load_lds(
      (const __attribute__((address_space(1))) unsigned int*)g,
      (__attribute__((address_space(3))) unsigned int*)l, 16, 0, 0);
}

#define WT12 asm volatile("s_waitcnt vmcnt(12)" ::: "memory")
#define WT6  asm volatile("s_waitcnt vmcnt(6)" ::: "memory")
#define WT0  asm volatile("s_waitcnt vmcnt(0)" ::: "memory")

// ---------------------------------------------------------------------------
// Kernel 1 (merged): blocks [0, 2*kM): activation fp32->bf16 + LoRA-down dots.
// blocks [2*kM, 2*kM+1024): weight convert+transpose (4 weights x 256 tiles).
__global__ __launch_bounds__(256) void k_prep_wt(
    const float* __restrict__ hs, const float* __restrict__ enc,
    const float* __restrict__ qdn, const float* __restrict__ kdn,
    const float* __restrict__ vdn,
    const float* __restrict__ Wq, const float* __restrict__ Wk,
    const float* __restrict__ Wv, const float* __restrict__ Wo,
    unsigned short* __restrict__ hsb, unsigned short* __restrict__ encb,
    float* __restrict__ tq, float* __restrict__ tkv,
    unsigned short* __restrict__ Wqt, unsigned short* __restrict__ Wkvt,
    unsigned short* __restrict__ Wot) {
  __shared__ float red[4][8];
  __shared__ unsigned short tile[64][65];
  const int bid = blockIdx.x;
  const int tid = threadIdx.x;

  if (bid < 2 * kM) {
    const bool isH = bid < kM;
    const int rr = isH ? bid : bid - kM;
    const float* srcRow = (isH ? hs : enc) + (size_t)rr * kD;
    unsigned short* dstRow = (isH ? hsb : encb) + (size_t)rr * kD;

    float4 x = reinterpret_cast<const float4*>(srcRow)[tid];
    short4 o;
    o.x = (short)f2bf(x.x); o.y = (short)f2bf(x.y);
    o.z = (short)f2bf(x.z); o.w = (short)f2bf(x.w);
    *reinterpret_cast<short4*>(dstRow + tid * 4) = o;

    float xs[4] = {x.x, x.y, x.z, x.w};
    float a[4] = {0.f, 0.f, 0.f, 0.f};
    float bacc[4] = {0.f, 0.f, 0.f, 0.f};
    const float* dnA = isH ? qdn : kdn;
    const int base = tid * 4;
#pragma unroll
    for (int e = 0; e < 4; ++e) {
      const float* dr = dnA + (size_t)(base + e) * 4;
      a[0] += xs[e] * dr[0]; a[1] += xs[e] * dr[1];
      a[2] += xs[e] * dr[2]; a[3] += xs[e] * dr[3];
    }
    if (!isH) {
#pragma unroll
      for (int e = 0; e < 4; ++e) {
        const float* dr = vdn + (size_t)(base + e) * 4;
        bacc[0] += xs[e] * dr[0]; bacc[1] += xs[e] * dr[1];
        bacc[2] += xs[e] * dr[2]; bacc[3] += xs[e] * dr[3];
      }
    }
    const int l = tid & 63, w = tid >> 6;
    float vals[8] = {a[0], a[1], a[2], a[3], bacc[0], bacc[1], bacc[2], bacc[3]};
#pragma unroll
    for (int k2 = 0; k2 < 8; ++k2) {
      float v = vals[k2];
#pragma unroll
      for (int m = 1; m < 64; m <<= 1) v += __shfl_xor(v, m);
      if (l == 0) red[w][k2] = v;
    }
    __syncthreads();
    if (tid < 8) {
      float s = red[0][tid] + red[1][tid] + red[2][tid] + red[3][tid];
      if (isH) {
        if (tid < 4) tq[(size_t)rr * 4 + tid] = s;
      } else {
        tkv[(size_t)rr * 8 + tid] = s;   // 0..3 = k-down, 4..7 = v-down
      }
    }
  } else {
    const int t = bid - 2 * kM;
    const int wid = t >> 8, tt = t & 255;
    const float* W = (wid == 0) ? Wq : (wid == 1) ? Wk : (wid == 2) ? Wv : Wo;
    unsigned short* Wt = (wid == 0) ? Wqt : (wid == 1) ? Wkvt
                        : (wid == 2) ? (Wkvt + (size_t)1024 * 1024) : Wot;
    const int tk0 = (tt & 15) * 64;
    const int tn0 = (tt >> 4) * 64;
    for (int i = tid; i < 4096; i += 256) {
      int r = i >> 6, c = i & 63;
      tile[r][c] = f2bf(W[(size_t)(tk0 + r) * 1024 + tn0 + c]);
    }
    __syncthreads();
    for (int i = tid; i < 4096; i += 256) {
      int r = i >> 6, c = i & 63;
      Wt[(size_t)(tn0 + r) * 1024 + tk0 + c] = tile[c][r];
    }
  }
}

// ---------------------------------------------------------------------------
// Big-tile GEMM core: BM=256, BN=128, BK=64, 8 waves (512 thr), 144KB LDS
// TRIPLE-buffer, counted vmcnt 3-deep pipeline (~15 loads in flight/wave),
// T2 XOR swizzle via pre-swizzled global source + swizzled ds_read.

// stage A-tile (256x64) + B-tile (128x64) for K-step kt into buffer dbuf.
// 6 gload16 per thread per stage (A:4, B:2).
#define GSTAGE(dbuf, kt) do {                                                 \
    _Pragma("unroll")                                                         \
    for (int j = 0; j < 4; ++j) {                                             \
      const int s = (j * 8 + w) * 64 + l;                                     \
      const int row = s >> 3, u = s & 7;                                      \
      gload16(Ap + (size_t)row * 1024 + (kt) * 64 + ((u ^ (row & 7)) * 8),    \
              &lA[dbuf][(j * 8 + w) * 512]);                                  \
    }                                                                         \
    _Pragma("unroll")                                                         \
    for (int j = 0; j < 2; ++j) {                                             \
      const int s = (j * 8 + w) * 64 + l;                                     \
      const int row = s >> 3, u = s & 7;                                      \
      gload16(Bp + (size_t)row * 1024 + (kt) * 64 + ((u ^ (row & 7)) * 8),    \
              &lB[dbuf][(j * 8 + w) * 512]);                                  \
    } } while (0)

#define BIG_GEMM_LOOP()                                                       \
  GSTAGE(0, 0);                                                               \
  GSTAGE(1, 1);                                                               \
  GSTAGE(2, 2);                                                               \
  _Pragma("unroll")                                                           \
  for (int kt = 0; kt < 16; ++kt) {                                           \
    const int cur = kt % 3;                                                   \
    if (kt <= 13) { WT12; } else if (kt == 14) { WT6; } else { WT0; }         \
    __builtin_amdgcn_s_barrier();                                             \
    asm volatile("" ::: "memory");                                            \
    _Pragma("unroll")                                                         \
    for (int kk = 0; kk < 2; ++kk) {                                          \
      bf16x8 af[8], bfr[2];                                                   \
      _Pragma("unroll")                                                       \
      for (int m = 0; m < 8; ++m) {                                           \
        const int ar = wr + m * 16 + lr;                                      \
        af[m] = *(const bf16x8*)&lA[cur][ar * 64 +                            \
                 (((kk * 4 + lk) ^ (ar & 7)) * 8)];                           \
      }                                                                       \
      _Pragma("unroll")                                                       \
      for (int n = 0; n < 2; ++n) {                                           \
        const int br = wc + n * 16 + lr;                                      \
        bfr[n] = *(const bf16x8*)&lB[cur][br * 64 +                           \
                 (((kk * 4 + lk) ^ (br & 7)) * 8)];                           \
      }                                                                       \
      __builtin_amdgcn_s_setprio(1);                                          \
      _Pragma("unroll")                                                       \
      for (int m = 0; m < 8; ++m)                                             \
        _Pragma("unroll")                                                     \
        for (int n = 0; n < 2; ++n)                                           \
          acc[m][n] = __builtin_amdgcn_mfma_f32_16x16x32_bf16(                \
              af[m], bfr[n], acc[m][n], 0, 0, 0);                             \
      __builtin_amdgcn_s_setprio(0);                                          \
    }                                                                         \
    asm volatile("s_waitcnt lgkmcnt(0)" ::: "memory");                        \
    __builtin_amdgcn_s_barrier();                                             \
    asm volatile("" ::: "memory");                                            \
    if (kt < 13) GSTAGE(cur, kt + 3);                                         \
  }

// Kernel 2: QKV projection. blocks [0,256): Q (N=1024); [256,768): K|V (N=2048,
// A=encb shared). XCD-swizzled within each segment.
__global__ __launch_bounds__(512, 2) void k_gemm_qkv(
    const unsigned short* __restrict__ hsb, const unsigned short* __restrict__ encb,
    const unsigned short* __restrict__ Wqt, const unsigned short* __restrict__ Wkvt,
    const float* __restrict__ tq, const float* __restrict__ tkv,
    const float* __restrict__ q_up, const float* __restrict__ k_up,
    const float* __restrict__ v_up,
    unsigned short* __restrict__ Qhp, unsigned short* __restrict__ Khp,
    unsigned short* __restrict__ Vhp) {
  __shared__ unsigned short lA[3][256 * 64];
  __shared__ unsigned short lB[3][128 * 64];
  const int tid = threadIdx.x;
  const int l = tid & 63, w = tid >> 6;
  const int bid = blockIdx.x;

  const unsigned short *A, *Bt;
  const float *tmat, *up;
  unsigned short* dst;
  int m0, nB0, nOut0, tstr;
  if (bid < 256) {
    const int rid = (bid & 7) * 32 + (bid >> 3);
    m0 = (rid >> 3) * 256; nB0 = (rid & 7) * 128;
    A = hsb; Bt = Wqt; tmat = tq; tstr = 4; up = q_up; dst = Qhp; nOut0 = nB0;
  } else {
    const int b2 = bid - 256;
    const int rid = (b2 & 7) * 64 + (b2 >> 3);
    m0 = (rid >> 4) * 256; nB0 = (rid & 15) * 128;
    A = encb; Bt = Wkvt; tstr = 8;
    if (nB0 < 1024) { tmat = tkv;     up = k_up; dst = Khp; nOut0 = nB0; }
    else            { tmat = tkv + 4; up = v_up; dst = Vhp; nOut0 = nB0 - 1024; }
  }
  const int wr = (w >> 2) * 128, wc = (w & 3) * 32;
  const int lr = l & 15, lk = l >> 4;
  const unsigned short* Ap = A  + (size_t)m0  * 1024;
  const unsigned short* Bp = Bt + (size_t)nB0 * 1024;

  f32x4 acc[8][2];
  const f32x4 zero = {0.f, 0.f, 0.f, 0.f};
#pragma unroll
  for (int m = 0; m < 8; ++m)
#pragma unroll
    for (int n = 0; n < 2; ++n) acc[m][n] = zero;

  BIG_GEMM_LOOP()

#pragma unroll
  for (int n = 0; n < 2; ++n) {
    const int gcol = nOut0 + wc + n * 16 + lr;
    const float u0 = up[gcol], u1 = up[1024 + gcol];
    const float u2 = up[2048 + gcol], u3 = up[3072 + gcol];
    const int h = gcol >> 6, d = gcol & 63;
#pragma unroll
    for (int m = 0; m < 8; ++m) {
#pragma unroll
      for (int r = 0; r < 4; ++r) {
        const int grow = m0 + wr + m * 16 + lk * 4 + r;
        const float4 tt = *reinterpret_cast<const float4*>(tmat + (size_t)grow * tstr);
        const float val = acc[m][n][r] + tt.x * u0 + tt.y * u1 + tt.z * u2 + tt.w * u3;
        const int b = grow >> 11, s = grow & 2047;
        dst[(((size_t)(b * kH + h)) * 2048 + s) * 64 + d] = f2bf(val);
      }
    }
  }
}

// Kernel 3: final GEMM  out = Ob @ Wot^T + bias + t_o @ o_up  (f32 output)
__global__ __launch_bounds__(512, 2) void k_gemm_out(
    const unsigned short* __restrict__ A, const unsigned short* __restrict__ Bt,
    const float* __restrict__ tmat, const float* __restrict__ up,
    const float* __restrict__ bias, float* __restrict__ outp) {
  __shared__ unsigned short lA[3][256 * 64];
  __shared__ unsigned short lB[3][128 * 64];
  const int tid = threadIdx.x;
  const int l = tid & 63, w = tid >> 6;
  const int bid = blockIdx.x;
  const int rid = (bid & 7) * 32 + (bid >> 3);
  const int m0 = (rid >> 3) * 256, nB0 = (rid & 7) * 128;
  const int wr = (w >> 2) * 128, wc = (w & 3) * 32;
  const int lr = l & 15, lk = l >> 4;
  const unsigned short* Ap = A  + (size_t)m0  * 1024;
  const unsigned short* Bp = Bt + (size_t)nB0 * 1024;

  f32x4 acc[8][2];
  const f32x4 zero = {0.f, 0.f, 0.f, 0.f};
#pragma unroll
  for (int m = 0; m < 8; ++m)
#pragma unroll
    for (int n = 0; n < 2; ++n) acc[m][n] = zero;

  BIG_GEMM_LOOP()

#pragma unroll
  for (int n = 0; n < 2; ++n) {
    const int gcol = nB0 + wc + n * 16 + lr;
    const float u0 = up[gcol], u1 = up[1024 + gcol];
    const float u2 = up[2048 + gcol], u3 = up[3072 + gcol];
    const float bz = bias[gcol];
#pragma unroll
    for (int m = 0; m < 8; ++m) {
#pragma unroll
      for (int r = 0; r < 4; ++r) {
        const int grow = m0 + wr + m * 16 + lk * 4 + r;
        const float4 tt = *reinterpret_cast<const float4*>(tmat + (size_t)grow * 4);
        outp[(size_t)grow * 1024 + gcol] =
            acc[m][n][r] + tt.x * u0 + tt.y * u1 + tt.z * u2 + tt.w * u3 + bz;
      }
    }
  }
}

// ---------------------------------------------------------------------------
// Kernel 4: V head-layout transpose: (bh, s, d) -> (bh, d, s)
__global__ __launch_bounds__(256) void k_vt(const unsigned short* __restrict__ Vh,
                                            unsigned short* __restrict__ Vt) {
  __shared__ unsigned short tile[64][65];
  const int bh = blockIdx.y;
  const int s0 = blockIdx.x * 64;
  const unsigned short* src = Vh + ((size_t)bh * kSKV + s0) * 64;
  for (int i = threadIdx.x; i < 4096; i += 256) {
    int r = i >> 6, c = i & 63;
    tile[r][c] = src[(size_t)r * 64 + c];
  }
  __syncthreads();
  unsigned short* dst = Vt + (size_t)bh * 64 * kSKV + s0;
  for (int i = threadIdx.x; i < 4096; i += 256) {
    int r = i >> 6, c = i & 63;
    dst[(size_t)r * kSKV + c] = tile[c][r];
  }
}

// ---------------------------------------------------------------------------
// Kernel 5: flash attention, QBLK=128 (4 waves x 32 q-rows), KV tiles of 64.
// Fixed-max softmax via exp2 (Q pre-scaled by log2e/8). Conflict-free
// 16B-unit XOR swizzle on K/V/P. (round-3 structure: dbuf + syncthreads)
__global__ __launch_bounds__(256) void k_attn(
    const unsigned short* __restrict__ Qh, const unsigned short* __restrict__ Kh,
    const unsigned short* __restrict__ Vt, unsigned short* __restrict__ Obf) {
  __shared__ unsigned short lK[2][4096];
  __shared__ unsigned short lV[2][4096];
  __shared__ __align__(16) unsigned short lP[4][1024];

  const int bid = blockIdx.x + 16 * blockIdx.y;              // 1024 blocks
  const int rid = (bid & 7) * 128 + (bid >> 3);
  const int q0 = (rid & 15) * 128;
  const int bh = rid >> 4;

  const int tid = threadIdx.x;
  const int l = tid & 63, w = tid >> 6;
  const int lr = l & 15, lk = l >> 4;
  const int m7 = lr & 7;
  const int lkh = lk >> 1, lkb = lk & 1;

  const unsigned short* Qb = Qh + (size_t)bh * kSQ * 64;
  const unsigned short* Kb = Kh + (size_t)bh * kSKV * 64;
  const unsigned short* Vb = Vt + (size_t)bh * 64 * kSKV;

  const float QS = 0.125f * 1.4426950408889634f;
  bf16x8 qf[2][2];
#pragma unroll
  for (int m = 0; m < 2; ++m)
#pragma unroll
    for (int kk = 0; kk < 2; ++kk) {
      bf16x8 v = *(const bf16x8*)
          &Qb[(size_t)(q0 + w * 32 + m * 16 + lr) * 64 + kk * 32 + lk * 8];
#pragma unroll
      for (int j = 0; j < 8; ++j) {
        unsigned short u = (unsigned short)v[j];
        v[j] = (short)f2bf(bf2f(u) * QS);
      }
      qf[m][kk] = v;
    }

  f32x4 oacc[2][4];
  const f32x4 zero = {0.f, 0.f, 0.f, 0.f};
#pragma unroll
  for (int m = 0; m < 2; ++m)
#pragma unroll
    for (int n = 0; n < 4; ++n) oacc[m][n] = zero;
  float lrow[2] = {0.f, 0.f};

  const int sr8 = l >> 3;
  const int su = (l & 7) ^ sr8;
  unsigned short* lPw = lP[w];

#define ASTAGE(dbuf, tile) do { \
    _Pragma("unroll") for (int cc = 0; cc < 2; ++cc) { \
      const int c = 2 * w + cc; const int row = c * 8 + sr8; \
      gload16(Kb + (size_t)((tile) * 64 + row) * 64 + su * 8, &lK[dbuf][c * 512]); \
      gload16(Vb + (size_t)row * kSKV + (tile) * 64 + su * 8, &lV[dbuf][c * 512]); \
    } } while (0)

  ASTAGE(0, 0);
  __syncthreads();

#pragma unroll 2
  for (int kt = 0; kt < 32; ++kt) {
    const int cur = kt & 1;
    if (kt < 31) ASTAGE(cur ^ 1, kt + 1);
    const unsigned short* bufK = lK[cur];
    const unsigned short* bufV = lV[cur];

    bf16x8 kf[4][2];
#pragma unroll
    for (int n = 0; n < 4; ++n)
#pragma unroll
      for (int kk = 0; kk < 2; ++kk) {
        const int ub = (kk * 4 + lk) ^ m7;
        kf[n][kk] = *(const bf16x8*)&bufK[(n * 16 + lr) * 64 + ub * 8];
      }

    f32x4 s0[4];
#pragma unroll
    for (int n = 0; n < 4; ++n) s0[n] = zero;
    __builtin_amdgcn_s_setprio(1);
#pragma unroll
    for (int kk = 0; kk < 2; ++kk)
#pragma unroll
      for (int n = 0; n < 4; ++n)
        s0[n] = __builtin_amdgcn_mfma_f32_16x16x32_bf16(kf[n][kk], qf[0][kk],
                                                        s0[n], 0, 0, 0);
    __builtin_amdgcn_s_setprio(0);
    float ls0 = 0.f;
#pragma unroll
    for (int n = 0; n < 4; ++n) {
      const float p0 = vexp2(s0[n][0]);
      const float p1 = vexp2(s0[n][1]);
      const float p2 = vexp2(s0[n][2]);
      const float p3 = vexp2(s0[n][3]);
      ls0 += (p0 + p1) + (p2 + p3);
      uint2 pv; pv.x = cvtpk(p0, p1); pv.y = cvtpk(p2, p3);
      *(uint2*)&lPw[lr * 64 + (((2 * n + lkh) ^ m7) << 3) + lkb * 4] = pv;
    }
    lrow[0] += ls0;

    f32x4 s1[4];
#pragma unroll
    for (int n = 0; n < 4; ++n) s1[n] = zero;
    __builtin_amdgcn_s_setprio(1);
#pragma unroll
    for (int kk = 0; kk < 2; ++kk)
#pragma unroll
      for (int n = 0; n < 4; ++n)
        s1[n] = __builtin_amdgcn_mfma_f32_16x16x32_bf16(kf[n][kk], qf[1][kk],
                                                        s1[n], 0, 0, 0);
    __builtin_amdgcn_s_setprio(0);
    float ls1 = 0.f;
    uint2 pw1[4];
#pragma unroll
    for (int n = 0; n < 4; ++n) {
      const float p0 = vexp2(s1[n][0]);
      const float p1 = vexp2(s1[n][1]);
      const float p2 = vexp2(s1[n][2]);
      const float p3 = vexp2(s1[n][3]);
      ls1 += (p0 + p1) + (p2 + p3);
      pw1[n].x = cvtpk(p0, p1); pw1[n].y = cvtpk(p2, p3);
    }
    lrow[1] += ls1;

    bf16x8 pf0[2], pf1[2];
#pragma unroll
    for (int kk = 0; kk < 2; ++kk)
      pf0[kk] = *(const bf16x8*)&lPw[lr * 64 + (((kk * 4 + lk) ^ m7) << 3)];
#pragma unroll
    for (int n = 0; n < 4; ++n)
      *(uint2*)&lPw[lr * 64 + (((2 * n + lkh) ^ m7) << 3) + lkb * 4] = pw1[n];
#pragma unroll
    for (int kk = 0; kk < 2; ++kk)
      pf1[kk] = *(const bf16x8*)&lPw[lr * 64 + (((kk * 4 + lk) ^ m7) << 3)];

    __builtin_amdgcn_s_setprio(1);
#pragma unroll
    for (int n = 0; n < 4; ++n)
#pragma unroll
      for (int kk = 0; kk < 2; ++kk) {
        const int ub = (kk * 4 + lk) ^ m7;
        bf16x8 vf = *(const bf16x8*)&bufV[(n * 16 + lr) * 64 + ub * 8];
        oacc[0][n] = __builtin_amdgcn_mfma_f32_16x16x32_bf16(pf0[kk], vf,
                                                             oacc[0][n], 0, 0, 0);
        oacc[1][n] = __builtin_amdgcn_mfma_f32_16x16x32_bf16(pf1[kk], vf,
                                                             oacc[1][n], 0, 0, 0);
      }
    __builtin_amdgcn_s_setprio(0);

    __syncthreads();
  }
#undef ASTAGE

  float rinv[2][4];
#pragma unroll
  for (int m = 0; m < 2; ++m) {
    float s = lrow[m];
    s += __shfl_xor(s, 16);
    s += __shfl_xor(s, 32);
#pragma unroll
    for (int r = 0; r < 4; ++r) rinv[m][r] = 1.0f / __shfl(s, lk * 4 + r);
  }

  const int b = bh >> 4, h = bh & 15;
#pragma unroll
  for (int m = 0; m < 2; ++m)
#pragma unroll
    for (int n = 0; n < 4; ++n)
#pragma unroll
      for (int r = 0; r < 4; ++r) {
        const int qrow = q0 + w * 32 + m * 16 + lk * 4 + r;
        const int d = n * 16 + lr;
        Obf[((size_t)b * kSQ + qrow) * kD + h * 64 + d] =
            f2bf(oacc[m][n][r] * rinv[m][r]);
      }
}

// ---------------------------------------------------------------------------
// Kernel 6: t_o = O(bf16) @ out_lora_down
__global__ __launch_bounds__(256) void k_tdown(const unsigned short* __restrict__ Ob,
                                               const float* __restrict__ dn,
                                               float* __restrict__ t_o) {
  const int row = blockIdx.x;
  const int tid = threadIdx.x;
  const unsigned short* src = Ob + (size_t)row * kD;
  short4 v4 = *reinterpret_cast<const short4*>(&src[tid * 4]);
  short vs[4] = {v4.x, v4.y, v4.z, v4.w};
  float a[4] = {0.f, 0.f, 0.f, 0.f};
#pragma unroll
  for (int e = 0; e < 4; ++e) {
    const float x = bf2f((unsigned short)vs[e]);
    const float* dr = dn + (size_t)(tid * 4 + e) * 4;
    a[0] += x * dr[0]; a[1] += x * dr[1]; a[2] += x * dr[2]; a[3] += x * dr[3];
  }
  __shared__ float red[4][4];
  const int l = tid & 63, w = tid >> 6;
#pragma unroll
  for (int k2 = 0; k2 < 4; ++k2) {
    float v = a[k2];
#pragma unroll
    for (int m = 1; m < 64; m <<= 1) v += __shfl_xor(v, m);
    if (l == 0) red[w][k2] = v;
  }
  __syncthreads();
  if (tid < 4)
    t_o[(size_t)row * 4 + tid] = red[0][tid] + red[1][tid] + red[2][tid] + red[3][tid];
}

// ---------------------------------------------------------------------------
extern "C" void kernel_launch(void* const* d_in, const int* in_sizes, int n_in,
                              void* d_out, int out_size, void* d_ws, size_t ws_size,
                              hipStream_t stream) {
  (void)in_sizes; (void)n_in; (void)out_size; (void)ws_size;
  const float* hs   = (const float*)d_in[0];
  const float* enc  = (const float*)d_in[1];
  const float* Wq   = (const float*)d_in[2];
  const float* Wk   = (const float*)d_in[3];
  const float* Wv   = (const float*)d_in[4];
  const float* Wo   = (const float*)d_in[5];
  const float* bo   = (const float*)d_in[6];
  const float* q_dn = (const float*)d_in[7];
  const float* q_up = (const float*)d_in[8];
  const float* k_dn = (const float*)d_in[9];
  const float* k_up = (const float*)d_in[10];
  const float* v_dn = (const float*)d_in[11];
  const float* v_up = (const float*)d_in[12];
  const float* o_dn = (const float*)d_in[13];
  const float* o_up = (const float*)d_in[14];

  char* ws = (char*)d_ws;
  size_t off = 0;
  auto alloc = [&](size_t bytes) -> void* {
    void* p = ws + off;
    off += (bytes + 255) & ~(size_t)255;
    return p;
  };
  const size_t ACT = (size_t)kM * kD * 2;
  unsigned short* hsb  = (unsigned short*)alloc(ACT);
  unsigned short* encb = (unsigned short*)alloc(ACT);
  unsigned short* Wqt  = (unsigned short*)alloc((size_t)1024 * 1024 * 2);
  unsigned short* Wkvt = (unsigned short*)alloc((size_t)2048 * 1024 * 2);
  unsigned short* Wot  = (unsigned short*)alloc((size_t)1024 * 1024 * 2);
  unsigned short* Qhp  = (unsigned short*)alloc(ACT);
  unsigned short* Khp  = (unsigned short*)alloc(ACT);
  unsigned short* Vhp  = (unsigned short*)alloc(ACT);
  float* tq  = (float*)alloc((size_t)kM * 4 * 4);
  float* tkv = (float*)alloc((size_t)kM * 8 * 4);
  float* to  = (float*)alloc((size_t)kM * 4 * 4);
  unsigned short* Vtt = hsb;   // alias: V^T reuses hidden bf16 buffer
  unsigned short* Ob  = encb;  // alias: attention O reuses encoder bf16 buffer

  k_prep_wt<<<dim3(2 * kM + 1024), dim3(256), 0, stream>>>(
      hs, enc, q_dn, k_dn, v_dn, Wq, Wk, Wv, Wo,
      hsb, encb, tq, tkv, Wqt, Wkvt, Wot);

  k_gemm_qkv<<<dim3(768), dim3(512), 0, stream>>>(
      hsb, encb, Wqt, Wkvt, tq, tkv, q_up, k_up, v_up, Qhp, Khp, Vhp);

  k_vt<<<dim3(32, 64), dim3(256), 0, stream>>>(Vhp, Vtt);
  k_attn<<<dim3(16, 64), dim3(256), 0, stream>>>(Qhp, Khp, Vtt, Ob);
  k_tdown<<<dim3(kM), dim3(256), 0, stream>>>(Ob, o_dn, to);

  k_gemm_out<<<dim3(256), dim3(512), 0, stream>>>(Ob, Wot, to, o_up, bo,
                                                  (float*)d_out);
}

// Round 12
// 250.526 us; speedup vs baseline: 1.6879x; 1.2953x over previous
//
#include <hip/hip_runtime.h>
#include <hip/hip_bf16.h>

typedef __attribute__((ext_vector_type(8))) short bf16x8;
typedef __attribute__((ext_vector_type(4))) float f32x4;

#define DEVFN static __device__ __forceinline__

constexpr int kSQ = 2048, kSKV = 2048, kD = 1024, kH = 16;
constexpr int kM = 4 * kSQ;   // 8192 query rows (B*SQ)

DEVFN unsigned short f2bf(float f) {
  union { float f; unsigned u; } v; v.f = f;
  unsigned r = v.u + 0x7FFFu + ((v.u >> 16) & 1u);
  return (unsigned short)(r >> 16);
}
DEVFN float bf2f(unsigned short h) {
  union { unsigned u; float f; } v; v.u = ((unsigned)h) << 16; return v.f;
}
DEVFN unsigned cvtpk(float lo, float hi) {
  unsigned r;
  asm("v_cvt_pk_bf16_f32 %0, %1, %2" : "=v"(r) : "v"(lo), "v"(hi));
  return r;
}
DEVFN float vexp2(float x) {
  float r;
  asm("v_exp_f32 %0, %1" : "=v"(r) : "v"(x));
  return r;
}

DEVFN void gload16(const void* g, void* l) {
  __builtin_amdgcn_global_load_lds(
      (const __attribute__((address_space(1))) unsigned int*)g,
      (__attribute__((address_space(3))) unsigned int*)l, 16, 0, 0);
}

#define WT12 asm volatile("s_waitcnt vmcnt(12)" ::: "memory")
#define WT6  asm volatile("s_waitcnt vmcnt(6)" ::: "memory")
#define WT0  asm volatile("s_waitcnt vmcnt(0)" ::: "memory")

// ---------------------------------------------------------------------------
// Kernel 1 (merged): blocks [0, 2*kM): activation fp32->bf16 + LoRA-down dots.
// blocks [2*kM, 2*kM+1024): weight convert+transpose (4 weights x 256 tiles).
__global__ __launch_bounds__(256) void k_prep_wt(
    const float* __restrict__ hs, const float* __restrict__ enc,
    const float* __restrict__ qdn, const float* __restrict__ kdn,
    const float* __restrict__ vdn,
    const float* __restrict__ Wq, const float* __restrict__ Wk,
    const float* __restrict__ Wv, const float* __restrict__ Wo,
    unsigned short* __restrict__ hsb, unsigned short* __restrict__ encb,
    float* __restrict__ tq, float* __restrict__ tkv,
    unsigned short* __restrict__ Wqt, unsigned short* __restrict__ Wkvt,
    unsigned short* __restrict__ Wot) {
  __shared__ float red[4][8];
  __shared__ unsigned short tile[64][65];
  const int bid = blockIdx.x;
  const int tid = threadIdx.x;

  if (bid < 2 * kM) {
    const bool isH = bid < kM;
    const int rr = isH ? bid : bid - kM;
    const float* srcRow = (isH ? hs : enc) + (size_t)rr * kD;
    unsigned short* dstRow = (isH ? hsb : encb) + (size_t)rr * kD;

    float4 x = reinterpret_cast<const float4*>(srcRow)[tid];
    short4 o;
    o.x = (short)f2bf(x.x); o.y = (short)f2bf(x.y);
    o.z = (short)f2bf(x.z); o.w = (short)f2bf(x.w);
    *reinterpret_cast<short4*>(dstRow + tid * 4) = o;

    float xs[4] = {x.x, x.y, x.z, x.w};
    float a[4] = {0.f, 0.f, 0.f, 0.f};
    float bacc[4] = {0.f, 0.f, 0.f, 0.f};
    const float* dnA = isH ? qdn : kdn;
    const int base = tid * 4;
#pragma unroll
    for (int e = 0; e < 4; ++e) {
      const float* dr = dnA + (size_t)(base + e) * 4;
      a[0] += xs[e] * dr[0]; a[1] += xs[e] * dr[1];
      a[2] += xs[e] * dr[2]; a[3] += xs[e] * dr[3];
    }
    if (!isH) {
#pragma unroll
      for (int e = 0; e < 4; ++e) {
        const float* dr = vdn + (size_t)(base + e) * 4;
        bacc[0] += xs[e] * dr[0]; bacc[1] += xs[e] * dr[1];
        bacc[2] += xs[e] * dr[2]; bacc[3] += xs[e] * dr[3];
      }
    }
    const int l = tid & 63, w = tid >> 6;
    float vals[8] = {a[0], a[1], a[2], a[3], bacc[0], bacc[1], bacc[2], bacc[3]};
#pragma unroll
    for (int k2 = 0; k2 < 8; ++k2) {
      float v = vals[k2];
#pragma unroll
      for (int m = 1; m < 64; m <<= 1) v += __shfl_xor(v, m);
      if (l == 0) red[w][k2] = v;
    }
    __syncthreads();
    if (tid < 8) {
      float s = red[0][tid] + red[1][tid] + red[2][tid] + red[3][tid];
      if (isH) {
        if (tid < 4) tq[(size_t)rr * 4 + tid] = s;
      } else {
        tkv[(size_t)rr * 8 + tid] = s;   // 0..3 = k-down, 4..7 = v-down
      }
    }
  } else {
    const int t = bid - 2 * kM;
    const int wid = t >> 8, tt = t & 255;
    const float* W = (wid == 0) ? Wq : (wid == 1) ? Wk : (wid == 2) ? Wv : Wo;
    unsigned short* Wt = (wid == 0) ? Wqt : (wid == 1) ? Wkvt
                        : (wid == 2) ? (Wkvt + (size_t)1024 * 1024) : Wot;
    const int tk0 = (tt & 15) * 64;
    const int tn0 = (tt >> 4) * 64;
    for (int i = tid; i < 4096; i += 256) {
      int r = i >> 6, c = i & 63;
      tile[r][c] = f2bf(W[(size_t)(tk0 + r) * 1024 + tn0 + c]);
    }
    __syncthreads();
    for (int i = tid; i < 4096; i += 256) {
      int r = i >> 6, c = i & 63;
      Wt[(size_t)(tn0 + r) * 1024 + tk0 + c] = tile[c][r];
    }
  }
}

// ---------------------------------------------------------------------------
// Big-tile GEMM core: BM=256, BN=128, BK=64, 8 waves (512 thr), 144KB LDS
// TRIPLE-buffer, counted vmcnt 3-deep pipeline, T2 XOR swizzle via
// pre-swizzled global source + swizzled ds_read.

#define GSTAGE(dbuf, kt) do {                                                 \
    _Pragma("unroll")                                                         \
    for (int j = 0; j < 4; ++j) {                                             \
      const int s = (j * 8 + w) * 64 + l;                                     \
      const int row = s >> 3, u = s & 7;                                      \
      gload16(Ap + (size_t)row * 1024 + (kt) * 64 + ((u ^ (row & 7)) * 8),    \
              &lA[dbuf][(j * 8 + w) * 512]);                                  \
    }                                                                         \
    _Pragma("unroll")                                                         \
    for (int j = 0; j < 2; ++j) {                                             \
      const int s = (j * 8 + w) * 64 + l;                                     \
      const int row = s >> 3, u = s & 7;                                      \
      gload16(Bp + (size_t)row * 1024 + (kt) * 64 + ((u ^ (row & 7)) * 8),    \
              &lB[dbuf][(j * 8 + w) * 512]);                                  \
    } } while (0)

// TRANS=1: mfma(bfr, af) -> acc[m][n][r] = C[row=wr+m*16+lr][col=wc+n*16+lk*4+r]
// TRANS=0: mfma(af, bfr) -> acc[m][n][r] = C[row=wr+m*16+lk*4+r][col=wc+n*16+lr]
#define BIG_GEMM_LOOP(TRANS)                                                  \
  GSTAGE(0, 0);                                                               \
  GSTAGE(1, 1);                                                               \
  GSTAGE(2, 2);                                                               \
  _Pragma("unroll")                                                           \
  for (int kt = 0; kt < 16; ++kt) {                                           \
    const int cur = kt % 3;                                                   \
    if (kt <= 13) { WT12; } else if (kt == 14) { WT6; } else { WT0; }         \
    __builtin_amdgcn_s_barrier();                                             \
    asm volatile("" ::: "memory");                                            \
    _Pragma("unroll")                                                         \
    for (int kk = 0; kk < 2; ++kk) {                                          \
      bf16x8 af[8], bfr[2];                                                   \
      _Pragma("unroll")                                                       \
      for (int m = 0; m < 8; ++m) {                                           \
        const int ar = wr + m * 16 + lr;                                      \
        af[m] = *(const bf16x8*)&lA[cur][ar * 64 +                            \
                 (((kk * 4 + lk) ^ (ar & 7)) * 8)];                           \
      }                                                                       \
      _Pragma("unroll")                                                       \
      for (int n = 0; n < 2; ++n) {                                           \
        const int br = wc + n * 16 + lr;                                      \
        bfr[n] = *(const bf16x8*)&lB[cur][br * 64 +                           \
                 (((kk * 4 + lk) ^ (br & 7)) * 8)];                           \
      }                                                                       \
      __builtin_amdgcn_s_setprio(1);                                          \
      _Pragma("unroll")                                                       \
      for (int m = 0; m < 8; ++m)                                             \
        _Pragma("unroll")                                                     \
        for (int n = 0; n < 2; ++n)                                           \
          acc[m][n] = (TRANS)                                                 \
            ? __builtin_amdgcn_mfma_f32_16x16x32_bf16(bfr[n], af[m],          \
                                                      acc[m][n], 0, 0, 0)     \
            : __builtin_amdgcn_mfma_f32_16x16x32_bf16(af[m], bfr[n],          \
                                                      acc[m][n], 0, 0, 0);    \
      __builtin_amdgcn_s_setprio(0);                                          \
    }                                                                         \
    asm volatile("s_waitcnt lgkmcnt(0)" ::: "memory");                        \
    __builtin_amdgcn_s_barrier();                                             \
    asm volatile("" ::: "memory");                                            \
    if (kt < 13) GSTAGE(cur, kt + 3);                                         \
  }

// Kernel 2: QKV projection. blocks [0,256): Q (N=1024); [256,768): K|V (N=2048).
// Transposed acc + LDS repack epilogue -> 1KB-per-wave coalesced stores.
__global__ __launch_bounds__(512, 2) void k_gemm_qkv(
    const unsigned short* __restrict__ hsb, const unsigned short* __restrict__ encb,
    const unsigned short* __restrict__ Wqt, const unsigned short* __restrict__ Wkvt,
    const float* __restrict__ tq, const float* __restrict__ tkv,
    const float* __restrict__ q_up, const float* __restrict__ k_up,
    const float* __restrict__ v_up,
    unsigned short* __restrict__ Qhp, unsigned short* __restrict__ Khp,
    unsigned short* __restrict__ Vhp) {
  __shared__ unsigned short lA[3][256 * 64];
  __shared__ unsigned short lB[3][128 * 64];
  const int tid = threadIdx.x;
  const int l = tid & 63, w = tid >> 6;
  const int bid = blockIdx.x;

  const unsigned short *A, *Bt;
  const float *tmat, *up;
  unsigned short* dst;
  int m0, nB0, nOut0, tstr;
  if (bid < 256) {
    const int rid = (bid & 7) * 32 + (bid >> 3);
    m0 = (rid >> 3) * 256; nB0 = (rid & 7) * 128;
    A = hsb; Bt = Wqt; tmat = tq; tstr = 4; up = q_up; dst = Qhp; nOut0 = nB0;
  } else {
    const int b2 = bid - 256;
    const int rid = (b2 & 7) * 64 + (b2 >> 3);
    m0 = (rid >> 4) * 256; nB0 = (rid & 15) * 128;
    A = encb; Bt = Wkvt; tstr = 8;
    if (nB0 < 1024) { tmat = tkv;     up = k_up; dst = Khp; nOut0 = nB0; }
    else            { tmat = tkv + 4; up = v_up; dst = Vhp; nOut0 = nB0 - 1024; }
  }
  const int wr = (w >> 2) * 128, wc = (w & 3) * 32;
  const int lr = l & 15, lk = l >> 4;
  const unsigned short* Ap = A  + (size_t)m0  * 1024;
  const unsigned short* Bp = Bt + (size_t)nB0 * 1024;

  f32x4 acc[8][2];
  const f32x4 zero = {0.f, 0.f, 0.f, 0.f};
#pragma unroll
  for (int m = 0; m < 8; ++m)
#pragma unroll
    for (int n = 0; n < 2; ++n) acc[m][n] = zero;

  BIG_GEMM_LOOP(1)

  // ---- epilogue: LoRA add + repack via LDS for coalesced stores -----------
  unsigned short* rep = &lA[0][0];           // 64KB: 256 rows x 128 cols bf16
#pragma unroll
  for (int n = 0; n < 2; ++n) {
    const int cb = wc + n * 16 + lk * 4;     // first of 4 consecutive cols
    const float4 u0v = *reinterpret_cast<const float4*>(&up[nOut0 + cb]);
    const float4 u1v = *reinterpret_cast<const float4*>(&up[1024 + nOut0 + cb]);
    const float4 u2v = *reinterpret_cast<const float4*>(&up[2048 + nOut0 + cb]);
    const float4 u3v = *reinterpret_cast<const float4*>(&up[3072 + nOut0 + cb]);
    const int u16 = cb >> 3;                 // 16B unit within 256B row
    const int bo8 = (lk & 1) * 8;
#pragma unroll
    for (int m = 0; m < 8; ++m) {
      const int row = wr + m * 16 + lr;
      const int grow = m0 + row;
      const float4 tt = *reinterpret_cast<const float4*>(tmat + (size_t)grow * tstr);
      const float v0 = acc[m][n][0] + tt.x * u0v.x + tt.y * u1v.x + tt.z * u2v.x + tt.w * u3v.x;
      const float v1 = acc[m][n][1] + tt.x * u0v.y + tt.y * u1v.y + tt.z * u2v.y + tt.w * u3v.y;
      const float v2 = acc[m][n][2] + tt.x * u0v.z + tt.y * u1v.z + tt.z * u2v.z + tt.w * u3v.z;
      const float v3 = acc[m][n][3] + tt.x * u0v.w + tt.y * u1v.w + tt.z * u2v.w + tt.w * u3v.w;
      uint2 pk; pk.x = cvtpk(v0, v1); pk.y = cvtpk(v2, v3);
      *(uint2*)((char*)rep + row * 256 + ((u16 ^ (row & 7)) << 4) + bo8) = pk;
    }
  }
  __syncthreads();
  const int sub = l & 7;
#pragma unroll
  for (int it = 0; it < 8; ++it) {
    const int g = w * 64 + it * 8 + (l >> 3);   // 0..511 (row, head-half)
    const int head = g >> 8, row = g & 255;
    const int ju = ((head * 8 + sub) ^ (row & 7)) << 4;
    uint4 val = *(const uint4*)((const char*)rep + row * 256 + ju);
    const int grow = m0 + row;
    const int b = grow >> 11, s = grow & 2047;
    const int hg = (nOut0 >> 6) + head;
    *(uint4*)&dst[(((size_t)(b * kH + hg)) * 2048 + s) * 64 + sub * 8] = val;
  }
}

// Kernel 3: final GEMM  out = Ob @ Wot^T + bias + t_o @ o_up  (f32 output,
// row-major stores already 64B-coalesced — original epilogue kept)
__global__ __launch_bounds__(512, 2) void k_gemm_out(
    const unsigned short* __restrict__ A, const unsigned short* __restrict__ Bt,
    const float* __restrict__ tmat, const float* __restrict__ up,
    const float* __restrict__ bias, float* __restrict__ outp) {
  __shared__ unsigned short lA[3][256 * 64];
  __shared__ unsigned short lB[3][128 * 64];
  const int tid = threadIdx.x;
  const int l = tid & 63, w = tid >> 6;
  const int bid = blockIdx.x;
  const int rid = (bid & 7) * 32 + (bid >> 3);
  const int m0 = (rid >> 3) * 256, nB0 = (rid & 7) * 128;
  const int wr = (w >> 2) * 128, wc = (w & 3) * 32;
  const int lr = l & 15, lk = l >> 4;
  const unsigned short* Ap = A  + (size_t)m0  * 1024;
  const unsigned short* Bp = Bt + (size_t)nB0 * 1024;

  f32x4 acc[8][2];
  const f32x4 zero = {0.f, 0.f, 0.f, 0.f};
#pragma unroll
  for (int m = 0; m < 8; ++m)
#pragma unroll
    for (int n = 0; n < 2; ++n) acc[m][n] = zero;

  BIG_GEMM_LOOP(0)

#pragma unroll
  for (int n = 0; n < 2; ++n) {
    const int gcol = nB0 + wc + n * 16 + lr;
    const float u0 = up[gcol], u1 = up[1024 + gcol];
    const float u2 = up[2048 + gcol], u3 = up[3072 + gcol];
    const float bz = bias[gcol];
#pragma unroll
    for (int m = 0; m < 8; ++m) {
#pragma unroll
      for (int r = 0; r < 4; ++r) {
        const int grow = m0 + wr + m * 16 + lk * 4 + r;
        const float4 tt = *reinterpret_cast<const float4*>(tmat + (size_t)grow * 4);
        outp[(size_t)grow * 1024 + gcol] =
            acc[m][n][r] + tt.x * u0 + tt.y * u1 + tt.z * u2 + tt.w * u3 + bz;
      }
    }
  }
}

// ---------------------------------------------------------------------------
// Kernel 4: V head-layout transpose: (bh, s, d) -> (bh, d, s)
__global__ __launch_bounds__(256) void k_vt(const unsigned short* __restrict__ Vh,
                                            unsigned short* __restrict__ Vt) {
  __shared__ unsigned short tile[64][65];
  const int bh = blockIdx.y;
  const int s0 = blockIdx.x * 64;
  const unsigned short* src = Vh + ((size_t)bh * kSKV + s0) * 64;
  for (int i = threadIdx.x; i < 4096; i += 256) {
    int r = i >> 6, c = i & 63;
    tile[r][c] = src[(size_t)r * 64 + c];
  }
  __syncthreads();
  unsigned short* dst = Vt + (size_t)bh * 64 * kSKV + s0;
  for (int i = threadIdx.x; i < 4096; i += 256) {
    int r = i >> 6, c = i & 63;
    dst[(size_t)r * kSKV + c] = tile[c][r];
  }
}

// ---------------------------------------------------------------------------
// Kernel 5: flash attention, QBLK=128 (4 waves x 32 q-rows), KV tiles of 64.
// Fixed-max softmax via exp2 (Q pre-scaled by log2e/8). Conflict-free
// 16B-unit XOR swizzle on K/V/P. (round-3 structure: dbuf + syncthreads)
__global__ __launch_bounds__(256) void k_attn(
    const unsigned short* __restrict__ Qh, const unsigned short* __restrict__ Kh,
    const unsigned short* __restrict__ Vt, unsigned short* __restrict__ Obf) {
  __shared__ unsigned short lK[2][4096];
  __shared__ unsigned short lV[2][4096];
  __shared__ __align__(16) unsigned short lP[4][1024];

  const int bid = blockIdx.x + 16 * blockIdx.y;              // 1024 blocks
  const int rid = (bid & 7) * 128 + (bid >> 3);
  const int q0 = (rid & 15) * 128;
  const int bh = rid >> 4;

  const int tid = threadIdx.x;
  const int l = tid & 63, w = tid >> 6;
  const int lr = l & 15, lk = l >> 4;
  const int m7 = lr & 7;
  const int lkh = lk >> 1, lkb = lk & 1;

  const unsigned short* Qb = Qh + (size_t)bh * kSQ * 64;
  const unsigned short* Kb = Kh + (size_t)bh * kSKV * 64;
  const unsigned short* Vb = Vt + (size_t)bh * 64 * kSKV;

  const float QS = 0.125f * 1.4426950408889634f;
  bf16x8 qf[2][2];
#pragma unroll
  for (int m = 0; m < 2; ++m)
#pragma unroll
    for (int kk = 0; kk < 2; ++kk) {
      bf16x8 v = *(const bf16x8*)
          &Qb[(size_t)(q0 + w * 32 + m * 16 + lr) * 64 + kk * 32 + lk * 8];
#pragma unroll
      for (int j = 0; j < 8; ++j) {
        unsigned short u = (unsigned short)v[j];
        v[j] = (short)f2bf(bf2f(u) * QS);
      }
      qf[m][kk] = v;
    }

  f32x4 oacc[2][4];
  const f32x4 zero = {0.f, 0.f, 0.f, 0.f};
#pragma unroll
  for (int m = 0; m < 2; ++m)
#pragma unroll
    for (int n = 0; n < 4; ++n) oacc[m][n] = zero;
  float lrow[2] = {0.f, 0.f};

  const int sr8 = l >> 3;
  const int su = (l & 7) ^ sr8;
  unsigned short* lPw = lP[w];

#define ASTAGE(dbuf, tile) do { \
    _Pragma("unroll") for (int cc = 0; cc < 2; ++cc) { \
      const int c = 2 * w + cc; const int row = c * 8 + sr8; \
      gload16(Kb + (size_t)((tile) * 64 + row) * 64 + su * 8, &lK[dbuf][c * 512]); \
      gload16(Vb + (size_t)row * kSKV + (tile) * 64 + su * 8, &lV[dbuf][c * 512]); \
    } } while (0)

  ASTAGE(0, 0);
  __syncthreads();

#pragma unroll 2
  for (int kt = 0; kt < 32; ++kt) {
    const int cur = kt & 1;
    if (kt < 31) ASTAGE(cur ^ 1, kt + 1);
    const unsigned short* bufK = lK[cur];
    const unsigned short* bufV = lV[cur];

    bf16x8 kf[4][2];
#pragma unroll
    for (int n = 0; n < 4; ++n)
#pragma unroll
      for (int kk = 0; kk < 2; ++kk) {
        const int ub = (kk * 4 + lk) ^ m7;
        kf[n][kk] = *(const bf16x8*)&bufK[(n * 16 + lr) * 64 + ub * 8];
      }

    f32x4 s0[4];
#pragma unroll
    for (int n = 0; n < 4; ++n) s0[n] = zero;
    __builtin_amdgcn_s_setprio(1);
#pragma unroll
    for (int kk = 0; kk < 2; ++kk)
#pragma unroll
      for (int n = 0; n < 4; ++n)
        s0[n] = __builtin_amdgcn_mfma_f32_16x16x32_bf16(kf[n][kk], qf[0][kk],
                                                        s0[n], 0, 0, 0);
    __builtin_amdgcn_s_setprio(0);
    float ls0 = 0.f;
#pragma unroll
    for (int n = 0; n < 4; ++n) {
      const float p0 = vexp2(s0[n][0]);
      const float p1 = vexp2(s0[n][1]);
      const float p2 = vexp2(s0[n][2]);
      const float p3 = vexp2(s0[n][3]);
      ls0 += (p0 + p1) + (p2 + p3);
      uint2 pv; pv.x = cvtpk(p0, p1); pv.y = cvtpk(p2, p3);
      *(uint2*)&lPw[lr * 64 + (((2 * n + lkh) ^ m7) << 3) + lkb * 4] = pv;
    }
    lrow[0] += ls0;

    f32x4 s1[4];
#pragma unroll
    for (int n = 0; n < 4; ++n) s1[n] = zero;
    __builtin_amdgcn_s_setprio(1);
#pragma unroll
    for (int kk = 0; kk < 2; ++kk)
#pragma unroll
      for (int n = 0; n < 4; ++n)
        s1[n] = __builtin_amdgcn_mfma_f32_16x16x32_bf16(kf[n][kk], qf[1][kk],
                                                        s1[n], 0, 0, 0);
    __builtin_amdgcn_s_setprio(0);
    float ls1 = 0.f;
    uint2 pw1[4];
#pragma unroll
    for (int n = 0; n < 4; ++n) {
      const float p0 = vexp2(s1[n][0]);
      const float p1 = vexp2(s1[n][1]);
      const float p2 = vexp2(s1[n][2]);
      const float p3 = vexp2(s1[n][3]);
      ls1 += (p0 + p1) + (p2 + p3);
      pw1[n].x = cvtpk(p0, p1); pw1[n].y = cvtpk(p2, p3);
    }
    lrow[1] += ls1;

    bf16x8 pf0[2], pf1[2];
#pragma unroll
    for (int kk = 0; kk < 2; ++kk)
      pf0[kk] = *(const bf16x8*)&lPw[lr * 64 + (((kk * 4 + lk) ^ m7) << 3)];
#pragma unroll
    for (int n = 0; n < 4; ++n)
      *(uint2*)&lPw[lr * 64 + (((2 * n + lkh) ^ m7) << 3) + lkb * 4] = pw1[n];
#pragma unroll
    for (int kk = 0; kk < 2; ++kk)
      pf1[kk] = *(const bf16x8*)&lPw[lr * 64 + (((kk * 4 + lk) ^ m7) << 3)];

    __builtin_amdgcn_s_setprio(1);
#pragma unroll
    for (int n = 0; n < 4; ++n)
#pragma unroll
      for (int kk = 0; kk < 2; ++kk) {
        const int ub = (kk * 4 + lk) ^ m7;
        bf16x8 vf = *(const bf16x8*)&bufV[(n * 16 + lr) * 64 + ub * 8];
        oacc[0][n] = __builtin_amdgcn_mfma_f32_16x16x32_bf16(pf0[kk], vf,
                                                             oacc[0][n], 0, 0, 0);
        oacc[1][n] = __builtin_amdgcn_mfma_f32_16x16x32_bf16(pf1[kk], vf,
                                                             oacc[1][n], 0, 0, 0);
      }
    __builtin_amdgcn_s_setprio(0);

    __syncthreads();
  }
#undef ASTAGE

  float rinv[2][4];
#pragma unroll
  for (int m = 0; m < 2; ++m) {
    float s = lrow[m];
    s += __shfl_xor(s, 16);
    s += __shfl_xor(s, 32);
#pragma unroll
    for (int r = 0; r < 4; ++r) rinv[m][r] = 1.0f / __shfl(s, lk * 4 + r);
  }

  const int b = bh >> 4, h = bh & 15;
#pragma unroll
  for (int m = 0; m < 2; ++m)
#pragma unroll
    for (int n = 0; n < 4; ++n)
#pragma unroll
      for (int r = 0; r < 4; ++r) {
        const int qrow = q0 + w * 32 + m * 16 + lk * 4 + r;
        const int d = n * 16 + lr;
        Obf[((size_t)b * kSQ + qrow) * kD + h * 64 + d] =
            f2bf(oacc[m][n][r] * rinv[m][r]);
      }
}

// ---------------------------------------------------------------------------
// Kernel 6: t_o = O(bf16) @ out_lora_down
__global__ __launch_bounds__(256) void k_tdown(const unsigned short* __restrict__ Ob,
                                               const float* __restrict__ dn,
                                               float* __restrict__ t_o) {
  const int row = blockIdx.x;
  const int tid = threadIdx.x;
  const unsigned short* src = Ob + (size_t)row * kD;
  short4 v4 = *reinterpret_cast<const short4*>(&src[tid * 4]);
  short vs[4] = {v4.x, v4.y, v4.z, v4.w};
  float a[4] = {0.f, 0.f, 0.f, 0.f};
#pragma unroll
  for (int e = 0; e < 4; ++e) {
    const float x = bf2f((unsigned short)vs[e]);
    const float* dr = dn + (size_t)(tid * 4 + e) * 4;
    a[0] += x * dr[0]; a[1] += x * dr[1]; a[2] += x * dr[2]; a[3] += x * dr[3];
  }
  __shared__ float red[4][4];
  const int l = tid & 63, w = tid >> 6;
#pragma unroll
  for (int k2 = 0; k2 < 4; ++k2) {
    float v = a[k2];
#pragma unroll
    for (int m = 1; m < 64; m <<= 1) v += __shfl_xor(v, m);
    if (l == 0) red[w][k2] = v;
  }
  __syncthreads();
  if (tid < 4)
    t_o[(size_t)row * 4 + tid] = red[0][tid] + red[1][tid] + red[2][tid] + red[3][tid];
}

// ---------------------------------------------------------------------------
extern "C" void kernel_launch(void* const* d_in, const int* in_sizes, int n_in,
                              void* d_out, int out_size, void* d_ws, size_t ws_size,
                              hipStream_t stream) {
  (void)in_sizes; (void)n_in; (void)out_size; (void)ws_size;
  const float* hs   = (const float*)d_in[0];
  const float* enc  = (const float*)d_in[1];
  const float* Wq   = (const float*)d_in[2];
  const float* Wk   = (const float*)d_in[3];
  const float* Wv   = (const float*)d_in[4];
  const float* Wo   = (const float*)d_in[5];
  const float* bo   = (const float*)d_in[6];
  const float* q_dn = (const float*)d_in[7];
  const float* q_up = (const float*)d_in[8];
  const float* k_dn = (const float*)d_in[9];
  const float* k_up = (const float*)d_in[10];
  const float* v_dn = (const float*)d_in[11];
  const float* v_up = (const float*)d_in[12];
  const float* o_dn = (const float*)d_in[13];
  const float* o_up = (const float*)d_in[14];

  char* ws = (char*)d_ws;
  size_t off = 0;
  auto alloc = [&](size_t bytes) -> void* {
    void* p = ws + off;
    off += (bytes + 255) & ~(size_t)255;
    return p;
  };
  const size_t ACT = (size_t)kM * kD * 2;
  unsigned short* hsb  = (unsigned short*)alloc(ACT);
  unsigned short* encb = (unsigned short*)alloc(ACT);
  unsigned short* Wqt  = (unsigned short*)alloc((size_t)1024 * 1024 * 2);
  unsigned short* Wkvt = (unsigned short*)alloc((size_t)2048 * 1024 * 2);
  unsigned short* Wot  = (unsigned short*)alloc((size_t)1024 * 1024 * 2);
  unsigned short* Qhp  = (unsigned short*)alloc(ACT);
  unsigned short* Khp  = (unsigned short*)alloc(ACT);
  unsigned short* Vhp  = (unsigned short*)alloc(ACT);
  float* tq  = (float*)alloc((size_t)kM * 4 * 4);
  float* tkv = (float*)alloc((size_t)kM * 8 * 4);
  float* to  = (float*)alloc((size_t)kM * 4 * 4);
  unsigned short* Vtt = hsb;   // alias: V^T reuses hidden bf16 buffer
  unsigned short* Ob  = encb;  // alias: attention O reuses encoder bf16 buffer

  k_prep_wt<<<dim3(2 * kM + 1024), dim3(256), 0, stream>>>(
      hs, enc, q_dn, k_dn, v_dn, Wq, Wk, Wv, Wo,
      hsb, encb, tq, tkv, Wqt, Wkvt, Wot);

  k_gemm_qkv<<<dim3(768), dim3(512), 0, stream>>>(
      hsb, encb, Wqt, Wkvt, tq, tkv, q_up, k_up, v_up, Qhp, Khp, Vhp);

  k_vt<<<dim3(32, 64), dim3(256), 0, stream>>>(Vhp, Vtt);
  k_attn<<<dim3(16, 64), dim3(256), 0, stream>>>(Qhp, Khp, Vtt, Ob);
  k_tdown<<<dim3(kM), dim3(256), 0, stream>>>(Ob, o_dn, to);

  k_gemm_out<<<dim3(256), dim3(512), 0, stream>>>(Ob, Wot, to, o_up, bo,
                                                  (float*)d_out);
}

// Round 13
// 245.410 us; speedup vs baseline: 1.7231x; 1.0208x over previous
//
#include <hip/hip_runtime.h>
#include <hip/hip_bf16.h>

typedef __attribute__((ext_vector_type(8))) short bf16x8;
typedef __attribute__((ext_vector_type(4))) float f32x4;

#define DEVFN static __device__ __forceinline__

constexpr int kSQ = 2048, kSKV = 2048, kD = 1024, kH = 16;
constexpr int kM = 4 * kSQ;   // 8192 query rows (B*SQ)

DEVFN unsigned short f2bf(float f) {
  union { float f; unsigned u; } v; v.f = f;
  unsigned r = v.u + 0x7FFFu + ((v.u >> 16) & 1u);
  return (unsigned short)(r >> 16);
}
DEVFN float bf2f(unsigned short h) {
  union { unsigned u; float f; } v; v.u = ((unsigned)h) << 16; return v.f;
}
DEVFN unsigned cvtpk(float lo, float hi) {
  unsigned r;
  asm("v_cvt_pk_bf16_f32 %0, %1, %2" : "=v"(r) : "v"(lo), "v"(hi));
  return r;
}
DEVFN float vexp2(float x) {
  float r;
  asm("v_exp_f32 %0, %1" : "=v"(r) : "v"(x));
  return r;
}

DEVFN void gload16(const void* g, void* l) {
  __builtin_amdgcn_global_load_lds(
      (const __attribute__((address_space(1))) unsigned int*)g,
      (__attribute__((address_space(3))) unsigned int*)l, 16, 0, 0);
}

#define WT12 asm volatile("s_waitcnt vmcnt(12)" ::: "memory")
#define WT6  asm volatile("s_waitcnt vmcnt(6)" ::: "memory")
#define WT0  asm volatile("s_waitcnt vmcnt(0)" ::: "memory")

// ---------------------------------------------------------------------------
// Kernel 1: blocks [0, 2*kM): activation fp32->bf16 streaming convert.
// blocks [2*kM, 2*kM+1024): weight convert+transpose (4 weights x 256 tiles).
__global__ __launch_bounds__(256) void k_prep_wt(
    const float* __restrict__ hs, const float* __restrict__ enc,
    const float* __restrict__ Wq, const float* __restrict__ Wk,
    const float* __restrict__ Wv, const float* __restrict__ Wo,
    unsigned short* __restrict__ hsb, unsigned short* __restrict__ encb,
    unsigned short* __restrict__ Wqt, unsigned short* __restrict__ Wkvt,
    unsigned short* __restrict__ Wot) {
  __shared__ unsigned short tile[64][65];
  const int bid = blockIdx.x;
  const int tid = threadIdx.x;

  if (bid < 2 * kM) {
    const bool isH = bid < kM;
    const int rr = isH ? bid : bid - kM;
    const float* srcRow = (isH ? hs : enc) + (size_t)rr * kD;
    unsigned short* dstRow = (isH ? hsb : encb) + (size_t)rr * kD;
    float4 x = reinterpret_cast<const float4*>(srcRow)[tid];
    short4 o;
    o.x = (short)f2bf(x.x); o.y = (short)f2bf(x.y);
    o.z = (short)f2bf(x.z); o.w = (short)f2bf(x.w);
    *reinterpret_cast<short4*>(dstRow + tid * 4) = o;
  } else {
    const int t = bid - 2 * kM;
    const int wid = t >> 8, tt = t & 255;
    const float* W = (wid == 0) ? Wq : (wid == 1) ? Wk : (wid == 2) ? Wv : Wo;
    unsigned short* Wt = (wid == 0) ? Wqt : (wid == 1) ? Wkvt
                        : (wid == 2) ? (Wkvt + (size_t)1024 * 1024) : Wot;
    const int tk0 = (tt & 15) * 64;
    const int tn0 = (tt >> 4) * 64;
    for (int i = tid; i < 4096; i += 256) {
      int r = i >> 6, c = i & 63;
      tile[r][c] = f2bf(W[(size_t)(tk0 + r) * 1024 + tn0 + c]);
    }
    __syncthreads();
    for (int i = tid; i < 4096; i += 256) {
      int r = i >> 6, c = i & 63;
      Wt[(size_t)(tn0 + r) * 1024 + tk0 + c] = tile[c][r];
    }
  }
}

// ---------------------------------------------------------------------------
// Kernel 1b: LoRA-down via MFMA (replaces shuffle-reduce dots).
// t[rows x tstr] = X(bf16, row-major, rows x 1024) @ [dn0 | dn1] (1024 x tstr).
// DN staged transposed+padded in LDS; K-reduce happens inside mfma.
// grid 128 blocks x 256 thr; block = 64 rows (wave = 16 rows).
__global__ __launch_bounds__(256) void k_lora(
    const unsigned short* __restrict__ X,
    const float* __restrict__ dn0, const float* __restrict__ dn1,
    float* __restrict__ tout, int tstr) {
  __shared__ unsigned short DNT[16][1032];   // [col][k], +8 pad: conflict-free
  const int tid = threadIdx.x;
  const int rbase = (int)blockIdx.x * 64;
  for (int i = tid; i < 16 * 1032; i += 256) DNT[i / 1032][i % 1032] = 0;
  __syncthreads();
  for (int i = tid; i < 4096; i += 256) {
    const int k = i >> 2, c = i & 3;
    DNT[c][k] = f2bf(dn0[i]);
  }
  if (dn1 != nullptr) {
    for (int i = tid; i < 4096; i += 256) {
      const int k = i >> 2, c = i & 3;
      DNT[4 + c][k] = f2bf(dn1[i]);
    }
  }
  __syncthreads();
  const int l = tid & 63, w = tid >> 6;
  const int lr = l & 15, lk = l >> 4;
  const unsigned short* Xr = X + (size_t)(rbase + w * 16 + lr) * 1024 + lk * 8;
  const f32x4 zero = {0.f, 0.f, 0.f, 0.f};
  f32x4 acc0 = zero, acc1 = zero;
#pragma unroll 4
  for (int k0 = 0; k0 < 1024; k0 += 64) {
    bf16x8 a0 = *(const bf16x8*)(Xr + k0);
    bf16x8 b0 = *(const bf16x8*)&DNT[lr][k0 + lk * 8];
    bf16x8 a1 = *(const bf16x8*)(Xr + k0 + 32);
    bf16x8 b1 = *(const bf16x8*)&DNT[lr][k0 + 32 + lk * 8];
    acc0 = __builtin_amdgcn_mfma_f32_16x16x32_bf16(a0, b0, acc0, 0, 0, 0);
    acc1 = __builtin_amdgcn_mfma_f32_16x16x32_bf16(a1, b1, acc1, 0, 0, 0);
  }
  // C: col = lr, row = lk*4 + r (within the wave's 16 rows)
  if (lr < tstr) {
#pragma unroll
    for (int r = 0; r < 4; ++r) {
      const int grow = rbase + w * 16 + lk * 4 + r;
      tout[(size_t)grow * tstr + lr] = acc0[r] + acc1[r];
    }
  }
}

// ---------------------------------------------------------------------------
// Big-tile GEMM core: BM=256, BN=128, BK=64, 8 waves (512 thr), 144KB LDS
// TRIPLE-buffer, counted vmcnt 3-deep pipeline, T2 XOR swizzle via
// pre-swizzled global source + swizzled ds_read.

#define GSTAGE(dbuf, kt) do {                                                 \
    _Pragma("unroll")                                                         \
    for (int j = 0; j < 4; ++j) {                                             \
      const int s = (j * 8 + w) * 64 + l;                                     \
      const int row = s >> 3, u = s & 7;                                      \
      gload16(Ap + (size_t)row * 1024 + (kt) * 64 + ((u ^ (row & 7)) * 8),    \
              &lA[dbuf][(j * 8 + w) * 512]);                                  \
    }                                                                         \
    _Pragma("unroll")                                                         \
    for (int j = 0; j < 2; ++j) {                                             \
      const int s = (j * 8 + w) * 64 + l;                                     \
      const int row = s >> 3, u = s & 7;                                      \
      gload16(Bp + (size_t)row * 1024 + (kt) * 64 + ((u ^ (row & 7)) * 8),    \
              &lB[dbuf][(j * 8 + w) * 512]);                                  \
    } } while (0)

// TRANS=1: mfma(bfr, af) -> acc[m][n][r] = C[row=wr+m*16+lr][col=wc+n*16+lk*4+r]
// TRANS=0: mfma(af, bfr) -> acc[m][n][r] = C[row=wr+m*16+lk*4+r][col=wc+n*16+lr]
#define BIG_GEMM_LOOP(TRANS)                                                  \
  GSTAGE(0, 0);                                                               \
  GSTAGE(1, 1);                                                               \
  GSTAGE(2, 2);                                                               \
  _Pragma("unroll")                                                           \
  for (int kt = 0; kt < 16; ++kt) {                                           \
    const int cur = kt % 3;                                                   \
    if (kt <= 13) { WT12; } else if (kt == 14) { WT6; } else { WT0; }         \
    __builtin_amdgcn_s_barrier();                                             \
    asm volatile("" ::: "memory");                                            \
    _Pragma("unroll")                                                         \
    for (int kk = 0; kk < 2; ++kk) {                                          \
      bf16x8 af[8], bfr[2];                                                   \
      _Pragma("unroll")                                                       \
      for (int m = 0; m < 8; ++m) {                                           \
        const int ar = wr + m * 16 + lr;                                      \
        af[m] = *(const bf16x8*)&lA[cur][ar * 64 +                            \
                 (((kk * 4 + lk) ^ (ar & 7)) * 8)];                           \
      }                                                                       \
      _Pragma("unroll")                                                       \
      for (int n = 0; n < 2; ++n) {                                           \
        const int br = wc + n * 16 + lr;                                      \
        bfr[n] = *(const bf16x8*)&lB[cur][br * 64 +                           \
                 (((kk * 4 + lk) ^ (br & 7)) * 8)];                           \
      }                                                                       \
      __builtin_amdgcn_s_setprio(1);                                          \
      _Pragma("unroll")                                                       \
      for (int m = 0; m < 8; ++m)                                             \
        _Pragma("unroll")                                                     \
        for (int n = 0; n < 2; ++n)                                           \
          acc[m][n] = (TRANS)                                                 \
            ? __builtin_amdgcn_mfma_f32_16x16x32_bf16(bfr[n], af[m],          \
                                                      acc[m][n], 0, 0, 0)     \
            : __builtin_amdgcn_mfma_f32_16x16x32_bf16(af[m], bfr[n],          \
                                                      acc[m][n], 0, 0, 0);    \
      __builtin_amdgcn_s_setprio(0);                                          \
    }                                                                         \
    asm volatile("s_waitcnt lgkmcnt(0)" ::: "memory");                        \
    __builtin_amdgcn_s_barrier();                                             \
    asm volatile("" ::: "memory");                                            \
    if (kt < 13) GSTAGE(cur, kt + 3);                                         \
  }

// Kernel 2: QKV projection. blocks [0,256): Q (N=1024); [256,768): K|V (N=2048).
// Transposed acc + LDS repack epilogue -> 1KB-per-wave coalesced stores.
__global__ __launch_bounds__(512, 2) void k_gemm_qkv(
    const unsigned short* __restrict__ hsb, const unsigned short* __restrict__ encb,
    const unsigned short* __restrict__ Wqt, const unsigned short* __restrict__ Wkvt,
    const float* __restrict__ tq, const float* __restrict__ tkv,
    const float* __restrict__ q_up, const float* __restrict__ k_up,
    const float* __restrict__ v_up,
    unsigned short* __restrict__ Qhp, unsigned short* __restrict__ Khp,
    unsigned short* __restrict__ Vhp) {
  __shared__ unsigned short lA[3][256 * 64];
  __shared__ unsigned short lB[3][128 * 64];
  const int tid = threadIdx.x;
  const int l = tid & 63, w = tid >> 6;
  const int bid = blockIdx.x;

  const unsigned short *A, *Bt;
  const float *tmat, *up;
  unsigned short* dst;
  int m0, nB0, nOut0, tstr;
  if (bid < 256) {
    const int rid = (bid & 7) * 32 + (bid >> 3);
    m0 = (rid >> 3) * 256; nB0 = (rid & 7) * 128;
    A = hsb; Bt = Wqt; tmat = tq; tstr = 4; up = q_up; dst = Qhp; nOut0 = nB0;
  } else {
    const int b2 = bid - 256;
    const int rid = (b2 & 7) * 64 + (b2 >> 3);
    m0 = (rid >> 4) * 256; nB0 = (rid & 15) * 128;
    A = encb; Bt = Wkvt; tstr = 8;
    if (nB0 < 1024) { tmat = tkv;     up = k_up; dst = Khp; nOut0 = nB0; }
    else            { tmat = tkv + 4; up = v_up; dst = Vhp; nOut0 = nB0 - 1024; }
  }
  const int wr = (w >> 2) * 128, wc = (w & 3) * 32;
  const int lr = l & 15, lk = l >> 4;
  const unsigned short* Ap = A  + (size_t)m0  * 1024;
  const unsigned short* Bp = Bt + (size_t)nB0 * 1024;

  f32x4 acc[8][2];
  const f32x4 zero = {0.f, 0.f, 0.f, 0.f};
#pragma unroll
  for (int m = 0; m < 8; ++m)
#pragma unroll
    for (int n = 0; n < 2; ++n) acc[m][n] = zero;

  BIG_GEMM_LOOP(1)

  // ---- epilogue: LoRA add + repack via LDS for coalesced stores -----------
  unsigned short* rep = &lA[0][0];           // 64KB: 256 rows x 128 cols bf16
#pragma unroll
  for (int n = 0; n < 2; ++n) {
    const int cb = wc + n * 16 + lk * 4;     // first of 4 consecutive cols
    const float4 u0v = *reinterpret_cast<const float4*>(&up[nOut0 + cb]);
    const float4 u1v = *reinterpret_cast<const float4*>(&up[1024 + nOut0 + cb]);
    const float4 u2v = *reinterpret_cast<const float4*>(&up[2048 + nOut0 + cb]);
    const float4 u3v = *reinterpret_cast<const float4*>(&up[3072 + nOut0 + cb]);
    const int u16 = cb >> 3;                 // 16B unit within 256B row
    const int bo8 = (lk & 1) * 8;
#pragma unroll
    for (int m = 0; m < 8; ++m) {
      const int row = wr + m * 16 + lr;
      const int grow = m0 + row;
      const float4 tt = *reinterpret_cast<const float4*>(tmat + (size_t)grow * tstr);
      const float v0 = acc[m][n][0] + tt.x * u0v.x + tt.y * u1v.x + tt.z * u2v.x + tt.w * u3v.x;
      const float v1 = acc[m][n][1] + tt.x * u0v.y + tt.y * u1v.y + tt.z * u2v.y + tt.w * u3v.y;
      const float v2 = acc[m][n][2] + tt.x * u0v.z + tt.y * u1v.z + tt.z * u2v.z + tt.w * u3v.z;
      const float v3 = acc[m][n][3] + tt.x * u0v.w + tt.y * u1v.w + tt.z * u2v.w + tt.w * u3v.w;
      uint2 pk; pk.x = cvtpk(v0, v1); pk.y = cvtpk(v2, v3);
      *(uint2*)((char*)rep + row * 256 + ((u16 ^ (row & 7)) << 4) + bo8) = pk;
    }
  }
  __syncthreads();
  const int sub = l & 7;
#pragma unroll
  for (int it = 0; it < 8; ++it) {
    const int g = w * 64 + it * 8 + (l >> 3);   // 0..511 (row, head-half)
    const int head = g >> 8, row = g & 255;
    const int ju = ((head * 8 + sub) ^ (row & 7)) << 4;
    uint4 val = *(const uint4*)((const char*)rep + row * 256 + ju);
    const int grow = m0 + row;
    const int b = grow >> 11, s = grow & 2047;
    const int hg = (nOut0 >> 6) + head;
    *(uint4*)&dst[(((size_t)(b * kH + hg)) * 2048 + s) * 64 + sub * 8] = val;
  }
}

// Kernel 3: final GEMM  out = Ob @ Wot^T + bias + t_o @ o_up  (f32 output)
__global__ __launch_bounds__(512, 2) void k_gemm_out(
    const unsigned short* __restrict__ A, const unsigned short* __restrict__ Bt,
    const float* __restrict__ tmat, const float* __restrict__ up,
    const float* __restrict__ bias, float* __restrict__ outp) {
  __shared__ unsigned short lA[3][256 * 64];
  __shared__ unsigned short lB[3][128 * 64];
  const int tid = threadIdx.x;
  const int l = tid & 63, w = tid >> 6;
  const int bid = blockIdx.x;
  const int rid = (bid & 7) * 32 + (bid >> 3);
  const int m0 = (rid >> 3) * 256, nB0 = (rid & 7) * 128;
  const int wr = (w >> 2) * 128, wc = (w & 3) * 32;
  const int lr = l & 15, lk = l >> 4;
  const unsigned short* Ap = A  + (size_t)m0  * 1024;
  const unsigned short* Bp = Bt + (size_t)nB0 * 1024;

  f32x4 acc[8][2];
  const f32x4 zero = {0.f, 0.f, 0.f, 0.f};
#pragma unroll
  for (int m = 0; m < 8; ++m)
#pragma unroll
    for (int n = 0; n < 2; ++n) acc[m][n] = zero;

  BIG_GEMM_LOOP(0)

#pragma unroll
  for (int n = 0; n < 2; ++n) {
    const int gcol = nB0 + wc + n * 16 + lr;
    const float u0 = up[gcol], u1 = up[1024 + gcol];
    const float u2 = up[2048 + gcol], u3 = up[3072 + gcol];
    const float bz = bias[gcol];
#pragma unroll
    for (int m = 0; m < 8; ++m) {
#pragma unroll
      for (int r = 0; r < 4; ++r) {
        const int grow = m0 + wr + m * 16 + lk * 4 + r;
        const float4 tt = *reinterpret_cast<const float4*>(tmat + (size_t)grow * 4);
        outp[(size_t)grow * 1024 + gcol] =
            acc[m][n][r] + tt.x * u0 + tt.y * u1 + tt.z * u2 + tt.w * u3 + bz;
      }
    }
  }
}

// ---------------------------------------------------------------------------
// Kernel 4: V head-layout transpose: (bh, s, d) -> (bh, d, s)
__global__ __launch_bounds__(256) void k_vt(const unsigned short* __restrict__ Vh,
                                            unsigned short* __restrict__ Vt) {
  __shared__ unsigned short tile[64][65];
  const int bh = blockIdx.y;
  const int s0 = blockIdx.x * 64;
  const unsigned short* src = Vh + ((size_t)bh * kSKV + s0) * 64;
  for (int i = threadIdx.x; i < 4096; i += 256) {
    int r = i >> 6, c = i & 63;
    tile[r][c] = src[(size_t)r * 64 + c];
  }
  __syncthreads();
  unsigned short* dst = Vt + (size_t)bh * 64 * kSKV + s0;
  for (int i = threadIdx.x; i < 4096; i += 256) {
    int r = i >> 6, c = i & 63;
    dst[(size_t)r * kSKV + c] = tile[c][r];
  }
}

// ---------------------------------------------------------------------------
// Kernel 5: flash attention, QBLK=128 (4 waves x 32 q-rows), KV tiles of 64.
// Fixed-max softmax via exp2 (Q pre-scaled by log2e/8). Conflict-free
// 16B-unit XOR swizzle on K/V/P. (round-3 structure: dbuf + syncthreads)
__global__ __launch_bounds__(256) void k_attn(
    const unsigned short* __restrict__ Qh, const unsigned short* __restrict__ Kh,
    const unsigned short* __restrict__ Vt, unsigned short* __restrict__ Obf) {
  __shared__ unsigned short lK[2][4096];
  __shared__ unsigned short lV[2][4096];
  __shared__ __align__(16) unsigned short lP[4][1024];

  const int bid = blockIdx.x + 16 * blockIdx.y;              // 1024 blocks
  const int rid = (bid & 7) * 128 + (bid >> 3);
  const int q0 = (rid & 15) * 128;
  const int bh = rid >> 4;

  const int tid = threadIdx.x;
  const int l = tid & 63, w = tid >> 6;
  const int lr = l & 15, lk = l >> 4;
  const int m7 = lr & 7;
  const int lkh = lk >> 1, lkb = lk & 1;

  const unsigned short* Qb = Qh + (size_t)bh * kSQ * 64;
  const unsigned short* Kb = Kh + (size_t)bh * kSKV * 64;
  const unsigned short* Vb = Vt + (size_t)bh * 64 * kSKV;

  const float QS = 0.125f * 1.4426950408889634f;
  bf16x8 qf[2][2];
#pragma unroll
  for (int m = 0; m < 2; ++m)
#pragma unroll
    for (int kk = 0; kk < 2; ++kk) {
      bf16x8 v = *(const bf16x8*)
          &Qb[(size_t)(q0 + w * 32 + m * 16 + lr) * 64 + kk * 32 + lk * 8];
#pragma unroll
      for (int j = 0; j < 8; ++j) {
        unsigned short u = (unsigned short)v[j];
        v[j] = (short)f2bf(bf2f(u) * QS);
      }
      qf[m][kk] = v;
    }

  f32x4 oacc[2][4];
  const f32x4 zero = {0.f, 0.f, 0.f, 0.f};
#pragma unroll
  for (int m = 0; m < 2; ++m)
#pragma unroll
    for (int n = 0; n < 4; ++n) oacc[m][n] = zero;
  float lrow[2] = {0.f, 0.f};

  const int sr8 = l >> 3;
  const int su = (l & 7) ^ sr8;
  unsigned short* lPw = lP[w];

#define ASTAGE(dbuf, tile) do { \
    _Pragma("unroll") for (int cc = 0; cc < 2; ++cc) { \
      const int c = 2 * w + cc; const int row = c * 8 + sr8; \
      gload16(Kb + (size_t)((tile) * 64 + row) * 64 + su * 8, &lK[dbuf][c * 512]); \
      gload16(Vb + (size_t)row * kSKV + (tile) * 64 + su * 8, &lV[dbuf][c * 512]); \
    } } while (0)

  ASTAGE(0, 0);
  __syncthreads();

#pragma unroll 2
  for (int kt = 0; kt < 32; ++kt) {
    const int cur = kt & 1;
    if (kt < 31) ASTAGE(cur ^ 1, kt + 1);
    const unsigned short* bufK = lK[cur];
    const unsigned short* bufV = lV[cur];

    bf16x8 kf[4][2];
#pragma unroll
    for (int n = 0; n < 4; ++n)
#pragma unroll
      for (int kk = 0; kk < 2; ++kk) {
        const int ub = (kk * 4 + lk) ^ m7;
        kf[n][kk] = *(const bf16x8*)&bufK[(n * 16 + lr) * 64 + ub * 8];
      }

    f32x4 s0[4];
#pragma unroll
    for (int n = 0; n < 4; ++n) s0[n] = zero;
    __builtin_amdgcn_s_setprio(1);
#pragma unroll
    for (int kk = 0; kk < 2; ++kk)
#pragma unroll
      for (int n = 0; n < 4; ++n)
        s0[n] = __builtin_amdgcn_mfma_f32_16x16x32_bf16(kf[n][kk], qf[0][kk],
                                                        s0[n], 0, 0, 0);
    __builtin_amdgcn_s_setprio(0);
    float ls0 = 0.f;
#pragma unroll
    for (int n = 0; n < 4; ++n) {
      const float p0 = vexp2(s0[n][0]);
      const float p1 = vexp2(s0[n][1]);
      const float p2 = vexp2(s0[n][2]);
      const float p3 = vexp2(s0[n][3]);
      ls0 += (p0 + p1) + (p2 + p3);
      uint2 pv; pv.x = cvtpk(p0, p1); pv.y = cvtpk(p2, p3);
      *(uint2*)&lPw[lr * 64 + (((2 * n + lkh) ^ m7) << 3) + lkb * 4] = pv;
    }
    lrow[0] += ls0;

    f32x4 s1[4];
#pragma unroll
    for (int n = 0; n < 4; ++n) s1[n] = zero;
    __builtin_amdgcn_s_setprio(1);
#pragma unroll
    for (int kk = 0; kk < 2; ++kk)
#pragma unroll
      for (int n = 0; n < 4; ++n)
        s1[n] = __builtin_amdgcn_mfma_f32_16x16x32_bf16(kf[n][kk], qf[1][kk],
                                                        s1[n], 0, 0, 0);
    __builtin_amdgcn_s_setprio(0);
    float ls1 = 0.f;
    uint2 pw1[4];
#pragma unroll
    for (int n = 0; n < 4; ++n) {
      const float p0 = vexp2(s1[n][0]);
      const float p1 = vexp2(s1[n][1]);
      const float p2 = vexp2(s1[n][2]);
      const float p3 = vexp2(s1[n][3]);
      ls1 += (p0 + p1) + (p2 + p3);
      pw1[n].x = cvtpk(p0, p1); pw1[n].y = cvtpk(p2, p3);
    }
    lrow[1] += ls1;

    bf16x8 pf0[2], pf1[2];
#pragma unroll
    for (int kk = 0; kk < 2; ++kk)
      pf0[kk] = *(const bf16x8*)&lPw[lr * 64 + (((kk * 4 + lk) ^ m7) << 3)];
#pragma unroll
    for (int n = 0; n < 4; ++n)
      *(uint2*)&lPw[lr * 64 + (((2 * n + lkh) ^ m7) << 3) + lkb * 4] = pw1[n];
#pragma unroll
    for (int kk = 0; kk < 2; ++kk)
      pf1[kk] = *(const bf16x8*)&lPw[lr * 64 + (((kk * 4 + lk) ^ m7) << 3)];

    __builtin_amdgcn_s_setprio(1);
#pragma unroll
    for (int n = 0; n < 4; ++n)
#pragma unroll
      for (int kk = 0; kk < 2; ++kk) {
        const int ub = (kk * 4 + lk) ^ m7;
        bf16x8 vf = *(const bf16x8*)&bufV[(n * 16 + lr) * 64 + ub * 8];
        oacc[0][n] = __builtin_amdgcn_mfma_f32_16x16x32_bf16(pf0[kk], vf,
                                                             oacc[0][n], 0, 0, 0);
        oacc[1][n] = __builtin_amdgcn_mfma_f32_16x16x32_bf16(pf1[kk], vf,
                                                             oacc[1][n], 0, 0, 0);
      }
    __builtin_amdgcn_s_setprio(0);

    __syncthreads();
  }
#undef ASTAGE

  float rinv[2][4];
#pragma unroll
  for (int m = 0; m < 2; ++m) {
    float s = lrow[m];
    s += __shfl_xor(s, 16);
    s += __shfl_xor(s, 32);
#pragma unroll
    for (int r = 0; r < 4; ++r) rinv[m][r] = 1.0f / __shfl(s, lk * 4 + r);
  }

  const int b = bh >> 4, h = bh & 15;
#pragma unroll
  for (int m = 0; m < 2; ++m)
#pragma unroll
    for (int n = 0; n < 4; ++n)
#pragma unroll
      for (int r = 0; r < 4; ++r) {
        const int qrow = q0 + w * 32 + m * 16 + lk * 4 + r;
        const int d = n * 16 + lr;
        Obf[((size_t)b * kSQ + qrow) * kD + h * 64 + d] =
            f2bf(oacc[m][n][r] * rinv[m][r]);
      }
}

// ---------------------------------------------------------------------------
extern "C" void kernel_launch(void* const* d_in, const int* in_sizes, int n_in,
                              void* d_out, int out_size, void* d_ws, size_t ws_size,
                              hipStream_t stream) {
  (void)in_sizes; (void)n_in; (void)out_size; (void)ws_size;
  const float* hs   = (const float*)d_in[0];
  const float* enc  = (const float*)d_in[1];
  const float* Wq   = (const float*)d_in[2];
  const float* Wk   = (const float*)d_in[3];
  const float* Wv   = (const float*)d_in[4];
  const float* Wo   = (const float*)d_in[5];
  const float* bo   = (const float*)d_in[6];
  const float* q_dn = (const float*)d_in[7];
  const float* q_up = (const float*)d_in[8];
  const float* k_dn = (const float*)d_in[9];
  const float* k_up = (const float*)d_in[10];
  const float* v_dn = (const float*)d_in[11];
  const float* v_up = (const float*)d_in[12];
  const float* o_dn = (const float*)d_in[13];
  const float* o_up = (const float*)d_in[14];

  char* ws = (char*)d_ws;
  size_t off = 0;
  auto alloc = [&](size_t bytes) -> void* {
    void* p = ws + off;
    off += (bytes + 255) & ~(size_t)255;
    return p;
  };
  const size_t ACT = (size_t)kM * kD * 2;
  unsigned short* hsb  = (unsigned short*)alloc(ACT);
  unsigned short* encb = (unsigned short*)alloc(ACT);
  unsigned short* Wqt  = (unsigned short*)alloc((size_t)1024 * 1024 * 2);
  unsigned short* Wkvt = (unsigned short*)alloc((size_t)2048 * 1024 * 2);
  unsigned short* Wot  = (unsigned short*)alloc((size_t)1024 * 1024 * 2);
  unsigned short* Qhp  = (unsigned short*)alloc(ACT);
  unsigned short* Khp  = (unsigned short*)alloc(ACT);
  unsigned short* Vhp  = (unsigned short*)alloc(ACT);
  float* tq  = (float*)alloc((size_t)kM * 4 * 4);
  float* tkv = (float*)alloc((size_t)kM * 8 * 4);
  float* to  = (float*)alloc((size_t)kM * 4 * 4);
  unsigned short* Vtt = hsb;   // alias: V^T reuses hidden bf16 buffer
  unsigned short* Ob  = encb;  // alias: attention O reuses encoder bf16 buffer

  k_prep_wt<<<dim3(2 * kM + 1024), dim3(256), 0, stream>>>(
      hs, enc, Wq, Wk, Wv, Wo, hsb, encb, Wqt, Wkvt, Wot);

  k_lora<<<dim3(128), dim3(256), 0, stream>>>(hsb, q_dn, (const float*)nullptr,
                                              tq, 4);
  k_lora<<<dim3(128), dim3(256), 0, stream>>>(encb, k_dn, v_dn, tkv, 8);

  k_gemm_qkv<<<dim3(768), dim3(512), 0, stream>>>(
      hsb, encb, Wqt, Wkvt, tq, tkv, q_up, k_up, v_up, Qhp, Khp, Vhp);

  k_vt<<<dim3(32, 64), dim3(256), 0, stream>>>(Vhp, Vtt);
  k_attn<<<dim3(16, 64), dim3(256), 0, stream>>>(Qhp, Khp, Vtt, Ob);

  k_lora<<<dim3(128), dim3(256), 0, stream>>>(Ob, o_dn, (const float*)nullptr,
                                              to, 4);

  k_gemm_out<<<dim3(256), dim3(512), 0, stream>>>(Ob, Wot, to, o_up, bo,
                                                  (float*)d_out);
}

// Round 14
// 233.150 us; speedup vs baseline: 1.8137x; 1.0526x over previous
//
#include <hip/hip_runtime.h>
#include <hip/hip_bf16.h>

typedef __attribute__((ext_vector_type(8))) short bf16x8;
typedef __attribute__((ext_vector_type(4))) float f32x4;

#define DEVFN static __device__ __forceinline__

constexpr int kSQ = 2048, kSKV = 2048, kD = 1024, kH = 16;
constexpr int kM = 4 * kSQ;   // 8192 query rows (B*SQ)

DEVFN unsigned short f2bf(float f) {
  union { float f; unsigned u; } v; v.f = f;
  unsigned r = v.u + 0x7FFFu + ((v.u >> 16) & 1u);
  return (unsigned short)(r >> 16);
}
DEVFN float bf2f(unsigned short h) {
  union { unsigned u; float f; } v; v.u = ((unsigned)h) << 16; return v.f;
}
DEVFN unsigned cvtpk(float lo, float hi) {
  unsigned r;
  asm("v_cvt_pk_bf16_f32 %0, %1, %2" : "=v"(r) : "v"(lo), "v"(hi));
  return r;
}
DEVFN float vexp2(float x) {
  float r;
  asm("v_exp_f32 %0, %1" : "=v"(r) : "v"(x));
  return r;
}

DEVFN void gload16(const void* g, void* l) {
  __builtin_amdgcn_global_load_lds(
      (const __attribute__((address_space(1))) unsigned int*)g,
      (__attribute__((address_space(3))) unsigned int*)l, 16, 0, 0);
}

#define WT12 asm volatile("s_waitcnt vmcnt(12)" ::: "memory")
#define WT6  asm volatile("s_waitcnt vmcnt(6)" ::: "memory")
#define WT0  asm volatile("s_waitcnt vmcnt(0)" ::: "memory")

// ---------------------------------------------------------------------------
// Kernel 1: blocks [0, 2*kM): activation fp32->bf16 streaming convert.
// blocks [2*kM, 2*kM+1024): weight convert+transpose (4 weights x 256 tiles).
__global__ __launch_bounds__(256) void k_prep_wt(
    const float* __restrict__ hs, const float* __restrict__ enc,
    const float* __restrict__ Wq, const float* __restrict__ Wk,
    const float* __restrict__ Wv, const float* __restrict__ Wo,
    unsigned short* __restrict__ hsb, unsigned short* __restrict__ encb,
    unsigned short* __restrict__ Wqt, unsigned short* __restrict__ Wkvt,
    unsigned short* __restrict__ Wot) {
  __shared__ unsigned short tile[64][65];
  const int bid = blockIdx.x;
  const int tid = threadIdx.x;

  if (bid < 2 * kM) {
    const bool isH = bid < kM;
    const int rr = isH ? bid : bid - kM;
    const float* srcRow = (isH ? hs : enc) + (size_t)rr * kD;
    unsigned short* dstRow = (isH ? hsb : encb) + (size_t)rr * kD;
    float4 x = reinterpret_cast<const float4*>(srcRow)[tid];
    short4 o;
    o.x = (short)f2bf(x.x); o.y = (short)f2bf(x.y);
    o.z = (short)f2bf(x.z); o.w = (short)f2bf(x.w);
    *reinterpret_cast<short4*>(dstRow + tid * 4) = o;
  } else {
    const int t = bid - 2 * kM;
    const int wid = t >> 8, tt = t & 255;
    const float* W = (wid == 0) ? Wq : (wid == 1) ? Wk : (wid == 2) ? Wv : Wo;
    unsigned short* Wt = (wid == 0) ? Wqt : (wid == 1) ? Wkvt
                        : (wid == 2) ? (Wkvt + (size_t)1024 * 1024) : Wot;
    const int tk0 = (tt & 15) * 64;
    const int tn0 = (tt >> 4) * 64;
    for (int i = tid; i < 4096; i += 256) {
      int r = i >> 6, c = i & 63;
      tile[r][c] = f2bf(W[(size_t)(tk0 + r) * 1024 + tn0 + c]);
    }
    __syncthreads();
    for (int i = tid; i < 4096; i += 256) {
      int r = i >> 6, c = i & 63;
      Wt[(size_t)(tn0 + r) * 1024 + tk0 + c] = tile[c][r];
    }
  }
}

// ---------------------------------------------------------------------------
// Kernel 1b: LoRA-down via MFMA.
__global__ __launch_bounds__(256) void k_lora(
    const unsigned short* __restrict__ X,
    const float* __restrict__ dn0, const float* __restrict__ dn1,
    float* __restrict__ tout, int tstr) {
  __shared__ unsigned short DNT[16][1032];
  const int tid = threadIdx.x;
  const int rbase = (int)blockIdx.x * 64;
  for (int i = tid; i < 16 * 1032; i += 256) DNT[i / 1032][i % 1032] = 0;
  __syncthreads();
  for (int i = tid; i < 4096; i += 256) {
    const int k = i >> 2, c = i & 3;
    DNT[c][k] = f2bf(dn0[i]);
  }
  if (dn1 != nullptr) {
    for (int i = tid; i < 4096; i += 256) {
      const int k = i >> 2, c = i & 3;
      DNT[4 + c][k] = f2bf(dn1[i]);
    }
  }
  __syncthreads();
  const int l = tid & 63, w = tid >> 6;
  const int lr = l & 15, lk = l >> 4;
  const unsigned short* Xr = X + (size_t)(rbase + w * 16 + lr) * 1024 + lk * 8;
  const f32x4 zero = {0.f, 0.f, 0.f, 0.f};
  f32x4 acc0 = zero, acc1 = zero;
#pragma unroll 4
  for (int k0 = 0; k0 < 1024; k0 += 64) {
    bf16x8 a0 = *(const bf16x8*)(Xr + k0);
    bf16x8 b0 = *(const bf16x8*)&DNT[lr][k0 + lk * 8];
    bf16x8 a1 = *(const bf16x8*)(Xr + k0 + 32);
    bf16x8 b1 = *(const bf16x8*)&DNT[lr][k0 + 32 + lk * 8];
    acc0 = __builtin_amdgcn_mfma_f32_16x16x32_bf16(a0, b0, acc0, 0, 0, 0);
    acc1 = __builtin_amdgcn_mfma_f32_16x16x32_bf16(a1, b1, acc1, 0, 0, 0);
  }
  if (lr < tstr) {
#pragma unroll
    for (int r = 0; r < 4; ++r) {
      const int grow = rbase + w * 16 + lk * 4 + r;
      tout[(size_t)grow * tstr + lr] = acc0[r] + acc1[r];
    }
  }
}

// ---------------------------------------------------------------------------
// Big-tile GEMM core: BM=256, BN=128, BK=64, 8 waves (512 thr), 144KB LDS
// TRIPLE-buffer, counted vmcnt 3-deep pipeline, T2 XOR swizzle.

#define GSTAGE(dbuf, kt) do {                                                 \
    _Pragma("unroll")                                                         \
    for (int j = 0; j < 4; ++j) {                                             \
      const int s = (j * 8 + w) * 64 + l;                                     \
      const int row = s >> 3, u = s & 7;                                      \
      gload16(Ap + (size_t)row * 1024 + (kt) * 64 + ((u ^ (row & 7)) * 8),    \
              &lA[dbuf][(j * 8 + w) * 512]);                                  \
    }                                                                         \
    _Pragma("unroll")                                                         \
    for (int j = 0; j < 2; ++j) {                                             \
      const int s = (j * 8 + w) * 64 + l;                                     \
      const int row = s >> 3, u = s & 7;                                      \
      gload16(Bp + (size_t)row * 1024 + (kt) * 64 + ((u ^ (row & 7)) * 8),    \
              &lB[dbuf][(j * 8 + w) * 512]);                                  \
    } } while (0)

#define BIG_GEMM_LOOP(TRANS)                                                  \
  GSTAGE(0, 0);                                                               \
  GSTAGE(1, 1);                                                               \
  GSTAGE(2, 2);                                                               \
  _Pragma("unroll")                                                           \
  for (int kt = 0; kt < 16; ++kt) {                                           \
    const int cur = kt % 3;                                                   \
    if (kt <= 13) { WT12; } else if (kt == 14) { WT6; } else { WT0; }         \
    __builtin_amdgcn_s_barrier();                                             \
    asm volatile("" ::: "memory");                                            \
    _Pragma("unroll")                                                         \
    for (int kk = 0; kk < 2; ++kk) {                                          \
      bf16x8 af[8], bfr[2];                                                   \
      _Pragma("unroll")                                                       \
      for (int m = 0; m < 8; ++m) {                                           \
        const int ar = wr + m * 16 + lr;                                      \
        af[m] = *(const bf16x8*)&lA[cur][ar * 64 +                            \
                 (((kk * 4 + lk) ^ (ar & 7)) * 8)];                           \
      }                                                                       \
      _Pragma("unroll")                                                       \
      for (int n = 0; n < 2; ++n) {                                           \
        const int br = wc + n * 16 + lr;                                      \
        bfr[n] = *(const bf16x8*)&lB[cur][br * 64 +                           \
                 (((kk * 4 + lk) ^ (br & 7)) * 8)];                           \
      }                                                                       \
      __builtin_amdgcn_s_setprio(1);                                          \
      _Pragma("unroll")                                                       \
      for (int m = 0; m < 8; ++m)                                             \
        _Pragma("unroll")                                                     \
        for (int n = 0; n < 2; ++n)                                           \
          acc[m][n] = (TRANS)                                                 \
            ? __builtin_amdgcn_mfma_f32_16x16x32_bf16(bfr[n], af[m],          \
                                                      acc[m][n], 0, 0, 0)     \
            : __builtin_amdgcn_mfma_f32_16x16x32_bf16(af[m], bfr[n],          \
                                                      acc[m][n], 0, 0, 0);    \
      __builtin_amdgcn_s_setprio(0);                                          \
    }                                                                         \
    asm volatile("s_waitcnt lgkmcnt(0)" ::: "memory");                        \
    __builtin_amdgcn_s_barrier();                                             \
    asm volatile("" ::: "memory");                                            \
    if (kt < 13) GSTAGE(cur, kt + 3);                                         \
  }

// Kernel 2: QKV projection. blocks [0,256): Q; [256,768): K|V.
__global__ __launch_bounds__(512, 2) void k_gemm_qkv(
    const unsigned short* __restrict__ hsb, const unsigned short* __restrict__ encb,
    const unsigned short* __restrict__ Wqt, const unsigned short* __restrict__ Wkvt,
    const float* __restrict__ tq, const float* __restrict__ tkv,
    const float* __restrict__ q_up, const float* __restrict__ k_up,
    const float* __restrict__ v_up,
    unsigned short* __restrict__ Qhp, unsigned short* __restrict__ Khp,
    unsigned short* __restrict__ Vhp) {
  __shared__ unsigned short lA[3][256 * 64];
  __shared__ unsigned short lB[3][128 * 64];
  const int tid = threadIdx.x;
  const int l = tid & 63, w = tid >> 6;
  const int bid = blockIdx.x;

  const unsigned short *A, *Bt;
  const float *tmat, *up;
  unsigned short* dst;
  int m0, nB0, nOut0, tstr;
  if (bid < 256) {
    const int rid = (bid & 7) * 32 + (bid >> 3);
    m0 = (rid >> 3) * 256; nB0 = (rid & 7) * 128;
    A = hsb; Bt = Wqt; tmat = tq; tstr = 4; up = q_up; dst = Qhp; nOut0 = nB0;
  } else {
    const int b2 = bid - 256;
    const int rid = (b2 & 7) * 64 + (b2 >> 3);
    m0 = (rid >> 4) * 256; nB0 = (rid & 15) * 128;
    A = encb; Bt = Wkvt; tstr = 8;
    if (nB0 < 1024) { tmat = tkv;     up = k_up; dst = Khp; nOut0 = nB0; }
    else            { tmat = tkv + 4; up = v_up; dst = Vhp; nOut0 = nB0 - 1024; }
  }
  const int wr = (w >> 2) * 128, wc = (w & 3) * 32;
  const int lr = l & 15, lk = l >> 4;
  const unsigned short* Ap = A  + (size_t)m0  * 1024;
  const unsigned short* Bp = Bt + (size_t)nB0 * 1024;

  f32x4 acc[8][2];
  const f32x4 zero = {0.f, 0.f, 0.f, 0.f};
#pragma unroll
  for (int m = 0; m < 8; ++m)
#pragma unroll
    for (int n = 0; n < 2; ++n) acc[m][n] = zero;

  BIG_GEMM_LOOP(1)

  // ---- epilogue: LoRA add + repack via LDS for coalesced stores -----------
  unsigned short* rep = &lA[0][0];
#pragma unroll
  for (int n = 0; n < 2; ++n) {
    const int cb = wc + n * 16 + lk * 4;
    const float4 u0v = *reinterpret_cast<const float4*>(&up[nOut0 + cb]);
    const float4 u1v = *reinterpret_cast<const float4*>(&up[1024 + nOut0 + cb]);
    const float4 u2v = *reinterpret_cast<const float4*>(&up[2048 + nOut0 + cb]);
    const float4 u3v = *reinterpret_cast<const float4*>(&up[3072 + nOut0 + cb]);
    const int u16 = cb >> 3;
    const int bo8 = (lk & 1) * 8;
#pragma unroll
    for (int m = 0; m < 8; ++m) {
      const int row = wr + m * 16 + lr;
      const int grow = m0 + row;
      const float4 tt = *reinterpret_cast<const float4*>(tmat + (size_t)grow * tstr);
      const float v0 = acc[m][n][0] + tt.x * u0v.x + tt.y * u1v.x + tt.z * u2v.x + tt.w * u3v.x;
      const float v1 = acc[m][n][1] + tt.x * u0v.y + tt.y * u1v.y + tt.z * u2v.y + tt.w * u3v.y;
      const float v2 = acc[m][n][2] + tt.x * u0v.z + tt.y * u1v.z + tt.z * u2v.z + tt.w * u3v.z;
      const float v3 = acc[m][n][3] + tt.x * u0v.w + tt.y * u1v.w + tt.z * u2v.w + tt.w * u3v.w;
      uint2 pk; pk.x = cvtpk(v0, v1); pk.y = cvtpk(v2, v3);
      *(uint2*)((char*)rep + row * 256 + ((u16 ^ (row & 7)) << 4) + bo8) = pk;
    }
  }
  __syncthreads();
  const int sub = l & 7;
#pragma unroll
  for (int it = 0; it < 8; ++it) {
    const int g = w * 64 + it * 8 + (l >> 3);
    const int head = g >> 8, row = g & 255;
    const int ju = ((head * 8 + sub) ^ (row & 7)) << 4;
    uint4 val = *(const uint4*)((const char*)rep + row * 256 + ju);
    const int grow = m0 + row;
    const int b = grow >> 11, s = grow & 2047;
    const int hg = (nOut0 >> 6) + head;
    *(uint4*)&dst[(((size_t)(b * kH + hg)) * 2048 + s) * 64 + sub * 8] = val;
  }
}

// Kernel 3: final GEMM  out = Ob @ Wot^T + bias + t_o @ o_up  (f32 output)
__global__ __launch_bounds__(512, 2) void k_gemm_out(
    const unsigned short* __restrict__ A, const unsigned short* __restrict__ Bt,
    const float* __restrict__ tmat, const float* __restrict__ up,
    const float* __restrict__ bias, float* __restrict__ outp) {
  __shared__ unsigned short lA[3][256 * 64];
  __shared__ unsigned short lB[3][128 * 64];
  const int tid = threadIdx.x;
  const int l = tid & 63, w = tid >> 6;
  const int bid = blockIdx.x;
  const int rid = (bid & 7) * 32 + (bid >> 3);
  const int m0 = (rid >> 3) * 256, nB0 = (rid & 7) * 128;
  const int wr = (w >> 2) * 128, wc = (w & 3) * 32;
  const int lr = l & 15, lk = l >> 4;
  const unsigned short* Ap = A  + (size_t)m0  * 1024;
  const unsigned short* Bp = Bt + (size_t)nB0 * 1024;

  f32x4 acc[8][2];
  const f32x4 zero = {0.f, 0.f, 0.f, 0.f};
#pragma unroll
  for (int m = 0; m < 8; ++m)
#pragma unroll
    for (int n = 0; n < 2; ++n) acc[m][n] = zero;

  BIG_GEMM_LOOP(0)

#pragma unroll
  for (int n = 0; n < 2; ++n) {
    const int gcol = nB0 + wc + n * 16 + lr;
    const float u0 = up[gcol], u1 = up[1024 + gcol];
    const float u2 = up[2048 + gcol], u3 = up[3072 + gcol];
    const float bz = bias[gcol];
#pragma unroll
    for (int m = 0; m < 8; ++m) {
#pragma unroll
      for (int r = 0; r < 4; ++r) {
        const int grow = m0 + wr + m * 16 + lk * 4 + r;
        const float4 tt = *reinterpret_cast<const float4*>(tmat + (size_t)grow * 4);
        outp[(size_t)grow * 1024 + gcol] =
            acc[m][n][r] + tt.x * u0 + tt.y * u1 + tt.z * u2 + tt.w * u3 + bz;
      }
    }
  }
}

// ---------------------------------------------------------------------------
// Kernel 4: V head-layout transpose: (bh, s, d) -> (bh, d, s)
__global__ __launch_bounds__(256) void k_vt(const unsigned short* __restrict__ Vh,
                                            unsigned short* __restrict__ Vt) {
  __shared__ unsigned short tile[64][65];
  const int bh = blockIdx.y;
  const int s0 = blockIdx.x * 64;
  const unsigned short* src = Vh + ((size_t)bh * kSKV + s0) * 64;
  for (int i = threadIdx.x; i < 4096; i += 256) {
    int r = i >> 6, c = i & 63;
    tile[r][c] = src[(size_t)r * 64 + c];
  }
  __syncthreads();
  unsigned short* dst = Vt + (size_t)bh * 64 * kSKV + s0;
  for (int i = threadIdx.x; i < 4096; i += 256) {
    int r = i >> 6, c = i & 63;
    dst[(size_t)r * kSKV + c] = tile[c][r];
  }
}

// ---------------------------------------------------------------------------
// Kernel 5: flash attention, QBLK=256 (4 waves x 64 q-rows each), KV tiles
// of 64. K/V fragments loaded once per kt serve 64 q-rows (2x amortization
// vs r13). Fixed-max softmax via exp2; conflict-free 16B-unit XOR swizzle.
__global__ __launch_bounds__(256, 2) void k_attn(
    const unsigned short* __restrict__ Qh, const unsigned short* __restrict__ Kh,
    const unsigned short* __restrict__ Vt, unsigned short* __restrict__ Obf) {
  __shared__ unsigned short lK[2][4096];
  __shared__ unsigned short lV[2][4096];
  __shared__ __align__(16) unsigned short lP[4][1024];

  const int bid = blockIdx.x;                       // 512 blocks
  const int rid = (bid & 7) * 64 + (bid >> 3);      // bijective, 512%8==0
  const int q0 = (rid & 7) * 256;
  const int bh = rid >> 3;

  const int tid = threadIdx.x;
  const int l = tid & 63, w = tid >> 6;
  const int lr = l & 15, lk = l >> 4;
  const int m7 = lr & 7;
  const int lkh = lk >> 1, lkb = lk & 1;

  const unsigned short* Qb = Qh + (size_t)bh * kSQ * 64;
  const unsigned short* Kb = Kh + (size_t)bh * kSKV * 64;
  const unsigned short* Vb = Vt + (size_t)bh * 64 * kSKV;

  const float QS = 0.125f * 1.4426950408889634f;
  bf16x8 qf[4][2];
#pragma unroll
  for (int m = 0; m < 4; ++m)
#pragma unroll
    for (int kk = 0; kk < 2; ++kk) {
      bf16x8 v = *(const bf16x8*)
          &Qb[(size_t)(q0 + w * 64 + m * 16 + lr) * 64 + kk * 32 + lk * 8];
#pragma unroll
      for (int j = 0; j < 8; ++j) {
        unsigned short u = (unsigned short)v[j];
        v[j] = (short)f2bf(bf2f(u) * QS);
      }
      qf[m][kk] = v;
    }

  f32x4 oacc[4][4];
  const f32x4 zero = {0.f, 0.f, 0.f, 0.f};
#pragma unroll
  for (int m = 0; m < 4; ++m)
#pragma unroll
    for (int n = 0; n < 4; ++n) oacc[m][n] = zero;
  float lrow[4] = {0.f, 0.f, 0.f, 0.f};

  const int sr8 = l >> 3;
  const int su = (l & 7) ^ sr8;
  unsigned short* lPw = lP[w];

#define ASTAGE(dbuf, tile) do { \
    _Pragma("unroll") for (int cc = 0; cc < 2; ++cc) { \
      const int c = 2 * w + cc; const int row = c * 8 + sr8; \
      gload16(Kb + (size_t)((tile) * 64 + row) * 64 + su * 8, &lK[dbuf][c * 512]); \
      gload16(Vb + (size_t)row * kSKV + (tile) * 64 + su * 8, &lV[dbuf][c * 512]); \
    } } while (0)

  ASTAGE(0, 0);
  __syncthreads();

  for (int kt = 0; kt < 32; ++kt) {
    const int cur = kt & 1;
    if (kt < 31) ASTAGE(cur ^ 1, kt + 1);
    const unsigned short* bufK = lK[cur];
    const unsigned short* bufV = lV[cur];

    // K fragments: loaded once, serve all 4 q-sub-blocks (64 rows)
    bf16x8 kf[4][2];
#pragma unroll
    for (int n = 0; n < 4; ++n)
#pragma unroll
      for (int kk = 0; kk < 2; ++kk) {
        const int ub = (kk * 4 + lk) ^ m7;
        kf[n][kk] = *(const bf16x8*)&bufK[(n * 16 + lr) * 64 + ub * 8];
      }

    bf16x8 pf[4][2];
#pragma unroll
    for (int mp = 0; mp < 2; ++mp) {
      const int ma = mp * 2, mb = mp * 2 + 1;
      // ---- q-sub-block ma ------------------------------------------------
      f32x4 s0[4];
#pragma unroll
      for (int n = 0; n < 4; ++n) s0[n] = zero;
      __builtin_amdgcn_s_setprio(1);
#pragma unroll
      for (int kk = 0; kk < 2; ++kk)
#pragma unroll
        for (int n = 0; n < 4; ++n)
          s0[n] = __builtin_amdgcn_mfma_f32_16x16x32_bf16(kf[n][kk], qf[ma][kk],
                                                          s0[n], 0, 0, 0);
      __builtin_amdgcn_s_setprio(0);
      float ls0 = 0.f;
#pragma unroll
      for (int n = 0; n < 4; ++n) {
        const float p0 = vexp2(s0[n][0]);
        const float p1 = vexp2(s0[n][1]);
        const float p2 = vexp2(s0[n][2]);
        const float p3 = vexp2(s0[n][3]);
        ls0 += (p0 + p1) + (p2 + p3);
        uint2 pv; pv.x = cvtpk(p0, p1); pv.y = cvtpk(p2, p3);
        *(uint2*)&lPw[lr * 64 + (((2 * n + lkh) ^ m7) << 3) + lkb * 4] = pv;
      }
      lrow[ma] += ls0;

      // ---- q-sub-block mb ------------------------------------------------
      f32x4 s1[4];
#pragma unroll
      for (int n = 0; n < 4; ++n) s1[n] = zero;
      __builtin_amdgcn_s_setprio(1);
#pragma unroll
      for (int kk = 0; kk < 2; ++kk)
#pragma unroll
        for (int n = 0; n < 4; ++n)
          s1[n] = __builtin_amdgcn_mfma_f32_16x16x32_bf16(kf[n][kk], qf[mb][kk],
                                                          s1[n], 0, 0, 0);
      __builtin_amdgcn_s_setprio(0);
      float ls1 = 0.f;
      uint2 pw1[4];
#pragma unroll
      for (int n = 0; n < 4; ++n) {
        const float p0 = vexp2(s1[n][0]);
        const float p1 = vexp2(s1[n][1]);
        const float p2 = vexp2(s1[n][2]);
        const float p3 = vexp2(s1[n][3]);
        ls1 += (p0 + p1) + (p2 + p3);
        pw1[n].x = cvtpk(p0, p1); pw1[n].y = cvtpk(p2, p3);
      }
      lrow[mb] += ls1;

      // read P(ma) (write latency covered by QK-mb), write P(mb), read P(mb)
#pragma unroll
      for (int kk = 0; kk < 2; ++kk)
        pf[ma][kk] = *(const bf16x8*)&lPw[lr * 64 + (((kk * 4 + lk) ^ m7) << 3)];
#pragma unroll
      for (int n = 0; n < 4; ++n)
        *(uint2*)&lPw[lr * 64 + (((2 * n + lkh) ^ m7) << 3) + lkb * 4] = pw1[n];
#pragma unroll
      for (int kk = 0; kk < 2; ++kk)
        pf[mb][kk] = *(const bf16x8*)&lPw[lr * 64 + (((kk * 4 + lk) ^ m7) << 3)];
    }

    // ---- O += P @ V : each vf load feeds 4 MFMAs (one per sub-block) -----
    __builtin_amdgcn_s_setprio(1);
#pragma unroll
    for (int n = 0; n < 4; ++n)
#pragma unroll
      for (int kk = 0; kk < 2; ++kk) {
        const int ub = (kk * 4 + lk) ^ m7;
        bf16x8 vf = *(const bf16x8*)&bufV[(n * 16 + lr) * 64 + ub * 8];
#pragma unroll
        for (int m = 0; m < 4; ++m)
          oacc[m][n] = __builtin_amdgcn_mfma_f32_16x16x32_bf16(pf[m][kk], vf,
                                                               oacc[m][n], 0, 0, 0);
      }
    __builtin_amdgcn_s_setprio(0);

    __syncthreads();
  }
#undef ASTAGE

  float rinv[4][4];
#pragma unroll
  for (int m = 0; m < 4; ++m) {
    float s = lrow[m];
    s += __shfl_xor(s, 16);
    s += __shfl_xor(s, 32);
#pragma unroll
    for (int r = 0; r < 4; ++r) rinv[m][r] = 1.0f / __shfl(s, lk * 4 + r);
  }

  const int b = bh >> 4, h = bh & 15;
#pragma unroll
  for (int m = 0; m < 4; ++m)
#pragma unroll
    for (int n = 0; n < 4; ++n)
#pragma unroll
      for (int r = 0; r < 4; ++r) {
        const int qrow = q0 + w * 64 + m * 16 + lk * 4 + r;
        const int d = n * 16 + lr;
        Obf[((size_t)b * kSQ + qrow) * kD + h * 64 + d] =
            f2bf(oacc[m][n][r] * rinv[m][r]);
      }
}

// ---------------------------------------------------------------------------
extern "C" void kernel_launch(void* const* d_in, const int* in_sizes, int n_in,
                              void* d_out, int out_size, void* d_ws, size_t ws_size,
                              hipStream_t stream) {
  (void)in_sizes; (void)n_in; (void)out_size; (void)ws_size;
  const float* hs   = (const float*)d_in[0];
  const float* enc  = (const float*)d_in[1];
  const float* Wq   = (const float*)d_in[2];
  const float* Wk   = (const float*)d_in[3];
  const float* Wv   = (const float*)d_in[4];
  const float* Wo   = (const float*)d_in[5];
  const float* bo   = (const float*)d_in[6];
  const float* q_dn = (const float*)d_in[7];
  const float* q_up = (const float*)d_in[8];
  const float* k_dn = (const float*)d_in[9];
  const float* k_up = (const float*)d_in[10];
  const float* v_dn = (const float*)d_in[11];
  const float* v_up = (const float*)d_in[12];
  const float* o_dn = (const float*)d_in[13];
  const float* o_up = (const float*)d_in[14];

  char* ws = (char*)d_ws;
  size_t off = 0;
  auto alloc = [&](size_t bytes) -> void* {
    void* p = ws + off;
    off += (bytes + 255) & ~(size_t)255;
    return p;
  };
  const size_t ACT = (size_t)kM * kD * 2;
  unsigned short* hsb  = (unsigned short*)alloc(ACT);
  unsigned short* encb = (unsigned short*)alloc(ACT);
  unsigned short* Wqt  = (unsigned short*)alloc((size_t)1024 * 1024 * 2);
  unsigned short* Wkvt = (unsigned short*)alloc((size_t)2048 * 1024 * 2);
  unsigned short* Wot  = (unsigned short*)alloc((size_t)1024 * 1024 * 2);
  unsigned short* Qhp  = (unsigned short*)alloc(ACT);
  unsigned short* Khp  = (unsigned short*)alloc(ACT);
  unsigned short* Vhp  = (unsigned short*)alloc(ACT);
  float* tq  = (float*)alloc((size_t)kM * 4 * 4);
  float* tkv = (float*)alloc((size_t)kM * 8 * 4);
  float* to  = (float*)alloc((size_t)kM * 4 * 4);
  unsigned short* Vtt = hsb;   // alias: V^T reuses hidden bf16 buffer
  unsigned short* Ob  = encb;  // alias: attention O reuses encoder bf16 buffer

  k_prep_wt<<<dim3(2 * kM + 1024), dim3(256), 0, stream>>>(
      hs, enc, Wq, Wk, Wv, Wo, hsb, encb, Wqt, Wkvt, Wot);

  k_lora<<<dim3(128), dim3(256), 0, stream>>>(hsb, q_dn, (const float*)nullptr,
                                              tq, 4);
  k_lora<<<dim3(128), dim3(256), 0, stream>>>(encb, k_dn, v_dn, tkv, 8);

  k_gemm_qkv<<<dim3(768), dim3(512), 0, stream>>>(
      hsb, encb, Wqt, Wkvt, tq, tkv, q_up, k_up, v_up, Qhp, Khp, Vhp);

  k_vt<<<dim3(32, 64), dim3(256), 0, stream>>>(Vhp, Vtt);
  k_attn<<<dim3(512), dim3(256), 0, stream>>>(Qhp, Khp, Vtt, Ob);

  k_lora<<<dim3(128), dim3(256), 0, stream>>>(Ob, o_dn, (const float*)nullptr,
                                              to, 4);

  k_gemm_out<<<dim3(256), dim3(512), 0, stream>>>(Ob, Wot, to, o_up, bo,
                                                  (float*)d_out);
}

// Round 16
// 232.400 us; speedup vs baseline: 1.8195x; 1.0032x over previous
//
#include <hip/hip_runtime.h>
#include <hip/hip_bf16.h>

typedef __attribute__((ext_vector_type(8))) short bf16x8;
typedef __attribute__((ext_vector_type(4))) float f32x4;

#define DEVFN static __device__ __forceinline__

constexpr int kSQ = 2048, kSKV = 2048, kD = 1024, kH = 16;
constexpr int kM = 4 * kSQ;   // 8192 query rows (B*SQ)

DEVFN unsigned short f2bf(float f) {
  union { float f; unsigned u; } v; v.f = f;
  unsigned r = v.u + 0x7FFFu + ((v.u >> 16) & 1u);
  return (unsigned short)(r >> 16);
}
DEVFN float bf2f(unsigned short h) {
  union { unsigned u; float f; } v; v.u = ((unsigned)h) << 16; return v.f;
}
DEVFN unsigned cvtpk(float lo, float hi) {
  unsigned r;
  asm("v_cvt_pk_bf16_f32 %0, %1, %2" : "=v"(r) : "v"(lo), "v"(hi));
  return r;
}
DEVFN float vexp2(float x) {
  float r;
  asm("v_exp_f32 %0, %1" : "=v"(r) : "v"(x));
  return r;
}

DEVFN void gload16(const void* g, void* l) {
  __builtin_amdgcn_global_load_lds(
      (const __attribute__((address_space(1))) unsigned int*)g,
      (__attribute__((address_space(3))) unsigned int*)l, 16, 0, 0);
}

#define WT12 asm volatile("s_waitcnt vmcnt(12)" ::: "memory")
#define WT6  asm volatile("s_waitcnt vmcnt(6)" ::: "memory")
#define WT0  asm volatile("s_waitcnt vmcnt(0)" ::: "memory")

// ---------------------------------------------------------------------------
// Kernel 1: blocks [0, 2*kM): activation fp32->bf16 streaming convert.
// blocks [2*kM, 2*kM+1024): weight convert+transpose (4 weights x 256 tiles).
__global__ __launch_bounds__(256) void k_prep_wt(
    const float* __restrict__ hs, const float* __restrict__ enc,
    const float* __restrict__ Wq, const float* __restrict__ Wk,
    const float* __restrict__ Wv, const float* __restrict__ Wo,
    unsigned short* __restrict__ hsb, unsigned short* __restrict__ encb,
    unsigned short* __restrict__ Wqt, unsigned short* __restrict__ Wkvt,
    unsigned short* __restrict__ Wot) {
  __shared__ unsigned short tile[64][65];
  const int bid = blockIdx.x;
  const int tid = threadIdx.x;

  if (bid < 2 * kM) {
    const bool isH = bid < kM;
    const int rr = isH ? bid : bid - kM;
    const float* srcRow = (isH ? hs : enc) + (size_t)rr * kD;
    unsigned short* dstRow = (isH ? hsb : encb) + (size_t)rr * kD;
    float4 x = reinterpret_cast<const float4*>(srcRow)[tid];
    short4 o;
    o.x = (short)f2bf(x.x); o.y = (short)f2bf(x.y);
    o.z = (short)f2bf(x.z); o.w = (short)f2bf(x.w);
    *reinterpret_cast<short4*>(dstRow + tid * 4) = o;
  } else {
    const int t = bid - 2 * kM;
    const int wid = t >> 8, tt = t & 255;
    const float* W = (wid == 0) ? Wq : (wid == 1) ? Wk : (wid == 2) ? Wv : Wo;
    unsigned short* Wt = (wid == 0) ? Wqt : (wid == 1) ? Wkvt
                        : (wid == 2) ? (Wkvt + (size_t)1024 * 1024) : Wot;
    const int tk0 = (tt & 15) * 64;
    const int tn0 = (tt >> 4) * 64;
    for (int i = tid; i < 4096; i += 256) {
      int r = i >> 6, c = i & 63;
      tile[r][c] = f2bf(W[(size_t)(tk0 + r) * 1024 + tn0 + c]);
    }
    __syncthreads();
    for (int i = tid; i < 4096; i += 256) {
      int r = i >> 6, c = i & 63;
      Wt[(size_t)(tn0 + r) * 1024 + tk0 + c] = tile[c][r];
    }
  }
}

// ---------------------------------------------------------------------------
// Kernel 1b: LoRA-down via MFMA.
__global__ __launch_bounds__(256) void k_lora(
    const unsigned short* __restrict__ X,
    const float* __restrict__ dn0, const float* __restrict__ dn1,
    float* __restrict__ tout, int tstr) {
  __shared__ unsigned short DNT[16][1032];
  const int tid = threadIdx.x;
  const int rbase = (int)blockIdx.x * 64;
  for (int i = tid; i < 16 * 1032; i += 256) DNT[i / 1032][i % 1032] = 0;
  __syncthreads();
  for (int i = tid; i < 4096; i += 256) {
    const int k = i >> 2, c = i & 3;
    DNT[c][k] = f2bf(dn0[i]);
  }
  if (dn1 != nullptr) {
    for (int i = tid; i < 4096; i += 256) {
      const int k = i >> 2, c = i & 3;
      DNT[4 + c][k] = f2bf(dn1[i]);
    }
  }
  __syncthreads();
  const int l = tid & 63, w = tid >> 6;
  const int lr = l & 15, lk = l >> 4;
  const unsigned short* Xr = X + (size_t)(rbase + w * 16 + lr) * 1024 + lk * 8;
  const f32x4 zero = {0.f, 0.f, 0.f, 0.f};
  f32x4 acc0 = zero, acc1 = zero;
#pragma unroll 4
  for (int k0 = 0; k0 < 1024; k0 += 64) {
    bf16x8 a0 = *(const bf16x8*)(Xr + k0);
    bf16x8 b0 = *(const bf16x8*)&DNT[lr][k0 + lk * 8];
    bf16x8 a1 = *(const bf16x8*)(Xr + k0 + 32);
    bf16x8 b1 = *(const bf16x8*)&DNT[lr][k0 + 32 + lk * 8];
    acc0 = __builtin_amdgcn_mfma_f32_16x16x32_bf16(a0, b0, acc0, 0, 0, 0);
    acc1 = __builtin_amdgcn_mfma_f32_16x16x32_bf16(a1, b1, acc1, 0, 0, 0);
  }
  if (lr < tstr) {
#pragma unroll
    for (int r = 0; r < 4; ++r) {
      const int grow = rbase + w * 16 + lk * 4 + r;
      tout[(size_t)grow * tstr + lr] = acc0[r] + acc1[r];
    }
  }
}

// ---------------------------------------------------------------------------
// Big-tile GEMM core: BM=256, BN=128, BK=64, 8 waves (512 thr), 144KB LDS
// TRIPLE-buffer, counted vmcnt 3-deep pipeline, T2 XOR swizzle.

#define GSTAGE(dbuf, kt) do {                                                 \
    _Pragma("unroll")                                                         \
    for (int j = 0; j < 4; ++j) {                                             \
      const int s = (j * 8 + w) * 64 + l;                                     \
      const int row = s >> 3, u = s & 7;                                      \
      gload16(Ap + (size_t)row * 1024 + (kt) * 64 + ((u ^ (row & 7)) * 8),    \
              &lA[dbuf][(j * 8 + w) * 512]);                                  \
    }                                                                         \
    _Pragma("unroll")                                                         \
    for (int j = 0; j < 2; ++j) {                                             \
      const int s = (j * 8 + w) * 64 + l;                                     \
      const int row = s >> 3, u = s & 7;                                      \
      gload16(Bp + (size_t)row * 1024 + (kt) * 64 + ((u ^ (row & 7)) * 8),    \
              &lB[dbuf][(j * 8 + w) * 512]);                                  \
    } } while (0)

#define BIG_GEMM_LOOP(TRANS)                                                  \
  GSTAGE(0, 0);                                                               \
  GSTAGE(1, 1);                                                               \
  GSTAGE(2, 2);                                                               \
  _Pragma("unroll")                                                           \
  for (int kt = 0; kt < 16; ++kt) {                                           \
    const int cur = kt % 3;                                                   \
    if (kt <= 13) { WT12; } else if (kt == 14) { WT6; } else { WT0; }         \
    __builtin_amdgcn_s_barrier();                                             \
    asm volatile("" ::: "memory");                                            \
    _Pragma("unroll")                                                         \
    for (int kk = 0; kk < 2; ++kk) {                                          \
      bf16x8 af[8], bfr[2];                                                   \
      _Pragma("unroll")                                                       \
      for (int m = 0; m < 8; ++m) {                                           \
        const int ar = wr + m * 16 + lr;                                      \
        af[m] = *(const bf16x8*)&lA[cur][ar * 64 +                            \
                 (((kk * 4 + lk) ^ (ar & 7)) * 8)];                           \
      }                                                                       \
      _Pragma("unroll")                                                       \
      for (int n = 0; n < 2; ++n) {                                           \
        const int br = wc + n * 16 + lr;                                      \
        bfr[n] = *(const bf16x8*)&lB[cur][br * 64 +                           \
                 (((kk * 4 + lk) ^ (br & 7)) * 8)];                           \
      }                                                                       \
      __builtin_amdgcn_s_setprio(1);                                          \
      _Pragma("unroll")                                                       \
      for (int m = 0; m < 8; ++m)                                             \
        _Pragma("unroll")                                                     \
        for (int n = 0; n < 2; ++n)                                           \
          acc[m][n] = (TRANS)                                                 \
            ? __builtin_amdgcn_mfma_f32_16x16x32_bf16(bfr[n], af[m],          \
                                                      acc[m][n], 0, 0, 0)     \
            : __builtin_amdgcn_mfma_f32_16x16x32_bf16(af[m], bfr[n],          \
                                                      acc[m][n], 0, 0, 0);    \
      __builtin_amdgcn_s_setprio(0);                                          \
    }                                                                         \
    asm volatile("s_waitcnt lgkmcnt(0)" ::: "memory");                        \
    __builtin_amdgcn_s_barrier();                                             \
    asm volatile("" ::: "memory");                                            \
    if (kt < 13) GSTAGE(cur, kt + 3);                                         \
  }

// Kernel 2: QKV projection. blocks [0,256): Q; [256,768): K|V.
__global__ __launch_bounds__(512, 2) void k_gemm_qkv(
    const unsigned short* __restrict__ hsb, const unsigned short* __restrict__ encb,
    const unsigned short* __restrict__ Wqt, const unsigned short* __restrict__ Wkvt,
    const float* __restrict__ tq, const float* __restrict__ tkv,
    const float* __restrict__ q_up, const float* __restrict__ k_up,
    const float* __restrict__ v_up,
    unsigned short* __restrict__ Qhp, unsigned short* __restrict__ Khp,
    unsigned short* __restrict__ Vhp) {
  __shared__ unsigned short lA[3][256 * 64];
  __shared__ unsigned short lB[3][128 * 64];
  const int tid = threadIdx.x;
  const int l = tid & 63, w = tid >> 6;
  const int bid = blockIdx.x;

  const unsigned short *A, *Bt;
  const float *tmat, *up;
  unsigned short* dst;
  int m0, nB0, nOut0, tstr;
  if (bid < 256) {
    const int rid = (bid & 7) * 32 + (bid >> 3);
    m0 = (rid >> 3) * 256; nB0 = (rid & 7) * 128;
    A = hsb; Bt = Wqt; tmat = tq; tstr = 4; up = q_up; dst = Qhp; nOut0 = nB0;
  } else {
    const int b2 = bid - 256;
    const int rid = (b2 & 7) * 64 + (b2 >> 3);
    m0 = (rid >> 4) * 256; nB0 = (rid & 15) * 128;
    A = encb; Bt = Wkvt; tstr = 8;
    if (nB0 < 1024) { tmat = tkv;     up = k_up; dst = Khp; nOut0 = nB0; }
    else            { tmat = tkv + 4; up = v_up; dst = Vhp; nOut0 = nB0 - 1024; }
  }
  const int wr = (w >> 2) * 128, wc = (w & 3) * 32;
  const int lr = l & 15, lk = l >> 4;
  const unsigned short* Ap = A  + (size_t)m0  * 1024;
  const unsigned short* Bp = Bt + (size_t)nB0 * 1024;

  f32x4 acc[8][2];
  const f32x4 zero = {0.f, 0.f, 0.f, 0.f};
#pragma unroll
  for (int m = 0; m < 8; ++m)
#pragma unroll
    for (int n = 0; n < 2; ++n) acc[m][n] = zero;

  BIG_GEMM_LOOP(1)

  // ---- epilogue: LoRA add + repack via LDS for coalesced stores -----------
  unsigned short* rep = &lA[0][0];
#pragma unroll
  for (int n = 0; n < 2; ++n) {
    const int cb = wc + n * 16 + lk * 4;
    const float4 u0v = *reinterpret_cast<const float4*>(&up[nOut0 + cb]);
    const float4 u1v = *reinterpret_cast<const float4*>(&up[1024 + nOut0 + cb]);
    const float4 u2v = *reinterpret_cast<const float4*>(&up[2048 + nOut0 + cb]);
    const float4 u3v = *reinterpret_cast<const float4*>(&up[3072 + nOut0 + cb]);
    const int u16 = cb >> 3;
    const int bo8 = (lk & 1) * 8;
#pragma unroll
    for (int m = 0; m < 8; ++m) {
      const int row = wr + m * 16 + lr;
      const int grow = m0 + row;
      const float4 tt = *reinterpret_cast<const float4*>(tmat + (size_t)grow * tstr);
      const float v0 = acc[m][n][0] + tt.x * u0v.x + tt.y * u1v.x + tt.z * u2v.x + tt.w * u3v.x;
      const float v1 = acc[m][n][1] + tt.x * u0v.y + tt.y * u1v.y + tt.z * u2v.y + tt.w * u3v.y;
      const float v2 = acc[m][n][2] + tt.x * u0v.z + tt.y * u1v.z + tt.z * u2v.z + tt.w * u3v.z;
      const float v3 = acc[m][n][3] + tt.x * u0v.w + tt.y * u1v.w + tt.z * u2v.w + tt.w * u3v.w;
      uint2 pk; pk.x = cvtpk(v0, v1); pk.y = cvtpk(v2, v3);
      *(uint2*)((char*)rep + row * 256 + ((u16 ^ (row & 7)) << 4) + bo8) = pk;
    }
  }
  __syncthreads();
  const int sub = l & 7;
#pragma unroll
  for (int it = 0; it < 8; ++it) {
    const int g = w * 64 + it * 8 + (l >> 3);
    const int head = g >> 8, row = g & 255;
    const int ju = ((head * 8 + sub) ^ (row & 7)) << 4;
    uint4 val = *(const uint4*)((const char*)rep + row * 256 + ju);
    const int grow = m0 + row;
    const int b = grow >> 11, s = grow & 2047;
    const int hg = (nOut0 >> 6) + head;
    *(uint4*)&dst[(((size_t)(b * kH + hg)) * 2048 + s) * 64 + sub * 8] = val;
  }
}

// Kernel 3: final GEMM  out = Ob @ Wot^T + bias + t_o @ o_up  (f32 output)
__global__ __launch_bounds__(512, 2) void k_gemm_out(
    const unsigned short* __restrict__ A, const unsigned short* __restrict__ Bt,
    const float* __restrict__ tmat, const float* __restrict__ up,
    const float* __restrict__ bias, float* __restrict__ outp) {
  __shared__ unsigned short lA[3][256 * 64];
  __shared__ unsigned short lB[3][128 * 64];
  const int tid = threadIdx.x;
  const int l = tid & 63, w = tid >> 6;
  const int bid = blockIdx.x;
  const int rid = (bid & 7) * 32 + (bid >> 3);
  const int m0 = (rid >> 3) * 256, nB0 = (rid & 7) * 128;
  const int wr = (w >> 2) * 128, wc = (w & 3) * 32;
  const int lr = l & 15, lk = l >> 4;
  const unsigned short* Ap = A  + (size_t)m0  * 1024;
  const unsigned short* Bp = Bt + (size_t)nB0 * 1024;

  f32x4 acc[8][2];
  const f32x4 zero = {0.f, 0.f, 0.f, 0.f};
#pragma unroll
  for (int m = 0; m < 8; ++m)
#pragma unroll
    for (int n = 0; n < 2; ++n) acc[m][n] = zero;

  BIG_GEMM_LOOP(0)

#pragma unroll
  for (int n = 0; n < 2; ++n) {
    const int gcol = nB0 + wc + n * 16 + lr;
    const float u0 = up[gcol], u1 = up[1024 + gcol];
    const float u2 = up[2048 + gcol], u3 = up[3072 + gcol];
    const float bz = bias[gcol];
#pragma unroll
    for (int m = 0; m < 8; ++m) {
#pragma unroll
      for (int r = 0; r < 4; ++r) {
        const int grow = m0 + wr + m * 16 + lk * 4 + r;
        const float4 tt = *reinterpret_cast<const float4*>(tmat + (size_t)grow * 4);
        outp[(size_t)grow * 1024 + gcol] =
            acc[m][n][r] + tt.x * u0 + tt.y * u1 + tt.z * u2 + tt.w * u3 + bz;
      }
    }
  }
}

// ---------------------------------------------------------------------------
// Kernel 4: V head-layout transpose: (bh, s, d) -> (bh, d, s)
__global__ __launch_bounds__(256) void k_vt(const unsigned short* __restrict__ Vh,
                                            unsigned short* __restrict__ Vt) {
  __shared__ unsigned short tile[64][65];
  const int bh = blockIdx.y;
  const int s0 = blockIdx.x * 64;
  const unsigned short* src = Vh + ((size_t)bh * kSKV + s0) * 64;
  for (int i = threadIdx.x; i < 4096; i += 256) {
    int r = i >> 6, c = i & 63;
    tile[r][c] = src[(size_t)r * 64 + c];
  }
  __syncthreads();
  unsigned short* dst = Vt + (size_t)bh * 64 * kSKV + s0;
  for (int i = threadIdx.x; i < 4096; i += 256) {
    int r = i >> 6, c = i & 63;
    dst[(size_t)r * kSKV + c] = tile[c][r];
  }
}

// ---------------------------------------------------------------------------
// Kernel 5: flash attention, QBLK=256 (4 waves x 64 q-rows each), KV tiles
// of 64. K/V fragments loaded once per kt serve 64 q-rows. Fixed-max softmax
// via exp2; conflict-free 16B-unit XOR swizzle.
__global__ __launch_bounds__(256, 2) void k_attn(
    const unsigned short* __restrict__ Qh, const unsigned short* __restrict__ Kh,
    const unsigned short* __restrict__ Vt, unsigned short* __restrict__ Obf) {
  __shared__ unsigned short lK[2][4096];
  __shared__ unsigned short lV[2][4096];
  __shared__ __align__(16) unsigned short lP[4][1024];

  const int bid = blockIdx.x;                       // 512 blocks
  const int rid = (bid & 7) * 64 + (bid >> 3);      // bijective, 512%8==0
  const int q0 = (rid & 7) * 256;
  const int bh = rid >> 3;

  const int tid = threadIdx.x;
  const int l = tid & 63, w = tid >> 6;
  const int lr = l & 15, lk = l >> 4;
  const int m7 = lr & 7;
  const int lkh = lk >> 1, lkb = lk & 1;

  const unsigned short* Qb = Qh + (size_t)bh * kSQ * 64;
  const unsigned short* Kb = Kh + (size_t)bh * kSKV * 64;
  const unsigned short* Vb = Vt + (size_t)bh * 64 * kSKV;

  const float QS = 0.125f * 1.4426950408889634f;
  bf16x8 qf[4][2];
#pragma unroll
  for (int m = 0; m < 4; ++m)
#pragma unroll
    for (int kk = 0; kk < 2; ++kk) {
      bf16x8 v = *(const bf16x8*)
          &Qb[(size_t)(q0 + w * 64 + m * 16 + lr) * 64 + kk * 32 + lk * 8];
#pragma unroll
      for (int j = 0; j < 8; ++j) {
        unsigned short u = (unsigned short)v[j];
        v[j] = (short)f2bf(bf2f(u) * QS);
      }
      qf[m][kk] = v;
    }

  f32x4 oacc[4][4];
  const f32x4 zero = {0.f, 0.f, 0.f, 0.f};
#pragma unroll
  for (int m = 0; m < 4; ++m)
#pragma unroll
    for (int n = 0; n < 4; ++n) oacc[m][n] = zero;
  float lrow[4] = {0.f, 0.f, 0.f, 0.f};

  const int sr8 = l >> 3;
  const int su = (l & 7) ^ sr8;
  unsigned short* lPw = lP[w];

#define ASTAGE(dbuf, tile) do { \
    _Pragma("unroll") for (int cc = 0; cc < 2; ++cc) { \
      const int c = 2 * w + cc; const int row = c * 8 + sr8; \
      gload16(Kb + (size_t)((tile) * 64 + row) * 64 + su * 8, &lK[dbuf][c * 512]); \
      gload16(Vb + (size_t)row * kSKV + (tile) * 64 + su * 8, &lV[dbuf][c * 512]); \
    } } while (0)

  ASTAGE(0, 0);
  __syncthreads();

  for (int kt = 0; kt < 32; ++kt) {
    const int cur = kt & 1;
    if (kt < 31) ASTAGE(cur ^ 1, kt + 1);
    const unsigned short* bufK = lK[cur];
    const unsigned short* bufV = lV[cur];

    // K fragments: loaded once, serve all 4 q-sub-blocks (64 rows)
    bf16x8 kf[4][2];
#pragma unroll
    for (int n = 0; n < 4; ++n)
#pragma unroll
      for (int kk = 0; kk < 2; ++kk) {
        const int ub = (kk * 4 + lk) ^ m7;
        kf[n][kk] = *(const bf16x8*)&bufK[(n * 16 + lr) * 64 + ub * 8];
      }

    bf16x8 pf[4][2];
#pragma unroll
    for (int mp = 0; mp < 2; ++mp) {
      const int ma = mp * 2, mb = mp * 2 + 1;
      // ---- q-sub-block ma ------------------------------------------------
      f32x4 s0[4];
#pragma unroll
      for (int n = 0; n < 4; ++n) s0[n] = zero;
      __builtin_amdgcn_s_setprio(1);
#pragma unroll
      for (int kk = 0; kk < 2; ++kk)
#pragma unroll
        for (int n = 0; n < 4; ++n)
          s0[n] = __builtin_amdgcn_mfma_f32_16x16x32_bf16(kf[n][kk], qf[ma][kk],
                                                          s0[n], 0, 0, 0);
      __builtin_amdgcn_s_setprio(0);
      float ls0 = 0.f;
#pragma unroll
      for (int n = 0; n < 4; ++n) {
        const float p0 = vexp2(s0[n][0]);
        const float p1 = vexp2(s0[n][1]);
        const float p2 = vexp2(s0[n][2]);
        const float p3 = vexp2(s0[n][3]);
        ls0 += (p0 + p1) + (p2 + p3);
        uint2 pv; pv.x = cvtpk(p0, p1); pv.y = cvtpk(p2, p3);
        *(uint2*)&lPw[lr * 64 + (((2 * n + lkh) ^ m7) << 3) + lkb * 4] = pv;
      }
      lrow[ma] += ls0;

      // ---- q-sub-block mb ------------------------------------------------
      f32x4 s1[4];
#pragma unroll
      for (int n = 0; n < 4; ++n) s1[n] = zero;
      __builtin_amdgcn_s_setprio(1);
#pragma unroll
      for (int kk = 0; kk < 2; ++kk)
#pragma unroll
        for (int n = 0; n < 4; ++n)
          s1[n] = __builtin_amdgcn_mfma_f32_16x16x32_bf16(kf[n][kk], qf[mb][kk],
                                                          s1[n], 0, 0, 0);
      __builtin_amdgcn_s_setprio(0);
      float ls1 = 0.f;
      uint2 pw1[4];
#pragma unroll
      for (int n = 0; n < 4; ++n) {
        const float p0 = vexp2(s1[n][0]);
        const float p1 = vexp2(s1[n][1]);
        const float p2 = vexp2(s1[n][2]);
        const float p3 = vexp2(s1[n][3]);
        ls1 += (p0 + p1) + (p2 + p3);
        pw1[n].x = cvtpk(p0, p1); pw1[n].y = cvtpk(p2, p3);
      }
      lrow[mb] += ls1;

      // read P(ma) (write latency covered by QK-mb), write P(mb), read P(mb)
#pragma unroll
      for (int kk = 0; kk < 2; ++kk)
        pf[ma][kk] = *(const bf16x8*)&lPw[lr * 64 + (((kk * 4 + lk) ^ m7) << 3)];
#pragma unroll
      for (int n = 0; n < 4; ++n)
        *(uint2*)&lPw[lr * 64 + (((2 * n + lkh) ^ m7) << 3) + lkb * 4] = pw1[n];
#pragma unroll
      for (int kk = 0; kk < 2; ++kk)
        pf[mb][kk] = *(const bf16x8*)&lPw[lr * 64 + (((kk * 4 + lk) ^ m7) << 3)];
    }

    // ---- O += P @ V : each vf load feeds 4 MFMAs (one per sub-block) -----
    __builtin_amdgcn_s_setprio(1);
#pragma unroll
    for (int n = 0; n < 4; ++n)
#pragma unroll
      for (int kk = 0; kk < 2; ++kk) {
        const int ub = (kk * 4 + lk) ^ m7;
        bf16x8 vf = *(const bf16x8*)&bufV[(n * 16 + lr) * 64 + ub * 8];
#pragma unroll
        for (int m = 0; m < 4; ++m)
          oacc[m][n] = __builtin_amdgcn_mfma_f32_16x16x32_bf16(pf[m][kk], vf,
                                                               oacc[m][n], 0, 0, 0);
      }
    __builtin_amdgcn_s_setprio(0);

    __syncthreads();
  }
#undef ASTAGE

  float rinv[4][4];
#pragma unroll
  for (int m = 0; m < 4; ++m) {
    float s = lrow[m];
    s += __shfl_xor(s, 16);
    s += __shfl_xor(s, 32);
#pragma unroll
    for (int r = 0; r < 4; ++r) rinv[m][r] = 1.0f / __shfl(s, lk * 4 + r);
  }

  const int b = bh >> 4, h = bh & 15;
#pragma unroll
  for (int m = 0; m < 4; ++m)
#pragma unroll
    for (int n = 0; n < 4; ++n)
#pragma unroll
      for (int r = 0; r < 4; ++r) {
        const int qrow = q0 + w * 64 + m * 16 + lk * 4 + r;
        const int d = n * 16 + lr;
        Obf[((size_t)b * kSQ + qrow) * kD + h * 64 + d] =
            f2bf(oacc[m][n][r] * rinv[m][r]);
      }
}

// ---------------------------------------------------------------------------
extern "C" void kernel_launch(void* const* d_in, const int* in_sizes, int n_in,
                              void* d_out, int out_size, void* d_ws, size_t ws_size,
                              hipStream_t stream) {
  (void)in_sizes; (void)n_in; (void)out_size; (void)ws_size;
  const float* hs   = (const float*)d_in[0];
  const float* enc  = (const float*)d_in[1];
  const float* Wq   = (const float*)d_in[2];
  const float* Wk   = (const float*)d_in[3];
  const float* Wv   = (const float*)d_in[4];
  const float* Wo   = (const float*)d_in[5];
  const float* bo   = (const float*)d_in[6];
  const float* q_dn = (const float*)d_in[7];
  const float* q_up = (const float*)d_in[8];
  const float* k_dn = (const float*)d_in[9];
  const float* k_up = (const float*)d_in[10];
  const float* v_dn = (const float*)d_in[11];
  const float* v_up = (const float*)d_in[12];
  const float* o_dn = (const float*)d_in[13];
  const float* o_up = (const float*)d_in[14];

  char* ws = (char*)d_ws;
  size_t off = 0;
  auto alloc = [&](size_t bytes) -> void* {
    void* p = ws + off;
    off += (bytes + 255) & ~(size_t)255;
    return p;
  };
  const size_t ACT = (size_t)kM * kD * 2;
  unsigned short* hsb  = (unsigned short*)alloc(ACT);
  unsigned short* encb = (unsigned short*)alloc(ACT);
  unsigned short* Wqt  = (unsigned short*)alloc((size_t)1024 * 1024 * 2);
  unsigned short* Wkvt = (unsigned short*)alloc((size_t)2048 * 1024 * 2);
  unsigned short* Wot  = (unsigned short*)alloc((size_t)1024 * 1024 * 2);
  unsigned short* Qhp  = (unsigned short*)alloc(ACT);
  unsigned short* Khp  = (unsigned short*)alloc(ACT);
  unsigned short* Vhp  = (unsigned short*)alloc(ACT);
  float* tq  = (float*)alloc((size_t)kM * 4 * 4);
  float* tkv = (float*)alloc((size_t)kM * 8 * 4);
  float* to  = (float*)alloc((size_t)kM * 4 * 4);
  unsigned short* Vtt = hsb;   // alias: V^T reuses hidden bf16 buffer
  unsigned short* Ob  = encb;  // alias: attention O reuses encoder bf16 buffer

  k_prep_wt<<<dim3(2 * kM + 1024), dim3(256), 0, stream>>>(
      hs, enc, Wq, Wk, Wv, Wo, hsb, encb, Wqt, Wkvt, Wot);

  k_lora<<<dim3(128), dim3(256), 0, stream>>>(hsb, q_dn, (const float*)nullptr,
                                              tq, 4);
  k_lora<<<dim3(128), dim3(256), 0, stream>>>(encb, k_dn, v_dn, tkv, 8);

  k_gemm_qkv<<<dim3(768), dim3(512), 0, stream>>>(
      hsb, encb, Wqt, Wkvt, tq, tkv, q_up, k_up, v_up, Qhp, Khp, Vhp);

  k_vt<<<dim3(32, 64), dim3(256), 0, stream>>>(Vhp, Vtt);
  k_attn<<<dim3(512), dim3(256), 0, stream>>>(Qhp, Khp, Vtt, Ob);

  k_lora<<<dim3(128), dim3(256), 0, stream>>>(Ob, o_dn, (const float*)nullptr,
                                              to, 4);

  k_gemm_out<<<dim3(256), dim3(512), 0, stream>>>(Ob, Wot, to, o_up, bo,
                                                  (float*)d_out);
}

// Round 17
// 226.554 us; speedup vs baseline: 1.8665x; 1.0258x over previous
//
#include <hip/hip_runtime.h>
#include <hip/hip_bf16.h>

typedef __attribute__((ext_vector_type(8))) short bf16x8;
typedef __attribute__((ext_vector_type(4))) float f32x4;

#define DEVFN static __device__ __forceinline__

constexpr int kSQ = 2048, kSKV = 2048, kD = 1024, kH = 16;
constexpr int kM = 4 * kSQ;   // 8192 query rows (B*SQ)

DEVFN unsigned short f2bf(float f) {
  union { float f; unsigned u; } v; v.f = f;
  unsigned r = v.u + 0x7FFFu + ((v.u >> 16) & 1u);
  return (unsigned short)(r >> 16);
}
DEVFN float bf2f(unsigned short h) {
  union { unsigned u; float f; } v; v.u = ((unsigned)h) << 16; return v.f;
}
DEVFN unsigned cvtpk(float lo, float hi) {
  unsigned r;
  asm("v_cvt_pk_bf16_f32 %0, %1, %2" : "=v"(r) : "v"(lo), "v"(hi));
  return r;
}
DEVFN float vexp2(float x) {
  float r;
  asm("v_exp_f32 %0, %1" : "=v"(r) : "v"(x));
  return r;
}

DEVFN void gload16(const void* g, void* l) {
  __builtin_amdgcn_global_load_lds(
      (const __attribute__((address_space(1))) unsigned int*)g,
      (__attribute__((address_space(3))) unsigned int*)l, 16, 0, 0);
}

#define WT12 asm volatile("s_waitcnt vmcnt(12)" ::: "memory")
#define WT6  asm volatile("s_waitcnt vmcnt(6)" ::: "memory")
#define WT0  asm volatile("s_waitcnt vmcnt(0)" ::: "memory")

// ---------------------------------------------------------------------------
// Kernel 1: blocks [0, 2*kM): activation fp32->bf16 streaming convert.
// blocks [2*kM, 2*kM+1024): weight convert+transpose (4 weights x 256 tiles).
__global__ __launch_bounds__(256) void k_prep_wt(
    const float* __restrict__ hs, const float* __restrict__ enc,
    const float* __restrict__ Wq, const float* __restrict__ Wk,
    const float* __restrict__ Wv, const float* __restrict__ Wo,
    unsigned short* __restrict__ hsb, unsigned short* __restrict__ encb,
    unsigned short* __restrict__ Wqt, unsigned short* __restrict__ Wkvt,
    unsigned short* __restrict__ Wot) {
  __shared__ unsigned short tile[64][65];
  const int bid = blockIdx.x;
  const int tid = threadIdx.x;

  if (bid < 2 * kM) {
    const bool isH = bid < kM;
    const int rr = isH ? bid : bid - kM;
    const float* srcRow = (isH ? hs : enc) + (size_t)rr * kD;
    unsigned short* dstRow = (isH ? hsb : encb) + (size_t)rr * kD;
    float4 x = reinterpret_cast<const float4*>(srcRow)[tid];
    short4 o;
    o.x = (short)f2bf(x.x); o.y = (short)f2bf(x.y);
    o.z = (short)f2bf(x.z); o.w = (short)f2bf(x.w);
    *reinterpret_cast<short4*>(dstRow + tid * 4) = o;
  } else {
    const int t = bid - 2 * kM;
    const int wid = t >> 8, tt = t & 255;
    const float* W = (wid == 0) ? Wq : (wid == 1) ? Wk : (wid == 2) ? Wv : Wo;
    unsigned short* Wt = (wid == 0) ? Wqt : (wid == 1) ? Wkvt
                        : (wid == 2) ? (Wkvt + (size_t)1024 * 1024) : Wot;
    const int tk0 = (tt & 15) * 64;
    const int tn0 = (tt >> 4) * 64;
    for (int i = tid; i < 4096; i += 256) {
      int r = i >> 6, c = i & 63;
      tile[r][c] = f2bf(W[(size_t)(tk0 + r) * 1024 + tn0 + c]);
    }
    __syncthreads();
    for (int i = tid; i < 4096; i += 256) {
      int r = i >> 6, c = i & 63;
      Wt[(size_t)(tn0 + r) * 1024 + tk0 + c] = tile[c][r];
    }
  }
}

// ---------------------------------------------------------------------------
// Kernel 1b: LoRA-down via MFMA, merged launch. blocks [0,128): tq = hsb@q_dn;
// blocks [128,256): tkv = encb@[k_dn|v_dn]. (Body identical to k_lora.)
__global__ __launch_bounds__(256) void k_lora2(
    const unsigned short* __restrict__ hsb, const unsigned short* __restrict__ encb,
    const float* __restrict__ q_dn, const float* __restrict__ k_dn,
    const float* __restrict__ v_dn,
    float* __restrict__ tq, float* __restrict__ tkv) {
  __shared__ unsigned short DNT[16][1032];
  const int tid = threadIdx.x;
  const bool isQ = blockIdx.x < 128;
  const int rbase = (isQ ? (int)blockIdx.x : (int)blockIdx.x - 128) * 64;
  const unsigned short* X = isQ ? hsb : encb;
  const float* dn0 = isQ ? q_dn : k_dn;
  const float* dn1 = isQ ? nullptr : v_dn;
  float* tout = isQ ? tq : tkv;
  const int tstr = isQ ? 4 : 8;

  for (int i = tid; i < 16 * 1032; i += 256) DNT[i / 1032][i % 1032] = 0;
  __syncthreads();
  for (int i = tid; i < 4096; i += 256) {
    const int k = i >> 2, c = i & 3;
    DNT[c][k] = f2bf(dn0[i]);
  }
  if (dn1 != nullptr) {
    for (int i = tid; i < 4096; i += 256) {
      const int k = i >> 2, c = i & 3;
      DNT[4 + c][k] = f2bf(dn1[i]);
    }
  }
  __syncthreads();
  const int l = tid & 63, w = tid >> 6;
  const int lr = l & 15, lk = l >> 4;
  const unsigned short* Xr = X + (size_t)(rbase + w * 16 + lr) * 1024 + lk * 8;
  const f32x4 zero = {0.f, 0.f, 0.f, 0.f};
  f32x4 acc0 = zero, acc1 = zero;
#pragma unroll 4
  for (int k0 = 0; k0 < 1024; k0 += 64) {
    bf16x8 a0 = *(const bf16x8*)(Xr + k0);
    bf16x8 b0 = *(const bf16x8*)&DNT[lr][k0 + lk * 8];
    bf16x8 a1 = *(const bf16x8*)(Xr + k0 + 32);
    bf16x8 b1 = *(const bf16x8*)&DNT[lr][k0 + 32 + lk * 8];
    acc0 = __builtin_amdgcn_mfma_f32_16x16x32_bf16(a0, b0, acc0, 0, 0, 0);
    acc1 = __builtin_amdgcn_mfma_f32_16x16x32_bf16(a1, b1, acc1, 0, 0, 0);
  }
  if (lr < tstr) {
#pragma unroll
    for (int r = 0; r < 4; ++r) {
      const int grow = rbase + w * 16 + lk * 4 + r;
      tout[(size_t)grow * tstr + lr] = acc0[r] + acc1[r];
    }
  }
}

// Kernel 1c: single-input LoRA-down (t_o after attention)
__global__ __launch_bounds__(256) void k_lora(
    const unsigned short* __restrict__ X,
    const float* __restrict__ dn0,
    float* __restrict__ tout, int tstr) {
  __shared__ unsigned short DNT[16][1032];
  const int tid = threadIdx.x;
  const int rbase = (int)blockIdx.x * 64;
  for (int i = tid; i < 16 * 1032; i += 256) DNT[i / 1032][i % 1032] = 0;
  __syncthreads();
  for (int i = tid; i < 4096; i += 256) {
    const int k = i >> 2, c = i & 3;
    DNT[c][k] = f2bf(dn0[i]);
  }
  __syncthreads();
  const int l = tid & 63, w = tid >> 6;
  const int lr = l & 15, lk = l >> 4;
  const unsigned short* Xr = X + (size_t)(rbase + w * 16 + lr) * 1024 + lk * 8;
  const f32x4 zero = {0.f, 0.f, 0.f, 0.f};
  f32x4 acc0 = zero, acc1 = zero;
#pragma unroll 4
  for (int k0 = 0; k0 < 1024; k0 += 64) {
    bf16x8 a0 = *(const bf16x8*)(Xr + k0);
    bf16x8 b0 = *(const bf16x8*)&DNT[lr][k0 + lk * 8];
    bf16x8 a1 = *(const bf16x8*)(Xr + k0 + 32);
    bf16x8 b1 = *(const bf16x8*)&DNT[lr][k0 + 32 + lk * 8];
    acc0 = __builtin_amdgcn_mfma_f32_16x16x32_bf16(a0, b0, acc0, 0, 0, 0);
    acc1 = __builtin_amdgcn_mfma_f32_16x16x32_bf16(a1, b1, acc1, 0, 0, 0);
  }
  if (lr < tstr) {
#pragma unroll
    for (int r = 0; r < 4; ++r) {
      const int grow = rbase + w * 16 + lk * 4 + r;
      tout[(size_t)grow * tstr + lr] = acc0[r] + acc1[r];
    }
  }
}

// ---------------------------------------------------------------------------
// Big-tile GEMM core: BM=256, BN=128, BK=64, 8 waves (512 thr), 144KB LDS
// TRIPLE-buffer, counted vmcnt 3-deep pipeline, T2 XOR swizzle.

#define GSTAGE(dbuf, kt) do {                                                 \
    _Pragma("unroll")                                                         \
    for (int j = 0; j < 4; ++j) {                                             \
      const int s = (j * 8 + w) * 64 + l;                                     \
      const int row = s >> 3, u = s & 7;                                      \
      gload16(Ap + (size_t)row * 1024 + (kt) * 64 + ((u ^ (row & 7)) * 8),    \
              &lA[dbuf][(j * 8 + w) * 512]);                                  \
    }                                                                         \
    _Pragma("unroll")                                                         \
    for (int j = 0; j < 2; ++j) {                                             \
      const int s = (j * 8 + w) * 64 + l;                                     \
      const int row = s >> 3, u = s & 7;                                      \
      gload16(Bp + (size_t)row * 1024 + (kt) * 64 + ((u ^ (row & 7)) * 8),    \
              &lB[dbuf][(j * 8 + w) * 512]);                                  \
    } } while (0)

#define BIG_GEMM_LOOP(TRANS)                                                  \
  GSTAGE(0, 0);                                                               \
  GSTAGE(1, 1);                                                               \
  GSTAGE(2, 2);                                                               \
  _Pragma("unroll")                                                           \
  for (int kt = 0; kt < 16; ++kt) {                                           \
    const int cur = kt % 3;                                                   \
    if (kt <= 13) { WT12; } else if (kt == 14) { WT6; } else { WT0; }         \
    __builtin_amdgcn_s_barrier();                                             \
    asm volatile("" ::: "memory");                                            \
    _Pragma("unroll")                                                         \
    for (int kk = 0; kk < 2; ++kk) {                                          \
      bf16x8 af[8], bfr[2];                                                   \
      _Pragma("unroll")                                                       \
      for (int m = 0; m < 8; ++m) {                                           \
        const int ar = wr + m * 16 + lr;                                      \
        af[m] = *(const bf16x8*)&lA[cur][ar * 64 +                            \
                 (((kk * 4 + lk) ^ (ar & 7)) * 8)];                           \
      }                                                                       \
      _Pragma("unroll")                                                       \
      for (int n = 0; n < 2; ++n) {                                           \
        const int br = wc + n * 16 + lr;                                      \
        bfr[n] = *(const bf16x8*)&lB[cur][br * 64 +                           \
                 (((kk * 4 + lk) ^ (br & 7)) * 8)];                           \
      }                                                                       \
      __builtin_amdgcn_s_setprio(1);                                          \
      _Pragma("unroll")                                                       \
      for (int m = 0; m < 8; ++m)                                             \
        _Pragma("unroll")                                                     \
        for (int n = 0; n < 2; ++n)                                           \
          acc[m][n] = (TRANS)                                                 \
            ? __builtin_amdgcn_mfma_f32_16x16x32_bf16(bfr[n], af[m],          \
                                                      acc[m][n], 0, 0, 0)     \
            : __builtin_amdgcn_mfma_f32_16x16x32_bf16(af[m], bfr[n],          \
                                                      acc[m][n], 0, 0, 0);    \
      __builtin_amdgcn_s_setprio(0);                                          \
    }                                                                         \
    asm volatile("s_waitcnt lgkmcnt(0)" ::: "memory");                        \
    __builtin_amdgcn_s_barrier();                                             \
    asm volatile("" ::: "memory");                                            \
    if (kt < 13) GSTAGE(cur, kt + 3);                                         \
  }

// Kernel 2: QKV projection. blocks [0,256): Q; [256,768): K|V.
__global__ __launch_bounds__(512, 2) void k_gemm_qkv(
    const unsigned short* __restrict__ hsb, const unsigned short* __restrict__ encb,
    const unsigned short* __restrict__ Wqt, const unsigned short* __restrict__ Wkvt,
    const float* __restrict__ tq, const float* __restrict__ tkv,
    const float* __restrict__ q_up, const float* __restrict__ k_up,
    const float* __restrict__ v_up,
    unsigned short* __restrict__ Qhp, unsigned short* __restrict__ Khp,
    unsigned short* __restrict__ Vhp) {
  __shared__ unsigned short lA[3][256 * 64];
  __shared__ unsigned short lB[3][128 * 64];
  const int tid = threadIdx.x;
  const int l = tid & 63, w = tid >> 6;
  const int bid = blockIdx.x;

  const unsigned short *A, *Bt;
  const float *tmat, *up;
  unsigned short* dst;
  int m0, nB0, nOut0, tstr;
  if (bid < 256) {
    const int rid = (bid & 7) * 32 + (bid >> 3);
    m0 = (rid >> 3) * 256; nB0 = (rid & 7) * 128;
    A = hsb; Bt = Wqt; tmat = tq; tstr = 4; up = q_up; dst = Qhp; nOut0 = nB0;
  } else {
    const int b2 = bid - 256;
    const int rid = (b2 & 7) * 64 + (b2 >> 3);
    m0 = (rid >> 4) * 256; nB0 = (rid & 15) * 128;
    A = encb; Bt = Wkvt; tstr = 8;
    if (nB0 < 1024) { tmat = tkv;     up = k_up; dst = Khp; nOut0 = nB0; }
    else            { tmat = tkv + 4; up = v_up; dst = Vhp; nOut0 = nB0 - 1024; }
  }
  const int wr = (w >> 2) * 128, wc = (w & 3) * 32;
  const int lr = l & 15, lk = l >> 4;
  const unsigned short* Ap = A  + (size_t)m0  * 1024;
  const unsigned short* Bp = Bt + (size_t)nB0 * 1024;

  f32x4 acc[8][2];
  const f32x4 zero = {0.f, 0.f, 0.f, 0.f};
#pragma unroll
  for (int m = 0; m < 8; ++m)
#pragma unroll
    for (int n = 0; n < 2; ++n) acc[m][n] = zero;

  BIG_GEMM_LOOP(1)

  // ---- epilogue: LoRA add + repack via LDS for coalesced stores -----------
  unsigned short* rep = &lA[0][0];
#pragma unroll
  for (int n = 0; n < 2; ++n) {
    const int cb = wc + n * 16 + lk * 4;
    const float4 u0v = *reinterpret_cast<const float4*>(&up[nOut0 + cb]);
    const float4 u1v = *reinterpret_cast<const float4*>(&up[1024 + nOut0 + cb]);
    const float4 u2v = *reinterpret_cast<const float4*>(&up[2048 + nOut0 + cb]);
    const float4 u3v = *reinterpret_cast<const float4*>(&up[3072 + nOut0 + cb]);
    const int u16 = cb >> 3;
    const int bo8 = (lk & 1) * 8;
#pragma unroll
    for (int m = 0; m < 8; ++m) {
      const int row = wr + m * 16 + lr;
      const int grow = m0 + row;
      const float4 tt = *reinterpret_cast<const float4*>(tmat + (size_t)grow * tstr);
      const float v0 = acc[m][n][0] + tt.x * u0v.x + tt.y * u1v.x + tt.z * u2v.x + tt.w * u3v.x;
      const float v1 = acc[m][n][1] + tt.x * u0v.y + tt.y * u1v.y + tt.z * u2v.y + tt.w * u3v.y;
      const float v2 = acc[m][n][2] + tt.x * u0v.z + tt.y * u1v.z + tt.z * u2v.z + tt.w * u3v.z;
      const float v3 = acc[m][n][3] + tt.x * u0v.w + tt.y * u1v.w + tt.z * u2v.w + tt.w * u3v.w;
      uint2 pk; pk.x = cvtpk(v0, v1); pk.y = cvtpk(v2, v3);
      *(uint2*)((char*)rep + row * 256 + ((u16 ^ (row & 7)) << 4) + bo8) = pk;
    }
  }
  __syncthreads();
  const int sub = l & 7;
#pragma unroll
  for (int it = 0; it < 8; ++it) {
    const int g = w * 64 + it * 8 + (l >> 3);
    const int head = g >> 8, row = g & 255;
    const int ju = ((head * 8 + sub) ^ (row & 7)) << 4;
    uint4 val = *(const uint4*)((const char*)rep + row * 256 + ju);
    const int grow = m0 + row;
    const int b = grow >> 11, s = grow & 2047;
    const int hg = (nOut0 >> 6) + head;
    *(uint4*)&dst[(((size_t)(b * kH + hg)) * 2048 + s) * 64 + sub * 8] = val;
  }
}

// Kernel 3: final GEMM  out = Ob @ Wot^T + bias + t_o @ o_up  (f32 output)
__global__ __launch_bounds__(512, 2) void k_gemm_out(
    const unsigned short* __restrict__ A, const unsigned short* __restrict__ Bt,
    const float* __restrict__ tmat, const float* __restrict__ up,
    const float* __restrict__ bias, float* __restrict__ outp) {
  __shared__ unsigned short lA[3][256 * 64];
  __shared__ unsigned short lB[3][128 * 64];
  const int tid = threadIdx.x;
  const int l = tid & 63, w = tid >> 6;
  const int bid = blockIdx.x;
  const int rid = (bid & 7) * 32 + (bid >> 3);
  const int m0 = (rid >> 3) * 256, nB0 = (rid & 7) * 128;
  const int wr = (w >> 2) * 128, wc = (w & 3) * 32;
  const int lr = l & 15, lk = l >> 4;
  const unsigned short* Ap = A  + (size_t)m0  * 1024;
  const unsigned short* Bp = Bt + (size_t)nB0 * 1024;

  f32x4 acc[8][2];
  const f32x4 zero = {0.f, 0.f, 0.f, 0.f};
#pragma unroll
  for (int m = 0; m < 8; ++m)
#pragma unroll
    for (int n = 0; n < 2; ++n) acc[m][n] = zero;

  BIG_GEMM_LOOP(0)

#pragma unroll
  for (int n = 0; n < 2; ++n) {
    const int gcol = nB0 + wc + n * 16 + lr;
    const float u0 = up[gcol], u1 = up[1024 + gcol];
    const float u2 = up[2048 + gcol], u3 = up[3072 + gcol];
    const float bz = bias[gcol];
#pragma unroll
    for (int m = 0; m < 8; ++m) {
#pragma unroll
      for (int r = 0; r < 4; ++r) {
        const int grow = m0 + wr + m * 16 + lk * 4 + r;
        const float4 tt = *reinterpret_cast<const float4*>(tmat + (size_t)grow * 4);
        outp[(size_t)grow * 1024 + gcol] =
            acc[m][n][r] + tt.x * u0 + tt.y * u1 + tt.z * u2 + tt.w * u3 + bz;
      }
    }
  }
}

// ---------------------------------------------------------------------------
// Kernel 4: V head-layout transpose: (bh, s, d) -> (bh, d, s)
__global__ __launch_bounds__(256) void k_vt(const unsigned short* __restrict__ Vh,
                                            unsigned short* __restrict__ Vt) {
  __shared__ unsigned short tile[64][65];
  const int bh = blockIdx.y;
  const int s0 = blockIdx.x * 64;
  const unsigned short* src = Vh + ((size_t)bh * kSKV + s0) * 64;
  for (int i = threadIdx.x; i < 4096; i += 256) {
    int r = i >> 6, c = i & 63;
    tile[r][c] = src[(size_t)r * 64 + c];
  }
  __syncthreads();
  unsigned short* dst = Vt + (size_t)bh * 64 * kSKV + s0;
  for (int i = threadIdx.x; i < 4096; i += 256) {
    int r = i >> 6, c = i & 63;
    dst[(size_t)r * kSKV + c] = tile[c][r];
  }
}

// ---------------------------------------------------------------------------
// Kernel 5: flash attention, QBLK=256 (4 waves x 64 q-rows each), KV tiles
// of 64. K/V fragments loaded once per kt serve 64 q-rows. Fixed-max softmax
// via exp2; conflict-free 16B-unit XOR swizzle.
__global__ __launch_bounds__(256, 2) void k_attn(
    const unsigned short* __restrict__ Qh, const unsigned short* __restrict__ Kh,
    const unsigned short* __restrict__ Vt, unsigned short* __restrict__ Obf) {
  __shared__ unsigned short lK[2][4096];
  __shared__ unsigned short lV[2][4096];
  __shared__ __align__(16) unsigned short lP[4][1024];

  const int bid = blockIdx.x;                       // 512 blocks
  const int rid = (bid & 7) * 64 + (bid >> 3);      // bijective, 512%8==0
  const int q0 = (rid & 7) * 256;
  const int bh = rid >> 3;

  const int tid = threadIdx.x;
  const int l = tid & 63, w = tid >> 6;
  const int lr = l & 15, lk = l >> 4;
  const int m7 = lr & 7;
  const int lkh = lk >> 1, lkb = lk & 1;

  const unsigned short* Qb = Qh + (size_t)bh * kSQ * 64;
  const unsigned short* Kb = Kh + (size_t)bh * kSKV * 64;
  const unsigned short* Vb = Vt + (size_t)bh * 64 * kSKV;

  const float QS = 0.125f * 1.4426950408889634f;
  bf16x8 qf[4][2];
#pragma unroll
  for (int m = 0; m < 4; ++m)
#pragma unroll
    for (int kk = 0; kk < 2; ++kk) {
      bf16x8 v = *(const bf16x8*)
          &Qb[(size_t)(q0 + w * 64 + m * 16 + lr) * 64 + kk * 32 + lk * 8];
#pragma unroll
      for (int j = 0; j < 8; ++j) {
        unsigned short u = (unsigned short)v[j];
        v[j] = (short)f2bf(bf2f(u) * QS);
      }
      qf[m][kk] = v;
    }

  f32x4 oacc[4][4];
  const f32x4 zero = {0.f, 0.f, 0.f, 0.f};
#pragma unroll
  for (int m = 0; m < 4; ++m)
#pragma unroll
    for (int n = 0; n < 4; ++n) oacc[m][n] = zero;
  float lrow[4] = {0.f, 0.f, 0.f, 0.f};

  const int sr8 = l >> 3;
  const int su = (l & 7) ^ sr8;
  unsigned short* lPw = lP[w];

#define ASTAGE(dbuf, tile) do { \
    _Pragma("unroll") for (int cc = 0; cc < 2; ++cc) { \
      const int c = 2 * w + cc; const int row = c * 8 + sr8; \
      gload16(Kb + (size_t)((tile) * 64 + row) * 64 + su * 8, &lK[dbuf][c * 512]); \
      gload16(Vb + (size_t)row * kSKV + (tile) * 64 + su * 8, &lV[dbuf][c * 512]); \
    } } while (0)

  ASTAGE(0, 0);
  __syncthreads();

  for (int kt = 0; kt < 32; ++kt) {
    const int cur = kt & 1;
    if (kt < 31) ASTAGE(cur ^ 1, kt + 1);
    const unsigned short* bufK = lK[cur];
    const unsigned short* bufV = lV[cur];

    // K fragments: loaded once, serve all 4 q-sub-blocks (64 rows)
    bf16x8 kf[4][2];
#pragma unroll
    for (int n = 0; n < 4; ++n)
#pragma unroll
      for (int kk = 0; kk < 2; ++kk) {
        const int ub = (kk * 4 + lk) ^ m7;
        kf[n][kk] = *(const bf16x8*)&bufK[(n * 16 + lr) * 64 + ub * 8];
      }

    bf16x8 pf[4][2];
#pragma unroll
    for (int mp = 0; mp < 2; ++mp) {
      const int ma = mp * 2, mb = mp * 2 + 1;
      // ---- q-sub-block ma ------------------------------------------------
      f32x4 s0[4];
#pragma unroll
      for (int n = 0; n < 4; ++n) s0[n] = zero;
      __builtin_amdgcn_s_setprio(1);
#pragma unroll
      for (int kk = 0; kk < 2; ++kk)
#pragma unroll
        for (int n = 0; n < 4; ++n)
          s0[n] = __builtin_amdgcn_mfma_f32_16x16x32_bf16(kf[n][kk], qf[ma][kk],
                                                          s0[n], 0, 0, 0);
      __builtin_amdgcn_s_setprio(0);
      float ls0 = 0.f;
#pragma unroll
      for (int n = 0; n < 4; ++n) {
        const float p0 = vexp2(s0[n][0]);
        const float p1 = vexp2(s0[n][1]);
        const float p2 = vexp2(s0[n][2]);
        const float p3 = vexp2(s0[n][3]);
        ls0 += (p0 + p1) + (p2 + p3);
        uint2 pv; pv.x = cvtpk(p0, p1); pv.y = cvtpk(p2, p3);
        *(uint2*)&lPw[lr * 64 + (((2 * n + lkh) ^ m7) << 3) + lkb * 4] = pv;
      }
      lrow[ma] += ls0;

      // ---- q-sub-block mb ------------------------------------------------
      f32x4 s1[4];
#pragma unroll
      for (int n = 0; n < 4; ++n) s1[n] = zero;
      __builtin_amdgcn_s_setprio(1);
#pragma unroll
      for (int kk = 0; kk < 2; ++kk)
#pragma unroll
        for (int n = 0; n < 4; ++n)
          s1[n] = __builtin_amdgcn_mfma_f32_16x16x32_bf16(kf[n][kk], qf[mb][kk],
                                                          s1[n], 0, 0, 0);
      __builtin_amdgcn_s_setprio(0);
      float ls1 = 0.f;
      uint2 pw1[4];
#pragma unroll
      for (int n = 0; n < 4; ++n) {
        const float p0 = vexp2(s1[n][0]);
        const float p1 = vexp2(s1[n][1]);
        const float p2 = vexp2(s1[n][2]);
        const float p3 = vexp2(s1[n][3]);
        ls1 += (p0 + p1) + (p2 + p3);
        pw1[n].x = cvtpk(p0, p1); pw1[n].y = cvtpk(p2, p3);
      }
      lrow[mb] += ls1;

      // read P(ma) (write latency covered by QK-mb), write P(mb), read P(mb)
#pragma unroll
      for (int kk = 0; kk < 2; ++kk)
        pf[ma][kk] = *(const bf16x8*)&lPw[lr * 64 + (((kk * 4 + lk) ^ m7) << 3)];
#pragma unroll
      for (int n = 0; n < 4; ++n)
        *(uint2*)&lPw[lr * 64 + (((2 * n + lkh) ^ m7) << 3) + lkb * 4] = pw1[n];
#pragma unroll
      for (int kk = 0; kk < 2; ++kk)
        pf[mb][kk] = *(const bf16x8*)&lPw[lr * 64 + (((kk * 4 + lk) ^ m7) << 3)];
    }

    // ---- O += P @ V : each vf load feeds 4 MFMAs (one per sub-block) -----
    __builtin_amdgcn_s_setprio(1);
#pragma unroll
    for (int n = 0; n < 4; ++n)
#pragma unroll
      for (int kk = 0; kk < 2; ++kk) {
        const int ub = (kk * 4 + lk) ^ m7;
        bf16x8 vf = *(const bf16x8*)&bufV[(n * 16 + lr) * 64 + ub * 8];
#pragma unroll
        for (int m = 0; m < 4; ++m)
          oacc[m][n] = __builtin_amdgcn_mfma_f32_16x16x32_bf16(pf[m][kk], vf,
                                                               oacc[m][n], 0, 0, 0);
      }
    __builtin_amdgcn_s_setprio(0);

    __syncthreads();
  }
#undef ASTAGE

  float rinv[4][4];
#pragma unroll
  for (int m = 0; m < 4; ++m) {
    float s = lrow[m];
    s += __shfl_xor(s, 16);
    s += __shfl_xor(s, 32);
#pragma unroll
    for (int r = 0; r < 4; ++r) rinv[m][r] = 1.0f / __shfl(s, lk * 4 + r);
  }

  const int b = bh >> 4, h = bh & 15;
#pragma unroll
  for (int m = 0; m < 4; ++m)
#pragma unroll
    for (int n = 0; n < 4; ++n)
#pragma unroll
      for (int r = 0; r < 4; ++r) {
        const int qrow = q0 + w * 64 + m * 16 + lk * 4 + r;
        const int d = n * 16 + lr;
        Obf[((size_t)b * kSQ + qrow) * kD + h * 64 + d] =
            f2bf(oacc[m][n][r] * rinv[m][r]);
      }
}

// ---------------------------------------------------------------------------
extern "C" void kernel_launch(void* const* d_in, const int* in_sizes, int n_in,
                              void* d_out, int out_size, void* d_ws, size_t ws_size,
                              hipStream_t stream) {
  (void)in_sizes; (void)n_in; (void)out_size; (void)ws_size;
  const float* hs   = (const float*)d_in[0];
  const float* enc  = (const float*)d_in[1];
  const float* Wq   = (const float*)d_in[2];
  const float* Wk   = (const float*)d_in[3];
  const float* Wv   = (const float*)d_in[4];
  const float* Wo   = (const float*)d_in[5];
  const float* bo   = (const float*)d_in[6];
  const float* q_dn = (const float*)d_in[7];
  const float* q_up = (const float*)d_in[8];
  const float* k_dn = (const float*)d_in[9];
  const float* k_up = (const float*)d_in[10];
  const float* v_dn = (const float*)d_in[11];
  const float* v_up = (const float*)d_in[12];
  const float* o_dn = (const float*)d_in[13];
  const float* o_up = (const float*)d_in[14];

  char* ws = (char*)d_ws;
  size_t off = 0;
  auto alloc = [&](size_t bytes) -> void* {
    void* p = ws + off;
    off += (bytes + 255) & ~(size_t)255;
    return p;
  };
  const size_t ACT = (size_t)kM * kD * 2;
  unsigned short* hsb  = (unsigned short*)alloc(ACT);
  unsigned short* encb = (unsigned short*)alloc(ACT);
  unsigned short* Wqt  = (unsigned short*)alloc((size_t)1024 * 1024 * 2);
  unsigned short* Wkvt = (unsigned short*)alloc((size_t)2048 * 1024 * 2);
  unsigned short* Wot  = (unsigned short*)alloc((size_t)1024 * 1024 * 2);
  unsigned short* Qhp  = (unsigned short*)alloc(ACT);
  unsigned short* Khp  = (unsigned short*)alloc(ACT);
  unsigned short* Vhp  = (unsigned short*)alloc(ACT);
  float* tq  = (float*)alloc((size_t)kM * 4 * 4);
  float* tkv = (float*)alloc((size_t)kM * 8 * 4);
  float* to  = (float*)alloc((size_t)kM * 4 * 4);
  unsigned short* Vtt = hsb;   // alias: V^T reuses hidden bf16 buffer
  unsigned short* Ob  = encb;  // alias: attention O reuses encoder bf16 buffer

  k_prep_wt<<<dim3(2 * kM + 1024), dim3(256), 0, stream>>>(
      hs, enc, Wq, Wk, Wv, Wo, hsb, encb, Wqt, Wkvt, Wot);

  k_lora2<<<dim3(256), dim3(256), 0, stream>>>(hsb, encb, q_dn, k_dn, v_dn,
                                               tq, tkv);

  k_gemm_qkv<<<dim3(768), dim3(512), 0, stream>>>(
      hsb, encb, Wqt, Wkvt, tq, tkv, q_up, k_up, v_up, Qhp, Khp, Vhp);

  k_vt<<<dim3(32, 64), dim3(256), 0, stream>>>(Vhp, Vtt);
  k_attn<<<dim3(512), dim3(256), 0, stream>>>(Qhp, Khp, Vtt, Ob);

  k_lora<<<dim3(128), dim3(256), 0, stream>>>(Ob, o_dn, to, 4);

  k_gemm_out<<<dim3(256), dim3(512), 0, stream>>>(Ob, Wot, to, o_up, bo,
                                                  (float*)d_out);
}

// Round 18
// 226.484 us; speedup vs baseline: 1.8670x; 1.0003x over previous
//
#include <hip/hip_runtime.h>
#include <hip/hip_bf16.h>

typedef __attribute__((ext_vector_type(8))) short bf16x8;
typedef __attribute__((ext_vector_type(4))) float f32x4;

#define DEVFN static __device__ __forceinline__

constexpr int kSQ = 2048, kSKV = 2048, kD = 1024, kH = 16;
constexpr int kM = 4 * kSQ;   // 8192 query rows (B*SQ)

DEVFN unsigned short f2bf(float f) {
  union { float f; unsigned u; } v; v.f = f;
  unsigned r = v.u + 0x7FFFu + ((v.u >> 16) & 1u);
  return (unsigned short)(r >> 16);
}
DEVFN float bf2f(unsigned short h) {
  union { unsigned u; float f; } v; v.u = ((unsigned)h) << 16; return v.f;
}
DEVFN unsigned cvtpk(float lo, float hi) {
  unsigned r;
  asm("v_cvt_pk_bf16_f32 %0, %1, %2" : "=v"(r) : "v"(lo), "v"(hi));
  return r;
}
DEVFN float vexp2(float x) {
  float r;
  asm("v_exp_f32 %0, %1" : "=v"(r) : "v"(x));
  return r;
}

DEVFN void gload16(const void* g, void* l) {
  __builtin_amdgcn_global_load_lds(
      (const __attribute__((address_space(1))) unsigned int*)g,
      (__attribute__((address_space(3))) unsigned int*)l, 16, 0, 0);
}

#define WT12 asm volatile("s_waitcnt vmcnt(12)" ::: "memory")
#define WT6  asm volatile("s_waitcnt vmcnt(6)" ::: "memory")
#define WT0  asm volatile("s_waitcnt vmcnt(0)" ::: "memory")

// ---------------------------------------------------------------------------
// Kernel 1: blocks [0, 2*kM): activation fp32->bf16 streaming convert.
// blocks [2*kM, 2*kM+1024): weight convert+transpose (4 weights x 256 tiles).
__global__ __launch_bounds__(256) void k_prep_wt(
    const float* __restrict__ hs, const float* __restrict__ enc,
    const float* __restrict__ Wq, const float* __restrict__ Wk,
    const float* __restrict__ Wv, const float* __restrict__ Wo,
    unsigned short* __restrict__ hsb, unsigned short* __restrict__ encb,
    unsigned short* __restrict__ Wqt, unsigned short* __restrict__ Wkvt,
    unsigned short* __restrict__ Wot) {
  __shared__ unsigned short tile[64][65];
  const int bid = blockIdx.x;
  const int tid = threadIdx.x;

  if (bid < 2 * kM) {
    const bool isH = bid < kM;
    const int rr = isH ? bid : bid - kM;
    const float* srcRow = (isH ? hs : enc) + (size_t)rr * kD;
    unsigned short* dstRow = (isH ? hsb : encb) + (size_t)rr * kD;
    float4 x = reinterpret_cast<const float4*>(srcRow)[tid];
    short4 o;
    o.x = (short)f2bf(x.x); o.y = (short)f2bf(x.y);
    o.z = (short)f2bf(x.z); o.w = (short)f2bf(x.w);
    *reinterpret_cast<short4*>(dstRow + tid * 4) = o;
  } else {
    const int t = bid - 2 * kM;
    const int wid = t >> 8, tt = t & 255;
    const float* W = (wid == 0) ? Wq : (wid == 1) ? Wk : (wid == 2) ? Wv : Wo;
    unsigned short* Wt = (wid == 0) ? Wqt : (wid == 1) ? Wkvt
                        : (wid == 2) ? (Wkvt + (size_t)1024 * 1024) : Wot;
    const int tk0 = (tt & 15) * 64;
    const int tn0 = (tt >> 4) * 64;
    for (int i = tid; i < 4096; i += 256) {
      int r = i >> 6, c = i & 63;
      tile[r][c] = f2bf(W[(size_t)(tk0 + r) * 1024 + tn0 + c]);
    }
    __syncthreads();
    for (int i = tid; i < 4096; i += 256) {
      int r = i >> 6, c = i & 63;
      Wt[(size_t)(tn0 + r) * 1024 + tk0 + c] = tile[c][r];
    }
  }
}

// ---------------------------------------------------------------------------
// Kernel 1b: LoRA-down via MFMA, merged launch. blocks [0,128): tq = hsb@q_dn;
// blocks [128,256): tkv = encb@[k_dn|v_dn].
__global__ __launch_bounds__(256) void k_lora2(
    const unsigned short* __restrict__ hsb, const unsigned short* __restrict__ encb,
    const float* __restrict__ q_dn, const float* __restrict__ k_dn,
    const float* __restrict__ v_dn,
    float* __restrict__ tq, float* __restrict__ tkv) {
  __shared__ unsigned short DNT[16][1032];
  const int tid = threadIdx.x;
  const bool isQ = blockIdx.x < 128;
  const int rbase = (isQ ? (int)blockIdx.x : (int)blockIdx.x - 128) * 64;
  const unsigned short* X = isQ ? hsb : encb;
  const float* dn0 = isQ ? q_dn : k_dn;
  const float* dn1 = isQ ? nullptr : v_dn;
  float* tout = isQ ? tq : tkv;
  const int tstr = isQ ? 4 : 8;

  for (int i = tid; i < 16 * 1032; i += 256) DNT[i / 1032][i % 1032] = 0;
  __syncthreads();
  for (int i = tid; i < 4096; i += 256) {
    const int k = i >> 2, c = i & 3;
    DNT[c][k] = f2bf(dn0[i]);
  }
  if (dn1 != nullptr) {
    for (int i = tid; i < 4096; i += 256) {
      const int k = i >> 2, c = i & 3;
      DNT[4 + c][k] = f2bf(dn1[i]);
    }
  }
  __syncthreads();
  const int l = tid & 63, w = tid >> 6;
  const int lr = l & 15, lk = l >> 4;
  const unsigned short* Xr = X + (size_t)(rbase + w * 16 + lr) * 1024 + lk * 8;
  const f32x4 zero = {0.f, 0.f, 0.f, 0.f};
  f32x4 acc0 = zero, acc1 = zero;
#pragma unroll 4
  for (int k0 = 0; k0 < 1024; k0 += 64) {
    bf16x8 a0 = *(const bf16x8*)(Xr + k0);
    bf16x8 b0 = *(const bf16x8*)&DNT[lr][k0 + lk * 8];
    bf16x8 a1 = *(const bf16x8*)(Xr + k0 + 32);
    bf16x8 b1 = *(const bf16x8*)&DNT[lr][k0 + 32 + lk * 8];
    acc0 = __builtin_amdgcn_mfma_f32_16x16x32_bf16(a0, b0, acc0, 0, 0, 0);
    acc1 = __builtin_amdgcn_mfma_f32_16x16x32_bf16(a1, b1, acc1, 0, 0, 0);
  }
  if (lr < tstr) {
#pragma unroll
    for (int r = 0; r < 4; ++r) {
      const int grow = rbase + w * 16 + lk * 4 + r;
      tout[(size_t)grow * tstr + lr] = acc0[r] + acc1[r];
    }
  }
}

// Kernel 1c: single-input LoRA-down (t_o after attention)
__global__ __launch_bounds__(256) void k_lora(
    const unsigned short* __restrict__ X,
    const float* __restrict__ dn0,
    float* __restrict__ tout, int tstr) {
  __shared__ unsigned short DNT[16][1032];
  const int tid = threadIdx.x;
  const int rbase = (int)blockIdx.x * 64;
  for (int i = tid; i < 16 * 1032; i += 256) DNT[i / 1032][i % 1032] = 0;
  __syncthreads();
  for (int i = tid; i < 4096; i += 256) {
    const int k = i >> 2, c = i & 3;
    DNT[c][k] = f2bf(dn0[i]);
  }
  __syncthreads();
  const int l = tid & 63, w = tid >> 6;
  const int lr = l & 15, lk = l >> 4;
  const unsigned short* Xr = X + (size_t)(rbase + w * 16 + lr) * 1024 + lk * 8;
  const f32x4 zero = {0.f, 0.f, 0.f, 0.f};
  f32x4 acc0 = zero, acc1 = zero;
#pragma unroll 4
  for (int k0 = 0; k0 < 1024; k0 += 64) {
    bf16x8 a0 = *(const bf16x8*)(Xr + k0);
    bf16x8 b0 = *(const bf16x8*)&DNT[lr][k0 + lk * 8];
    bf16x8 a1 = *(const bf16x8*)(Xr + k0 + 32);
    bf16x8 b1 = *(const bf16x8*)&DNT[lr][k0 + 32 + lk * 8];
    acc0 = __builtin_amdgcn_mfma_f32_16x16x32_bf16(a0, b0, acc0, 0, 0, 0);
    acc1 = __builtin_amdgcn_mfma_f32_16x16x32_bf16(a1, b1, acc1, 0, 0, 0);
  }
  if (lr < tstr) {
#pragma unroll
    for (int r = 0; r < 4; ++r) {
      const int grow = rbase + w * 16 + lk * 4 + r;
      tout[(size_t)grow * tstr + lr] = acc0[r] + acc1[r];
    }
  }
}

// ---------------------------------------------------------------------------
// Big-tile GEMM core: BM=256, BN=128, BK=64, 8 waves (512 thr), 144KB LDS
// TRIPLE-buffer, counted vmcnt 3-deep pipeline, T2 XOR swizzle.

#define GSTAGE(dbuf, kt) do {                                                 \
    _Pragma("unroll")                                                         \
    for (int j = 0; j < 4; ++j) {                                             \
      const int s = (j * 8 + w) * 64 + l;                                     \
      const int row = s >> 3, u = s & 7;                                      \
      gload16(Ap + (size_t)row * 1024 + (kt) * 64 + ((u ^ (row & 7)) * 8),    \
              &lA[dbuf][(j * 8 + w) * 512]);                                  \
    }                                                                         \
    _Pragma("unroll")                                                         \
    for (int j = 0; j < 2; ++j) {                                             \
      const int s = (j * 8 + w) * 64 + l;                                     \
      const int row = s >> 3, u = s & 7;                                      \
      gload16(Bp + (size_t)row * 1024 + (kt) * 64 + ((u ^ (row & 7)) * 8),    \
              &lB[dbuf][(j * 8 + w) * 512]);                                  \
    } } while (0)

#define BIG_GEMM_LOOP(TRANS)                                                  \
  GSTAGE(0, 0);                                                               \
  GSTAGE(1, 1);                                                               \
  GSTAGE(2, 2);                                                               \
  _Pragma("unroll")                                                           \
  for (int kt = 0; kt < 16; ++kt) {                                           \
    const int cur = kt % 3;                                                   \
    if (kt <= 13) { WT12; } else if (kt == 14) { WT6; } else { WT0; }         \
    __builtin_amdgcn_s_barrier();                                             \
    asm volatile("" ::: "memory");                                            \
    _Pragma("unroll")                                                         \
    for (int kk = 0; kk < 2; ++kk) {                                          \
      bf16x8 af[8], bfr[2];                                                   \
      _Pragma("unroll")                                                       \
      for (int m = 0; m < 8; ++m) {                                           \
        const int ar = wr + m * 16 + lr;                                      \
        af[m] = *(const bf16x8*)&lA[cur][ar * 64 +                            \
                 (((kk * 4 + lk) ^ (ar & 7)) * 8)];                           \
      }                                                                       \
      _Pragma("unroll")                                                       \
      for (int n = 0; n < 2; ++n) {                                           \
        const int br = wc + n * 16 + lr;                                      \
        bfr[n] = *(const bf16x8*)&lB[cur][br * 64 +                           \
                 (((kk * 4 + lk) ^ (br & 7)) * 8)];                           \
      }                                                                       \
      __builtin_amdgcn_s_setprio(1);                                          \
      _Pragma("unroll")                                                       \
      for (int m = 0; m < 8; ++m)                                             \
        _Pragma("unroll")                                                     \
        for (int n = 0; n < 2; ++n)                                           \
          acc[m][n] = (TRANS)                                                 \
            ? __builtin_amdgcn_mfma_f32_16x16x32_bf16(bfr[n], af[m],          \
                                                      acc[m][n], 0, 0, 0)     \
            : __builtin_amdgcn_mfma_f32_16x16x32_bf16(af[m], bfr[n],          \
                                                      acc[m][n], 0, 0, 0);    \
      __builtin_amdgcn_s_setprio(0);                                          \
    }                                                                         \
    asm volatile("s_waitcnt lgkmcnt(0)" ::: "memory");                        \
    __builtin_amdgcn_s_barrier();                                             \
    asm volatile("" ::: "memory");                                            \
    if (kt < 13) GSTAGE(cur, kt + 3);                                         \
  }

// Kernel 2: QKV projection. blocks [0,256): Q; [256,768): K|V.
__global__ __launch_bounds__(512, 2) void k_gemm_qkv(
    const unsigned short* __restrict__ hsb, const unsigned short* __restrict__ encb,
    const unsigned short* __restrict__ Wqt, const unsigned short* __restrict__ Wkvt,
    const float* __restrict__ tq, const float* __restrict__ tkv,
    const float* __restrict__ q_up, const float* __restrict__ k_up,
    const float* __restrict__ v_up,
    unsigned short* __restrict__ Qhp, unsigned short* __restrict__ Khp,
    unsigned short* __restrict__ Vhp) {
  __shared__ unsigned short lA[3][256 * 64];
  __shared__ unsigned short lB[3][128 * 64];
  const int tid = threadIdx.x;
  const int l = tid & 63, w = tid >> 6;
  const int bid = blockIdx.x;

  const unsigned short *A, *Bt;
  const float *tmat, *up;
  unsigned short* dst;
  int m0, nB0, nOut0, tstr;
  if (bid < 256) {
    const int rid = (bid & 7) * 32 + (bid >> 3);
    m0 = (rid >> 3) * 256; nB0 = (rid & 7) * 128;
    A = hsb; Bt = Wqt; tmat = tq; tstr = 4; up = q_up; dst = Qhp; nOut0 = nB0;
  } else {
    const int b2 = bid - 256;
    const int rid = (b2 & 7) * 64 + (b2 >> 3);
    m0 = (rid >> 4) * 256; nB0 = (rid & 15) * 128;
    A = encb; Bt = Wkvt; tstr = 8;
    if (nB0 < 1024) { tmat = tkv;     up = k_up; dst = Khp; nOut0 = nB0; }
    else            { tmat = tkv + 4; up = v_up; dst = Vhp; nOut0 = nB0 - 1024; }
  }
  const int wr = (w >> 2) * 128, wc = (w & 3) * 32;
  const int lr = l & 15, lk = l >> 4;
  const unsigned short* Ap = A  + (size_t)m0  * 1024;
  const unsigned short* Bp = Bt + (size_t)nB0 * 1024;

  f32x4 acc[8][2];
  const f32x4 zero = {0.f, 0.f, 0.f, 0.f};
#pragma unroll
  for (int m = 0; m < 8; ++m)
#pragma unroll
    for (int n = 0; n < 2; ++n) acc[m][n] = zero;

  BIG_GEMM_LOOP(1)

  // ---- epilogue: LoRA add + repack via LDS for coalesced stores -----------
  unsigned short* rep = &lA[0][0];
#pragma unroll
  for (int n = 0; n < 2; ++n) {
    const int cb = wc + n * 16 + lk * 4;
    const float4 u0v = *reinterpret_cast<const float4*>(&up[nOut0 + cb]);
    const float4 u1v = *reinterpret_cast<const float4*>(&up[1024 + nOut0 + cb]);
    const float4 u2v = *reinterpret_cast<const float4*>(&up[2048 + nOut0 + cb]);
    const float4 u3v = *reinterpret_cast<const float4*>(&up[3072 + nOut0 + cb]);
    const int u16 = cb >> 3;
    const int bo8 = (lk & 1) * 8;
#pragma unroll
    for (int m = 0; m < 8; ++m) {
      const int row = wr + m * 16 + lr;
      const int grow = m0 + row;
      const float4 tt = *reinterpret_cast<const float4*>(tmat + (size_t)grow * tstr);
      const float v0 = acc[m][n][0] + tt.x * u0v.x + tt.y * u1v.x + tt.z * u2v.x + tt.w * u3v.x;
      const float v1 = acc[m][n][1] + tt.x * u0v.y + tt.y * u1v.y + tt.z * u2v.y + tt.w * u3v.y;
      const float v2 = acc[m][n][2] + tt.x * u0v.z + tt.y * u1v.z + tt.z * u2v.z + tt.w * u3v.z;
      const float v3 = acc[m][n][3] + tt.x * u0v.w + tt.y * u1v.w + tt.z * u2v.w + tt.w * u3v.w;
      uint2 pk; pk.x = cvtpk(v0, v1); pk.y = cvtpk(v2, v3);
      *(uint2*)((char*)rep + row * 256 + ((u16 ^ (row & 7)) << 4) + bo8) = pk;
    }
  }
  __syncthreads();
  const int sub = l & 7;
#pragma unroll
  for (int it = 0; it < 8; ++it) {
    const int g = w * 64 + it * 8 + (l >> 3);
    const int head = g >> 8, row = g & 255;
    const int ju = ((head * 8 + sub) ^ (row & 7)) << 4;
    uint4 val = *(const uint4*)((const char*)rep + row * 256 + ju);
    const int grow = m0 + row;
    const int b = grow >> 11, s = grow & 2047;
    const int hg = (nOut0 >> 6) + head;
    *(uint4*)&dst[(((size_t)(b * kH + hg)) * 2048 + s) * 64 + sub * 8] = val;
  }
}

// Kernel 3: final GEMM  out = Ob @ Wot^T + bias + t_o @ o_up  (f32 output)
__global__ __launch_bounds__(512, 2) void k_gemm_out(
    const unsigned short* __restrict__ A, const unsigned short* __restrict__ Bt,
    const float* __restrict__ tmat, const float* __restrict__ up,
    const float* __restrict__ bias, float* __restrict__ outp) {
  __shared__ unsigned short lA[3][256 * 64];
  __shared__ unsigned short lB[3][128 * 64];
  const int tid = threadIdx.x;
  const int l = tid & 63, w = tid >> 6;
  const int bid = blockIdx.x;
  const int rid = (bid & 7) * 32 + (bid >> 3);
  const int m0 = (rid >> 3) * 256, nB0 = (rid & 7) * 128;
  const int wr = (w >> 2) * 128, wc = (w & 3) * 32;
  const int lr = l & 15, lk = l >> 4;
  const unsigned short* Ap = A  + (size_t)m0  * 1024;
  const unsigned short* Bp = Bt + (size_t)nB0 * 1024;

  f32x4 acc[8][2];
  const f32x4 zero = {0.f, 0.f, 0.f, 0.f};
#pragma unroll
  for (int m = 0; m < 8; ++m)
#pragma unroll
    for (int n = 0; n < 2; ++n) acc[m][n] = zero;

  BIG_GEMM_LOOP(0)

#pragma unroll
  for (int n = 0; n < 2; ++n) {
    const int gcol = nB0 + wc + n * 16 + lr;
    const float u0 = up[gcol], u1 = up[1024 + gcol];
    const float u2 = up[2048 + gcol], u3 = up[3072 + gcol];
    const float bz = bias[gcol];
#pragma unroll
    for (int m = 0; m < 8; ++m) {
#pragma unroll
      for (int r = 0; r < 4; ++r) {
        const int grow = m0 + wr + m * 16 + lk * 4 + r;
        const float4 tt = *reinterpret_cast<const float4*>(tmat + (size_t)grow * 4);
        outp[(size_t)grow * 1024 + gcol] =
            acc[m][n][r] + tt.x * u0 + tt.y * u1 + tt.z * u2 + tt.w * u3 + bz;
      }
    }
  }
}

// ---------------------------------------------------------------------------
// Kernel 4: V head-layout transpose (bh, s, d) -> (bh, d, s), VECTORIZED:
// 16B/lane global loads and stores; transpose via padded LDS tile (scalar
// LDS reads only, global sides fully coalesced).
__global__ __launch_bounds__(256) void k_vt(const unsigned short* __restrict__ Vh,
                                            unsigned short* __restrict__ Vt) {
  __shared__ unsigned short tile[64][72];   // +8 pad breaks column-bank stride
  const int bh = blockIdx.y;
  const int s0 = blockIdx.x * 64;
  const int tid = threadIdx.x;
  const unsigned short* src = Vh + ((size_t)bh * kSKV + s0) * 64;
#pragma unroll
  for (int it = 0; it < 2; ++it) {
    const int idx = it * 256 + tid;            // 0..511
    const int r = idx >> 3, c8 = (idx & 7) * 8;
    uint4 v = *(const uint4*)&src[(size_t)r * 64 + c8];
    *(uint4*)&tile[r][c8] = v;
  }
  __syncthreads();
  unsigned short* dst = Vt + (size_t)bh * 64 * kSKV + s0;
#pragma unroll
  for (int it = 0; it < 2; ++it) {
    const int idx = it * 256 + tid;            // 0..511
    const int d = idx >> 3, su = (idx & 7) * 8;
    unsigned short tmp[8];
#pragma unroll
    for (int j = 0; j < 8; ++j) tmp[j] = tile[su + j][d];
    *(uint4*)&dst[(size_t)d * kSKV + su] = *(const uint4*)tmp;
  }
}

// ---------------------------------------------------------------------------
// Kernel 5: flash attention, QBLK=256 (4 waves x 64 q-rows each), KV tiles
// of 64. K/V fragments loaded once per kt serve 64 q-rows. Fixed-max softmax
// via exp2; conflict-free 16B-unit XOR swizzle.
__global__ __launch_bounds__(256, 2) void k_attn(
    const unsigned short* __restrict__ Qh, const unsigned short* __restrict__ Kh,
    const unsigned short* __restrict__ Vt, unsigned short* __restrict__ Obf) {
  __shared__ unsigned short lK[2][4096];
  __shared__ unsigned short lV[2][4096];
  __shared__ __align__(16) unsigned short lP[4][1024];

  const int bid = blockIdx.x;                       // 512 blocks
  const int rid = (bid & 7) * 64 + (bid >> 3);      // bijective, 512%8==0
  const int q0 = (rid & 7) * 256;
  const int bh = rid >> 3;

  const int tid = threadIdx.x;
  const int l = tid & 63, w = tid >> 6;
  const int lr = l & 15, lk = l >> 4;
  const int m7 = lr & 7;
  const int lkh = lk >> 1, lkb = lk & 1;

  const unsigned short* Qb = Qh + (size_t)bh * kSQ * 64;
  const unsigned short* Kb = Kh + (size_t)bh * kSKV * 64;
  const unsigned short* Vb = Vt + (size_t)bh * 64 * kSKV;

  const float QS = 0.125f * 1.4426950408889634f;
  bf16x8 qf[4][2];
#pragma unroll
  for (int m = 0; m < 4; ++m)
#pragma unroll
    for (int kk = 0; kk < 2; ++kk) {
      bf16x8 v = *(const bf16x8*)
          &Qb[(size_t)(q0 + w * 64 + m * 16 + lr) * 64 + kk * 32 + lk * 8];
#pragma unroll
      for (int j = 0; j < 8; ++j) {
        unsigned short u = (unsigned short)v[j];
        v[j] = (short)f2bf(bf2f(u) * QS);
      }
      qf[m][kk] = v;
    }

  f32x4 oacc[4][4];
  const f32x4 zero = {0.f, 0.f, 0.f, 0.f};
#pragma unroll
  for (int m = 0; m < 4; ++m)
#pragma unroll
    for (int n = 0; n < 4; ++n) oacc[m][n] = zero;
  float lrow[4] = {0.f, 0.f, 0.f, 0.f};

  const int sr8 = l >> 3;
  const int su = (l & 7) ^ sr8;
  unsigned short* lPw = lP[w];

#define ASTAGE(dbuf, tile) do { \
    _Pragma("unroll") for (int cc = 0; cc < 2; ++cc) { \
      const int c = 2 * w + cc; const int row = c * 8 + sr8; \
      gload16(Kb + (size_t)((tile) * 64 + row) * 64 + su * 8, &lK[dbuf][c * 512]); \
      gload16(Vb + (size_t)row * kSKV + (tile) * 64 + su * 8, &lV[dbuf][c * 512]); \
    } } while (0)

  ASTAGE(0, 0);
  __syncthreads();

  for (int kt = 0; kt < 32; ++kt) {
    const int cur = kt & 1;
    if (kt < 31) ASTAGE(cur ^ 1, kt + 1);
    const unsigned short* bufK = lK[cur];
    const unsigned short* bufV = lV[cur];

    // K fragments: loaded once, serve all 4 q-sub-blocks (64 rows)
    bf16x8 kf[4][2];
#pragma unroll
    for (int n = 0; n < 4; ++n)
#pragma unroll
      for (int kk = 0; kk < 2; ++kk) {
        const int ub = (kk * 4 + lk) ^ m7;
        kf[n][kk] = *(const bf16x8*)&bufK[(n * 16 + lr) * 64 + ub * 8];
      }

    bf16x8 pf[4][2];
#pragma unroll
    for (int mp = 0; mp < 2; ++mp) {
      const int ma = mp * 2, mb = mp * 2 + 1;
      // ---- q-sub-block ma ------------------------------------------------
      f32x4 s0[4];
#pragma unroll
      for (int n = 0; n < 4; ++n) s0[n] = zero;
      __builtin_amdgcn_s_setprio(1);
#pragma unroll
      for (int kk = 0; kk < 2; ++kk)
#pragma unroll
        for (int n = 0; n < 4; ++n)
          s0[n] = __builtin_amdgcn_mfma_f32_16x16x32_bf16(kf[n][kk], qf[ma][kk],
                                                          s0[n], 0, 0, 0);
      __builtin_amdgcn_s_setprio(0);
      float ls0 = 0.f;
#pragma unroll
      for (int n = 0; n < 4; ++n) {
        const float p0 = vexp2(s0[n][0]);
        const float p1 = vexp2(s0[n][1]);
        const float p2 = vexp2(s0[n][2]);
        const float p3 = vexp2(s0[n][3]);
        ls0 += (p0 + p1) + (p2 + p3);
        uint2 pv; pv.x = cvtpk(p0, p1); pv.y = cvtpk(p2, p3);
        *(uint2*)&lPw[lr * 64 + (((2 * n + lkh) ^ m7) << 3) + lkb * 4] = pv;
      }
      lrow[ma] += ls0;

      // ---- q-sub-block mb ------------------------------------------------
      f32x4 s1[4];
#pragma unroll
      for (int n = 0; n < 4; ++n) s1[n] = zero;
      __builtin_amdgcn_s_setprio(1);
#pragma unroll
      for (int kk = 0; kk < 2; ++kk)
#pragma unroll
        for (int n = 0; n < 4; ++n)
          s1[n] = __builtin_amdgcn_mfma_f32_16x16x32_bf16(kf[n][kk], qf[mb][kk],
                                                          s1[n], 0, 0, 0);
      __builtin_amdgcn_s_setprio(0);
      float ls1 = 0.f;
      uint2 pw1[4];
#pragma unroll
      for (int n = 0; n < 4; ++n) {
        const float p0 = vexp2(s1[n][0]);
        const float p1 = vexp2(s1[n][1]);
        const float p2 = vexp2(s1[n][2]);
        const float p3 = vexp2(s1[n][3]);
        ls1 += (p0 + p1) + (p2 + p3);
        pw1[n].x = cvtpk(p0, p1); pw1[n].y = cvtpk(p2, p3);
      }
      lrow[mb] += ls1;

      // read P(ma) (write latency covered by QK-mb), write P(mb), read P(mb)
#pragma unroll
      for (int kk = 0; kk < 2; ++kk)
        pf[ma][kk] = *(const bf16x8*)&lPw[lr * 64 + (((kk * 4 + lk) ^ m7) << 3)];
#pragma unroll
      for (int n = 0; n < 4; ++n)
        *(uint2*)&lPw[lr * 64 + (((2 * n + lkh) ^ m7) << 3) + lkb * 4] = pw1[n];
#pragma unroll
      for (int kk = 0; kk < 2; ++kk)
        pf[mb][kk] = *(const bf16x8*)&lPw[lr * 64 + (((kk * 4 + lk) ^ m7) << 3)];
    }

    // ---- O += P @ V : each vf load feeds 4 MFMAs (one per sub-block) -----
    __builtin_amdgcn_s_setprio(1);
#pragma unroll
    for (int n = 0; n < 4; ++n)
#pragma unroll
      for (int kk = 0; kk < 2; ++kk) {
        const int ub = (kk * 4 + lk) ^ m7;
        bf16x8 vf = *(const bf16x8*)&bufV[(n * 16 + lr) * 64 + ub * 8];
#pragma unroll
        for (int m = 0; m < 4; ++m)
          oacc[m][n] = __builtin_amdgcn_mfma_f32_16x16x32_bf16(pf[m][kk], vf,
                                                               oacc[m][n], 0, 0, 0);
      }
    __builtin_amdgcn_s_setprio(0);

    __syncthreads();
  }
#undef ASTAGE

  float rinv[4][4];
#pragma unroll
  for (int m = 0; m < 4; ++m) {
    float s = lrow[m];
    s += __shfl_xor(s, 16);
    s += __shfl_xor(s, 32);
#pragma unroll
    for (int r = 0; r < 4; ++r) rinv[m][r] = 1.0f / __shfl(s, lk * 4 + r);
  }

  const int b = bh >> 4, h = bh & 15;
#pragma unroll
  for (int m = 0; m < 4; ++m)
#pragma unroll
    for (int n = 0; n < 4; ++n)
#pragma unroll
      for (int r = 0; r < 4; ++r) {
        const int qrow = q0 + w * 64 + m * 16 + lk * 4 + r;
        const int d = n * 16 + lr;
        Obf[((size_t)b * kSQ + qrow) * kD + h * 64 + d] =
            f2bf(oacc[m][n][r] * rinv[m][r]);
      }
}

// ---------------------------------------------------------------------------
extern "C" void kernel_launch(void* const* d_in, const int* in_sizes, int n_in,
                              void* d_out, int out_size, void* d_ws, size_t ws_size,
                              hipStream_t stream) {
  (void)in_sizes; (void)n_in; (void)out_size; (void)ws_size;
  const float* hs   = (const float*)d_in[0];
  const float* enc  = (const float*)d_in[1];
  const float* Wq   = (const float*)d_in[2];
  const float* Wk   = (const float*)d_in[3];
  const float* Wv   = (const float*)d_in[4];
  const float* Wo   = (const float*)d_in[5];
  const float* bo   = (const float*)d_in[6];
  const float* q_dn = (const float*)d_in[7];
  const float* q_up = (const float*)d_in[8];
  const float* k_dn = (const float*)d_in[9];
  const float* k_up = (const float*)d_in[10];
  const float* v_dn = (const float*)d_in[11];
  const float* v_up = (const float*)d_in[12];
  const float* o_dn = (const float*)d_in[13];
  const float* o_up = (const float*)d_in[14];

  char* ws = (char*)d_ws;
  size_t off = 0;
  auto alloc = [&](size_t bytes) -> void* {
    void* p = ws + off;
    off += (bytes + 255) & ~(size_t)255;
    return p;
  };
  const size_t ACT = (size_t)kM * kD * 2;
  unsigned short* hsb  = (unsigned short*)alloc(ACT);
  unsigned short* encb = (unsigned short*)alloc(ACT);
  unsigned short* Wqt  = (unsigned short*)alloc((size_t)1024 * 1024 * 2);
  unsigned short* Wkvt = (unsigned short*)alloc((size_t)2048 * 1024 * 2);
  unsigned short* Wot  = (unsigned short*)alloc((size_t)1024 * 1024 * 2);
  unsigned short* Qhp  = (unsigned short*)alloc(ACT);
  unsigned short* Khp  = (unsigned short*)alloc(ACT);
  unsigned short* Vhp  = (unsigned short*)alloc(ACT);
  float* tq  = (float*)alloc((size_t)kM * 4 * 4);
  float* tkv = (float*)alloc((size_t)kM * 8 * 4);
  float* to  = (float*)alloc((size_t)kM * 4 * 4);
  unsigned short* Vtt = hsb;   // alias: V^T reuses hidden bf16 buffer
  unsigned short* Ob  = encb;  // alias: attention O reuses encoder bf16 buffer

  k_prep_wt<<<dim3(2 * kM + 1024), dim3(256), 0, stream>>>(
      hs, enc, Wq, Wk, Wv, Wo, hsb, encb, Wqt, Wkvt, Wot);

  k_lora2<<<dim3(256), dim3(256), 0, stream>>>(hsb, encb, q_dn, k_dn, v_dn,
                                               tq, tkv);

  k_gemm_qkv<<<dim3(768), dim3(512), 0, stream>>>(
      hsb, encb, Wqt, Wkvt, tq, tkv, q_up, k_up, v_up, Qhp, Khp, Vhp);

  k_vt<<<dim3(32, 64), dim3(256), 0, stream>>>(Vhp, Vtt);
  k_attn<<<dim3(512), dim3(256), 0, stream>>>(Qhp, Khp, Vtt, Ob);

  k_lora<<<dim3(128), dim3(256), 0, stream>>>(Ob, o_dn, to, 4);

  k_gemm_out<<<dim3(256), dim3(512), 0, stream>>>(Ob, Wot, to, o_up, bo,
                                                  (float*)d_out);
}